// Round 9
// baseline (436.719 us; speedup 1.0000x reference)
//
#include <hip/hip_runtime.h>
#include <math.h>

typedef unsigned short u16;
typedef __attribute__((ext_vector_type(8))) __bf16 bfx8;
typedef __attribute__((ext_vector_type(4))) float f32x4;
typedef __attribute__((ext_vector_type(8))) unsigned short us8;
typedef __attribute__((ext_vector_type(4))) unsigned short us4;

#define NCOPY 8

__device__ inline float bf2f(u16 u) {
    union { unsigned int i; float f; } v;
    v.i = ((unsigned int)u) << 16;
    return v.f;
}
__device__ inline u16 f2bf(float f) {
    union { float f; unsigned int i; } v;
    v.f = f;
    unsigned int b = v.i;
    return (u16)((b + 0x7FFFu + ((b >> 16) & 1u)) >> 16);
}

// ---------------- CSR build ----------------

__global__ void k_zero_int(int* __restrict__ p, int n) {
    int i = blockIdx.x * blockDim.x + threadIdx.x;
    if (i < n) p[i] = 0;
}

// single atomic pass: count into 8-way replicated counters + record local
// offset within (node, copy). copy = gid&7 (recomputable in k_place).
__global__ __launch_bounds__(256) void k_count_loc(const int* __restrict__ ei,
                                                   int* __restrict__ cnt2,
                                                   int* __restrict__ lo,
                                                   int E, int N) {
    int gid = blockIdx.x * blockDim.x + threadIdx.x;
    int base = gid * 4;
    int* cp = cnt2 + (size_t)(gid & (NCOPY - 1)) * N;
    if (base + 4 <= E) {
        int4 d = *(const int4*)(ei + E + base);
        int l0 = atomicAdd(&cp[d.x], 1);
        int l1 = atomicAdd(&cp[d.y], 1);
        int l2 = atomicAdd(&cp[d.z], 1);
        int l3 = atomicAdd(&cp[d.w], 1);
        *(int4*)(lo + base) = make_int4(l0, l1, l2, l3);
    } else {
        for (int e = base; e < E; ++e) {
            lo[e] = atomicAdd(&cp[ei[E + e]], 1);
        }
    }
}

// per-block (512 nodes) partial sums of total counts (sum over copies)
__global__ __launch_bounds__(256) void k_partial(const int* __restrict__ cnt2,
                                                 int* __restrict__ partials,
                                                 int n, int N) {
    __shared__ int sdata[256];
    int base = blockIdx.x * 512;
    int t = threadIdx.x;
    int v = 0;
    #pragma unroll
    for (int c = 0; c < NCOPY; ++c) {
        const int* cp = cnt2 + (size_t)c * N;
        if (base + t < n) v += cp[base + t];
        if (base + 256 + t < n) v += cp[base + 256 + t];
    }
    sdata[t] = v;
    __syncthreads();
    for (int s = 128; s > 0; s >>= 1) {
        if (t < s) sdata[t] += sdata[t + s];
        __syncthreads();
    }
    if (t == 0) partials[blockIdx.x] = sdata[0];
}

__global__ __launch_bounds__(256) void k_scan_top(const int* __restrict__ partials,
                                                  int* __restrict__ blkoff, int nb) {
    __shared__ int lds[256];
    int t = threadIdx.x;
    int v = (t < nb) ? partials[t] : 0;
    lds[t] = v;
    __syncthreads();
    for (int off = 1; off < 256; off <<= 1) {
        int x = lds[t];
        int y = (t >= off) ? lds[t - off] : 0;
        __syncthreads();
        lds[t] = x + y;
        __syncthreads();
    }
    if (t < nb) blkoff[t] = lds[t] - v;   // exclusive
}

// per-block local scan + block offset -> row_ptr, dinv, per-copy bases
__global__ __launch_bounds__(512) void k_apply(const int* __restrict__ cnt2,
                                               const int* __restrict__ blkoff,
                                               int* __restrict__ row_ptr,
                                               int* __restrict__ cbase,
                                               float* __restrict__ dinv,
                                               int n, int N, int Etot) {
    __shared__ int lds[512];
    int b = blockIdx.x, t = threadIdx.x;
    int i = b * 512 + t;
    int v = 0;
    if (i < n) {
        int pre = 0;
        #pragma unroll
        for (int c = 0; c < NCOPY; ++c) {
            int vc = cnt2[(size_t)c * N + i];
            cbase[(size_t)c * N + i] = pre;
            pre += vc;
        }
        v = pre;
    }
    lds[t] = v;
    __syncthreads();
    for (int off = 1; off < 512; off <<= 1) {
        int x = lds[t];
        int y = (t >= off) ? lds[t - off] : 0;
        __syncthreads();
        lds[t] = x + y;
        __syncthreads();
    }
    if (i < n) {
        int excl = blkoff[b] + lds[t] - v;
        row_ptr[i] = excl;
        dinv[i] = rsqrtf((float)v + 1.0f);
    }
    if (i == 0) row_ptr[n] = Etot;
}

// atomic-free placement: csr_src[row_ptr[d] + cbase[copy][d] + lo[e]] = s
__global__ __launch_bounds__(256) void k_place(const int* __restrict__ ei,
                                               const int* __restrict__ row_ptr,
                                               const int* __restrict__ cbase,
                                               const int* __restrict__ lo,
                                               int* __restrict__ csr_src,
                                               int E, int N) {
    int gid = blockIdx.x * blockDim.x + threadIdx.x;
    int base = gid * 4;
    const int* cb = cbase + (size_t)(gid & (NCOPY - 1)) * N;
    if (base + 4 <= E) {
        int4 s = *(const int4*)(ei + base);
        int4 d = *(const int4*)(ei + E + base);
        int4 l = *(const int4*)(lo + base);
        int p0 = row_ptr[d.x] + cb[d.x] + l.x;
        int p1 = row_ptr[d.y] + cb[d.y] + l.y;
        int p2 = row_ptr[d.z] + cb[d.z] + l.z;
        int p3 = row_ptr[d.w] + cb[d.w] + l.w;
        csr_src[p0] = s.x;
        csr_src[p1] = s.y;
        csr_src[p2] = s.z;
        csr_src[p3] = s.w;
    } else {
        for (int e = base; e < E; ++e) {
            int d = ei[E + e];
            csr_src[row_ptr[d] + cb[d] + lo[e]] = ei[e];
        }
    }
}

// ---------------- small converts ----------------

__global__ void k_bnfold(const float* __restrict__ b, const float* __restrict__ g,
                         const float* __restrict__ be, const float* __restrict__ m,
                         const float* __restrict__ v, float* __restrict__ s,
                         float* __restrict__ t, int H) {
    int i = blockIdx.x * blockDim.x + threadIdx.x;
    if (i < H) {
        float sc = g[i] * rsqrtf(v[i] + 1e-5f);
        s[i] = sc;
        t[i] = (b[i] - m[i]) * sc + be[i];
    }
}

// W[K,F] f32 -> Wt[F,K] bf16
__global__ void k_w2bf(const float* __restrict__ W, u16* __restrict__ Wt, int K, int F) {
    int i = blockIdx.x * blockDim.x + threadIdx.x;
    if (i < K * F) {
        int k = i / F, f = i % F;
        Wt[(size_t)f * K + k] = f2bf(W[i]);
    }
}

// x f32 -> bf16 pre-scaled by dinv[row]  (row = i4/32 for F=128)
__global__ void k_x2bf(const float* __restrict__ x, u16* __restrict__ xb,
                       const float* __restrict__ dinv, int n4) {
    int i = blockIdx.x * blockDim.x + threadIdx.x;
    if (i < n4) {
        float d = dinv[i >> 5];
        float4 v = *(const float4*)(x + (size_t)i * 4);
        us4 o;
        o.x = f2bf(v.x * d); o.y = f2bf(v.y * d); o.z = f2bf(v.z * d); o.w = f2bf(v.w * d);
        *(us4*)(xb + (size_t)i * 4) = o;
    }
}

// ---------------- MFMA GEMM: persistent blocks, B in registers, A via LDS ---
template<int K, int FT, int MODE, int MINW>
__global__ __launch_bounds__(256, MINW) void g_mfma_lds(
    const u16* __restrict__ A, const u16* __restrict__ Wt,
    u16* __restrict__ C, int M, int Ftot,
    const float* __restrict__ s, const float* __restrict__ t,
    const float* __restrict__ dinv, int nTiles)
{
    constexpr int BK  = 128;
    constexpr int SA  = BK + 8;
    constexpr int NH  = K / BK;
    constexpr int NKH = BK / 32;
    constexpr int NF  = FT / 16;
    constexpr int SC  = FT + 8;

    __shared__ u16 Asmem[2][64 * SA];
    __shared__ u16 Csmem[64 * SC];

    int tid = threadIdx.x;
    int w = tid >> 6, l = tid & 63;
    int lr = l & 15, koff8 = (l >> 4) * 8;
    int col0 = blockIdx.y * FT;

    bfx8 bfr[NH][NKH][NF];
    {
        const u16* wp = Wt + (size_t)(col0 + lr) * K + koff8;
        #pragma unroll
        for (int h = 0; h < NH; ++h)
            #pragma unroll
            for (int kk = 0; kk < NKH; ++kk)
                #pragma unroll
                for (int c = 0; c < NF; ++c)
                    bfr[h][kk][c] = *(const bfx8*)(wp + (size_t)c * 16 * K + h * BK + kk * 32);
    }

    int myT = (blockIdx.x < nTiles) ? ((nTiles - 1 - (int)blockIdx.x) / (int)gridDim.x + 1) : 0;
    int NM = myT * NH;
    if (NM == 0) return;

    f32x4 acc[NF];
    #pragma unroll
    for (int c = 0; c < NF; ++c) acc[c] = (f32x4){0.f, 0.f, 0.f, 0.f};

    us8 rga[4];

    {
        int row0 = blockIdx.x * 64;
        #pragma unroll
        for (int j = 0; j < 4; ++j) {
            int cid = j * 256 + tid;
            int row = cid >> 4, ch = cid & 15;
            int gr = row0 + row; if (gr > M - 1) gr = M - 1;
            rga[j] = *(const us8*)(A + (size_t)gr * K + 0 * BK + ch * 8);
        }
        #pragma unroll
        for (int j = 0; j < 4; ++j) {
            int cid = j * 256 + tid;
            int row = cid >> 4, ch = cid & 15;
            *(us8*)&Asmem[0][row * SA + ch * 8] = rga[j];
        }
        if (NM > 1) {
            constexpr int gt1 = 1 / NH, h1 = 1 % NH;
            int r0 = (blockIdx.x + gt1 * gridDim.x) * 64;
            #pragma unroll
            for (int j = 0; j < 4; ++j) {
                int cid = j * 256 + tid;
                int row = cid >> 4, ch = cid & 15;
                int gr = r0 + row; if (gr > M - 1) gr = M - 1;
                rga[j] = *(const us8*)(A + (size_t)gr * K + h1 * BK + ch * 8);
            }
        }
    }
    __syncthreads();

    int cur = 0, gm = 0;
    for (int ti = 0; ti < myT; ++ti) {
        int row0g = (blockIdx.x + ti * gridDim.x) * 64;
        #pragma unroll
        for (int h = 0; h < NH; ++h) {
            const u16* ab = &Asmem[cur][0];
            #pragma unroll
            for (int kk = 0; kk < NKH; ++kk) {
                bfx8 af = *(const bfx8*)(ab + (w * 16 + lr) * SA + koff8 + kk * 32);
                #pragma unroll
                for (int c = 0; c < NF; ++c)
                    acc[c] = __builtin_amdgcn_mfma_f32_16x16x32_bf16(af, bfr[h][kk][c], acc[c], 0, 0, 0);
            }
            if (h == NH - 1) {
                int orow = w * 16 + (l >> 4) * 4;
                float dr[4];
                #pragma unroll
                for (int r = 0; r < 4; ++r) {
                    int grow = row0g + orow + r;
                    dr[r] = (MODE == 1) ? ((grow < M) ? dinv[grow] : 0.f) : 1.f;
                }
                #pragma unroll
                for (int c = 0; c < NF; ++c) {
                    int gc = col0 + c * 16 + lr;
                    float sc = (MODE == 1) ? s[gc] : 0.f;
                    float tc = (MODE == 1) ? t[gc] : 0.f;
                    #pragma unroll
                    for (int r = 0; r < 4; ++r) {
                        float v = acc[c][r];
                        u16 ov = (MODE == 1) ? f2bf(fmaxf(v * sc + tc, 0.f) * dr[r])
                                             : f2bf(v);
                        Csmem[(orow + r) * SC + c * 16 + lr] = ov;
                    }
                    acc[c] = (f32x4){0.f, 0.f, 0.f, 0.f};
                }
            }
            __syncthreads();
            if (gm + 1 < NM) {
                #pragma unroll
                for (int j = 0; j < 4; ++j) {
                    int cid = j * 256 + tid;
                    int row = cid >> 4, ch = cid & 15;
                    *(us8*)&Asmem[cur ^ 1][row * SA + ch * 8] = rga[j];
                }
            }
            if (h == NH - 1) {
                constexpr int CPR = FT / 8;
                constexpr int CPT = (64 * CPR) / 256;
                #pragma unroll
                for (int j = 0; j < CPT; ++j) {
                    int cid = j * 256 + tid;
                    int crow = cid / CPR;
                    int ccol = (cid % CPR) * 8;
                    int grow = row0g + crow;
                    if (grow < M) {
                        us8 vv = *(const us8*)&Csmem[crow * SC + ccol];
                        *(us8*)(C + (size_t)grow * Ftot + col0 + ccol) = vv;
                    }
                }
            }
            if (gm + 2 < NM) {
                int g2 = gm + 2;
                int gt2 = g2 / NH, h2 = g2 % NH;
                int r0 = (blockIdx.x + gt2 * gridDim.x) * 64;
                #pragma unroll
                for (int j = 0; j < 4; ++j) {
                    int cid = j * 256 + tid;
                    int row = cid >> 4, ch = cid & 15;
                    int gr = r0 + row; if (gr > M - 1) gr = M - 1;
                    rga[j] = *(const us8*)(A + (size_t)gr * K + h2 * BK + ch * 8);
                }
            }
            __syncthreads();
            cur ^= 1; ++gm;
        }
    }
}

// ---------------- Aggregation ----------------
// agg_x: F=128 bf16. 32 lanes/node, lane owns 4 features. 8-edge unroll.
__global__ __launch_bounds__(256) void agg_x(const u16* __restrict__ in,
                                             u16* __restrict__ outp,
                                             const int* __restrict__ row_ptr,
                                             const int* __restrict__ csr_src,
                                             const float* __restrict__ dinv,
                                             int nnodes) {
    int tid = threadIdx.x;
    int wv = tid >> 6, lane = tid & 63;
    int half = lane >> 5, l32 = lane & 31;
    int node = (blockIdx.x * 4 + wv) * 2 + half;
    if (node >= nnodes) return;
    int off = l32 * 4;
    const u16* bp = in + off;
    us4 su = *(const us4*)(in + (size_t)node * 128 + off);
    float a0 = bf2f(su.x), a1 = bf2f(su.y), a2 = bf2f(su.z), a3 = bf2f(su.w);
    int e = row_ptr[node], e1 = row_ptr[node + 1];
    for (; e + 8 <= e1; e += 8) {
        int sx[8];
        #pragma unroll
        for (int q = 0; q < 8; ++q) sx[q] = csr_src[e + q];
        us4 vv[8];
        #pragma unroll
        for (int q = 0; q < 8; ++q) vv[q] = *(const us4*)(bp + (size_t)sx[q] * 128);
        #pragma unroll
        for (int q = 0; q < 8; ++q) {
            a0 += bf2f(vv[q].x); a1 += bf2f(vv[q].y);
            a2 += bf2f(vv[q].z); a3 += bf2f(vv[q].w);
        }
    }
    for (; e < e1; ++e) {
        int s0 = csr_src[e];
        us4 v0 = *(const us4*)(bp + (size_t)s0 * 128);
        a0 += bf2f(v0.x); a1 += bf2f(v0.y);
        a2 += bf2f(v0.z); a3 += bf2f(v0.w);
    }
    float d = dinv[node];
    us4 o;
    o.x = f2bf(a0 * d); o.y = f2bf(a1 * d); o.z = f2bf(a2 * d); o.w = f2bf(a3 * d);
    *(us4*)(outp + (size_t)node * 128 + off) = o;
}

// agg_h: F=256 bf16. 32 lanes/node, lane owns 8 features. 8-edge unroll.
__global__ __launch_bounds__(256) void agg_h(const u16* __restrict__ in,
                                             u16* __restrict__ outp,
                                             const int* __restrict__ row_ptr,
                                             const int* __restrict__ csr_src,
                                             const float* __restrict__ dinv,
                                             int nnodes) {
    int tid = threadIdx.x;
    int wv = tid >> 6, lane = tid & 63;
    int half = lane >> 5, l32 = lane & 31;
    int node = (blockIdx.x * 4 + wv) * 2 + half;
    if (node >= nnodes) return;
    int off = l32 * 8;
    const u16* bp = in + off;
    float acc[8];
    us8 su = *(const us8*)(in + (size_t)node * 256 + off);
    #pragma unroll
    for (int j = 0; j < 8; ++j) acc[j] = bf2f(su[j]);
    int e = row_ptr[node], e1 = row_ptr[node + 1];
    for (; e + 8 <= e1; e += 8) {
        int sx[8];
        #pragma unroll
        for (int q = 0; q < 8; ++q) sx[q] = csr_src[e + q];
        us8 vv[8];
        #pragma unroll
        for (int q = 0; q < 8; ++q) vv[q] = *(const us8*)(bp + (size_t)sx[q] * 256);
        #pragma unroll
        for (int q = 0; q < 8; ++q)
            #pragma unroll
            for (int j = 0; j < 8; ++j) acc[j] += bf2f(vv[q][j]);
    }
    for (; e < e1; ++e) {
        int s0 = csr_src[e];
        us8 v0 = *(const us8*)(bp + (size_t)s0 * 256);
        #pragma unroll
        for (int j = 0; j < 8; ++j) acc[j] += bf2f(v0[j]);
    }
    float d = dinv[node];
    us8 o;
    #pragma unroll
    for (int j = 0; j < 8; ++j) o[j] = f2bf(acc[j] * d);
    *(us8*)(outp + (size_t)node * 256 + off) = o;
}

// agg32: F=32 bf16 in, f32 sigmoid out. 32 lanes/node, 2 nodes/wave.
__global__ __launch_bounds__(256) void agg32_sig(const u16* __restrict__ z,
                                                 float* __restrict__ out,
                                                 const int* __restrict__ row_ptr,
                                                 const int* __restrict__ csr_src,
                                                 const float* __restrict__ dinv,
                                                 const float* __restrict__ b3,
                                                 int nnodes) {
    int tid = threadIdx.x;
    int wv = tid >> 6, lane = tid & 63;
    int half = lane >> 5, l32 = lane & 31;
    int node = (blockIdx.x * 4 + wv) * 2 + half;
    if (node >= nnodes) return;
    float acc = bf2f(z[(size_t)node * 32 + l32]);
    int e = row_ptr[node], e1 = row_ptr[node + 1];
    for (; e + 4 <= e1; e += 4) {
        int s0 = csr_src[e], s1 = csr_src[e + 1], s2 = csr_src[e + 2], s3 = csr_src[e + 3];
        float z0 = bf2f(z[(size_t)s0 * 32 + l32]);
        float z1 = bf2f(z[(size_t)s1 * 32 + l32]);
        float z2 = bf2f(z[(size_t)s2 * 32 + l32]);
        float z3v = bf2f(z[(size_t)s3 * 32 + l32]);
        acc += z0 + z1 + z2 + z3v;
    }
    for (; e < e1; ++e) {
        acc += bf2f(z[(size_t)csr_src[e] * 32 + l32]);
    }
    acc = acc * dinv[node] + b3[l32];
    out[(size_t)node * 32 + l32] = 1.f / (1.f + expf(-acc));
}

// ---------------- launch ----------------

extern "C" void kernel_launch(void* const* d_in, const int* in_sizes, int n_in,
                              void* d_out, int out_size, void* d_ws, size_t ws_size,
                              hipStream_t stream) {
    const float* x  = (const float*)d_in[0];
    const int*   ei = (const int*)d_in[1];
    const float* W1 = (const float*)d_in[2];
    const float* b1 = (const float*)d_in[3];
    const float* g1 = (const float*)d_in[4];
    const float* be1 = (const float*)d_in[5];
    const float* m1 = (const float*)d_in[6];
    const float* v1 = (const float*)d_in[7];
    const float* W2 = (const float*)d_in[8];
    const float* b2 = (const float*)d_in[9];
    const float* g2 = (const float*)d_in[10];
    const float* be2 = (const float*)d_in[11];
    const float* m2 = (const float*)d_in[12];
    const float* v2 = (const float*)d_in[13];
    const float* W3 = (const float*)d_in[14];
    const float* b3 = (const float*)d_in[15];
    float* out = (float*)d_out;

    const int N = in_sizes[0] / 128;   // 100000
    const int E = in_sizes[1] / 2;     // 1600000

    char* w = (char*)d_ws;
    auto alloc = [&](size_t bytes) -> void* {
        void* p = (void*)w;
        w += (bytes + 255) & ~(size_t)255;
        return p;
    };
    int* cnt2     = (int*)alloc((size_t)N * NCOPY * 4);
    int* cbase    = (int*)alloc((size_t)N * NCOPY * 4);
    int* row_ptr  = (int*)alloc((size_t)(N + 1) * 4);
    int* lo       = (int*)alloc((size_t)E * 4);
    float* dinv   = (float*)alloc((size_t)N * 4);
    int* partials = (int*)alloc(256 * 4);
    int* blkoff   = (int*)alloc(256 * 4);
    float* s1 = (float*)alloc(256 * 4);
    float* t1 = (float*)alloc(256 * 4);
    float* s2 = (float*)alloc(256 * 4);
    float* t2 = (float*)alloc(256 * 4);
    u16* Wt1 = (u16*)alloc((size_t)128 * 256 * 2);
    u16* Wt2 = (u16*)alloc((size_t)256 * 256 * 2);
    u16* Wt3 = (u16*)alloc((size_t)256 * 32 * 2);
    int* csr_src = (int*)alloc((size_t)E * 4);
    u16* xbf  = (u16*)alloc((size_t)N * 128 * 2);
    u16* bufA = (u16*)alloc((size_t)N * 256 * 2);
    u16* bufB = (u16*)alloc((size_t)N * 256 * 2);
    u16* z3 = xbf;

    int nb = (N + 511) / 512;
    int nT = (N + 63) / 64;
    int gagg = (N + 7) / 8;
    int ge4 = (E / 4 + 255) / 256;

    // CSR build: one atomic pass (8-way counters) + scan + atomic-free place
    k_zero_int<<<(N * NCOPY + 255) / 256, 256, 0, stream>>>(cnt2, N * NCOPY);
    k_count_loc<<<ge4, 256, 0, stream>>>(ei, cnt2, lo, E, N);
    k_partial<<<nb, 256, 0, stream>>>(cnt2, partials, N, N);
    k_scan_top<<<1, 256, 0, stream>>>(partials, blkoff, nb);
    k_apply<<<nb, 512, 0, stream>>>(cnt2, blkoff, row_ptr, cbase, dinv, N, N, E);
    k_place<<<ge4, 256, 0, stream>>>(ei, row_ptr, cbase, lo, csr_src, E, N);

    // param prep
    k_bnfold<<<1, 256, 0, stream>>>(b1, g1, be1, m1, v1, s1, t1, 256);
    k_bnfold<<<1, 256, 0, stream>>>(b2, g2, be2, m2, v2, s2, t2, 256);
    k_w2bf<<<(128 * 256 + 255) / 256, 256, 0, stream>>>(W1, Wt1, 128, 256);
    k_w2bf<<<(256 * 256 + 255) / 256, 256, 0, stream>>>(W2, Wt2, 256, 256);
    k_w2bf<<<(256 * 32 + 255) / 256, 256, 0, stream>>>(W3, Wt3, 256, 32);
    k_x2bf<<<(N * 128 / 4 + 255) / 256, 256, 0, stream>>>(x, xbf, dinv, N * 128 / 4);

    // Layer 1
    agg_x<<<gagg, 256, 0, stream>>>(xbf, bufA, row_ptr, csr_src, dinv, N);
    g_mfma_lds<128, 64, 1, 2><<<dim3(128, 4), 256, 0, stream>>>(
        bufA, Wt1, bufB, N, 256, s1, t1, dinv, nT);

    // Layer 2
    agg_h<<<gagg, 256, 0, stream>>>(bufB, bufA, row_ptr, csr_src, dinv, N);
    g_mfma_lds<256, 64, 1, 2><<<dim3(128, 4), 256, 0, stream>>>(
        bufA, Wt2, bufB, N, 256, s2, t2, dinv, nT);

    // Layer 3
    g_mfma_lds<256, 32, 2, 2><<<dim3(512, 1), 256, 0, stream>>>(
        bufB, Wt3, z3, N, 32, (const float*)nullptr, (const float*)nullptr,
        (const float*)nullptr, nT);
    agg32_sig<<<gagg, 256, 0, stream>>>(z3, out, row_ptr, csr_src, dinv, b3, N);
}

// Round 10
// 367.892 us; speedup vs baseline: 1.1871x; 1.1871x over previous
//
#include <hip/hip_runtime.h>
#include <math.h>

typedef unsigned short u16;
typedef unsigned char u8;
typedef __attribute__((ext_vector_type(8))) __bf16 bfx8;
typedef __attribute__((ext_vector_type(4))) float f32x4;
typedef __attribute__((ext_vector_type(2))) float f32x2;
typedef __attribute__((ext_vector_type(8))) unsigned short us8;
typedef __attribute__((ext_vector_type(4))) unsigned short us4;

__device__ inline float bf2f(u16 u) {
    union { unsigned int i; float f; } v;
    v.i = ((unsigned int)u) << 16;
    return v.f;
}
__device__ inline u16 f2bf(float f) {
    union { float f; unsigned int i; } v;
    v.f = f;
    unsigned int b = v.i;
    return (u16)((b + 0x7FFFu + ((b >> 16) & 1u)) >> 16);
}

// ---------------- CSR build (round-8 form) ----------------

__global__ void k_zero_int(int* __restrict__ p, int n) {
    int i = blockIdx.x * blockDim.x + threadIdx.x;
    if (i < n) p[i] = 0;
}

__global__ __launch_bounds__(256) void k_count_loc(const int* __restrict__ ei,
                                                   int* __restrict__ cnt,
                                                   int* __restrict__ lo, int E) {
    int base = (blockIdx.x * blockDim.x + threadIdx.x) * 4;
    if (base + 4 <= E) {
        int4 d = *(const int4*)(ei + E + base);
        int l0 = atomicAdd(&cnt[d.x], 1);
        int l1 = atomicAdd(&cnt[d.y], 1);
        int l2 = atomicAdd(&cnt[d.z], 1);
        int l3 = atomicAdd(&cnt[d.w], 1);
        *(int4*)(lo + base) = make_int4(l0, l1, l2, l3);
    } else {
        for (int e = base; e < E; ++e) {
            lo[e] = atomicAdd(&cnt[ei[E + e]], 1);
        }
    }
}

__global__ __launch_bounds__(256) void k_partial(const int* __restrict__ cnt,
                                                 int* __restrict__ partials, int n) {
    __shared__ int sdata[256];
    int base = blockIdx.x * 512;
    int t = threadIdx.x;
    int v = 0;
    if (base + t < n) v += cnt[base + t];
    if (base + 256 + t < n) v += cnt[base + 256 + t];
    sdata[t] = v;
    __syncthreads();
    for (int s = 128; s > 0; s >>= 1) {
        if (t < s) sdata[t] += sdata[t + s];
        __syncthreads();
    }
    if (t == 0) partials[blockIdx.x] = sdata[0];
}

__global__ __launch_bounds__(256) void k_scan_top(const int* __restrict__ partials,
                                                  int* __restrict__ blkoff, int nb) {
    __shared__ int lds[256];
    int t = threadIdx.x;
    int v = (t < nb) ? partials[t] : 0;
    lds[t] = v;
    __syncthreads();
    for (int off = 1; off < 256; off <<= 1) {
        int x = lds[t];
        int y = (t >= off) ? lds[t - off] : 0;
        __syncthreads();
        lds[t] = x + y;
        __syncthreads();
    }
    if (t < nb) blkoff[t] = lds[t] - v;   // exclusive
}

__global__ __launch_bounds__(512) void k_apply(const int* __restrict__ cnt,
                                               const int* __restrict__ blkoff,
                                               int* __restrict__ row_ptr,
                                               float* __restrict__ dinv,
                                               int n, int Etot) {
    __shared__ int lds[512];
    int b = blockIdx.x, t = threadIdx.x;
    int i = b * 512 + t;
    int v = (i < n) ? cnt[i] : 0;
    lds[t] = v;
    __syncthreads();
    for (int off = 1; off < 512; off <<= 1) {
        int x = lds[t];
        int y = (t >= off) ? lds[t - off] : 0;
        __syncthreads();
        lds[t] = x + y;
        __syncthreads();
    }
    if (i < n) {
        int excl = blkoff[b] + lds[t] - v;
        row_ptr[i] = excl;
        dinv[i] = rsqrtf((float)v + 1.0f);
    }
    if (i == 0) row_ptr[n] = Etot;
}

__global__ __launch_bounds__(256) void k_place(const int* __restrict__ ei,
                                               const int* __restrict__ row_ptr,
                                               const int* __restrict__ lo,
                                               int* __restrict__ csr_src, int E) {
    int base = (blockIdx.x * blockDim.x + threadIdx.x) * 4;
    if (base + 4 <= E) {
        int4 s = *(const int4*)(ei + base);
        int4 d = *(const int4*)(ei + E + base);
        int4 l = *(const int4*)(lo + base);
        int p0 = row_ptr[d.x] + l.x;
        int p1 = row_ptr[d.y] + l.y;
        int p2 = row_ptr[d.z] + l.z;
        int p3 = row_ptr[d.w] + l.w;
        csr_src[p0] = s.x;
        csr_src[p1] = s.y;
        csr_src[p2] = s.z;
        csr_src[p3] = s.w;
    } else {
        for (int e = base; e < E; ++e) {
            csr_src[row_ptr[ei[E + e]] + lo[e]] = ei[e];
        }
    }
}

// ---------------- small converts ----------------

__global__ void k_bnfold(const float* __restrict__ b, const float* __restrict__ g,
                         const float* __restrict__ be, const float* __restrict__ m,
                         const float* __restrict__ v, float* __restrict__ s,
                         float* __restrict__ t, int H) {
    int i = blockIdx.x * blockDim.x + threadIdx.x;
    if (i < H) {
        float sc = g[i] * rsqrtf(v[i] + 1e-5f);
        s[i] = sc;
        t[i] = (b[i] - m[i]) * sc + be[i];
    }
}

// W[K,F] f32 -> Wt[F,K] bf16
__global__ void k_w2bf(const float* __restrict__ W, u16* __restrict__ Wt, int K, int F) {
    int i = blockIdx.x * blockDim.x + threadIdx.x;
    if (i < K * F) {
        int k = i / F, f = i % F;
        Wt[(size_t)f * K + k] = f2bf(W[i]);
    }
}

// x f32 -> bf16 pre-scaled by dinv[row]  (row = i4/32 for F=128)
__global__ void k_x2bf(const float* __restrict__ x, u16* __restrict__ xb,
                       const float* __restrict__ dinv, int n4) {
    int i = blockIdx.x * blockDim.x + threadIdx.x;
    if (i < n4) {
        float d = dinv[i >> 5];
        float4 v = *(const float4*)(x + (size_t)i * 4);
        us4 o;
        o.x = f2bf(v.x * d); o.y = f2bf(v.y * d); o.z = f2bf(v.z * d); o.w = f2bf(v.w * d);
        *(us4*)(xb + (size_t)i * 4) = o;
    }
}

// ---------------- MFMA GEMM: persistent blocks, B in registers, A via LDS ---
// MODE 1: BN+ReLU then * dinv[row], bf16 store.
// MODE 2: plain bf16 store.
// MODE 3: BN+ReLU then * dinv[row], fp8(e4m3 HW cvt) store.
template<int K, int FT, int MODE, int MINW>
__global__ __launch_bounds__(256, MINW) void g_mfma_lds(
    const u16* __restrict__ A, const u16* __restrict__ Wt,
    void* __restrict__ Cv, int M, int Ftot,
    const float* __restrict__ s, const float* __restrict__ t,
    const float* __restrict__ dinv, int nTiles)
{
    constexpr int BK  = 128;
    constexpr int SA  = BK + 8;
    constexpr int NH  = K / BK;
    constexpr int NKH = BK / 32;
    constexpr int NF  = FT / 16;
    constexpr int EB  = (MODE == 3) ? 1 : 2;       // bytes per C element
    constexpr int SCB = FT * EB + 16;              // padded C row stride (bytes)

    __shared__ u16 Asmem[2][64 * SA];
    __shared__ u8  Cs8[64 * SCB];

    int tid = threadIdx.x;
    int w = tid >> 6, l = tid & 63;
    int lr = l & 15, koff8 = (l >> 4) * 8;
    int col0 = blockIdx.y * FT;

    bfx8 bfr[NH][NKH][NF];
    {
        const u16* wp = Wt + (size_t)(col0 + lr) * K + koff8;
        #pragma unroll
        for (int h = 0; h < NH; ++h)
            #pragma unroll
            for (int kk = 0; kk < NKH; ++kk)
                #pragma unroll
                for (int c = 0; c < NF; ++c)
                    bfr[h][kk][c] = *(const bfx8*)(wp + (size_t)c * 16 * K + h * BK + kk * 32);
    }

    int myT = (blockIdx.x < nTiles) ? ((nTiles - 1 - (int)blockIdx.x) / (int)gridDim.x + 1) : 0;
    int NM = myT * NH;
    if (NM == 0) return;

    f32x4 acc[NF];
    #pragma unroll
    for (int c = 0; c < NF; ++c) acc[c] = (f32x4){0.f, 0.f, 0.f, 0.f};

    us8 rga[4];

    {
        int row0 = blockIdx.x * 64;
        #pragma unroll
        for (int j = 0; j < 4; ++j) {
            int cid = j * 256 + tid;
            int row = cid >> 4, ch = cid & 15;
            int gr = row0 + row; if (gr > M - 1) gr = M - 1;
            rga[j] = *(const us8*)(A + (size_t)gr * K + 0 * BK + ch * 8);
        }
        #pragma unroll
        for (int j = 0; j < 4; ++j) {
            int cid = j * 256 + tid;
            int row = cid >> 4, ch = cid & 15;
            *(us8*)&Asmem[0][row * SA + ch * 8] = rga[j];
        }
        if (NM > 1) {
            constexpr int gt1 = 1 / NH, h1 = 1 % NH;
            int r0 = (blockIdx.x + gt1 * gridDim.x) * 64;
            #pragma unroll
            for (int j = 0; j < 4; ++j) {
                int cid = j * 256 + tid;
                int row = cid >> 4, ch = cid & 15;
                int gr = r0 + row; if (gr > M - 1) gr = M - 1;
                rga[j] = *(const us8*)(A + (size_t)gr * K + h1 * BK + ch * 8);
            }
        }
    }
    __syncthreads();

    int cur = 0, gm = 0;
    for (int ti = 0; ti < myT; ++ti) {
        int row0g = (blockIdx.x + ti * gridDim.x) * 64;
        #pragma unroll
        for (int h = 0; h < NH; ++h) {
            const u16* ab = &Asmem[cur][0];
            #pragma unroll
            for (int kk = 0; kk < NKH; ++kk) {
                bfx8 af = *(const bfx8*)(ab + (w * 16 + lr) * SA + koff8 + kk * 32);
                #pragma unroll
                for (int c = 0; c < NF; ++c)
                    acc[c] = __builtin_amdgcn_mfma_f32_16x16x32_bf16(af, bfr[h][kk][c], acc[c], 0, 0, 0);
            }
            if (h == NH - 1) {
                int orow = w * 16 + (l >> 4) * 4;
                float dr[4];
                #pragma unroll
                for (int r = 0; r < 4; ++r) {
                    int grow = row0g + orow + r;
                    dr[r] = (MODE == 2) ? 1.f : ((grow < M) ? dinv[grow] : 0.f);
                }
                #pragma unroll
                for (int c = 0; c < NF; ++c) {
                    int gc = col0 + c * 16 + lr;
                    float sc = (MODE == 2) ? 0.f : s[gc];
                    float tc = (MODE == 2) ? 0.f : t[gc];
                    #pragma unroll
                    for (int r = 0; r < 4; ++r) {
                        float v = acc[c][r];
                        if (MODE != 2) v = fmaxf(v * sc + tc, 0.f) * dr[r];
                        if (MODE == 3) {
                            int enc = __builtin_amdgcn_cvt_pk_fp8_f32(v, v, 0, false);
                            Cs8[(orow + r) * SCB + (c * 16 + lr)] = (u8)(enc & 0xff);
                        } else {
                            *(u16*)&Cs8[(orow + r) * SCB + (c * 16 + lr) * 2] = f2bf(v);
                        }
                    }
                    acc[c] = (f32x4){0.f, 0.f, 0.f, 0.f};
                }
            }
            __syncthreads();
            if (gm + 1 < NM) {
                #pragma unroll
                for (int j = 0; j < 4; ++j) {
                    int cid = j * 256 + tid;
                    int row = cid >> 4, ch = cid & 15;
                    *(us8*)&Asmem[cur ^ 1][row * SA + ch * 8] = rga[j];
                }
            }
            if (h == NH - 1) {
                constexpr int CPR = (FT * EB) / 16;    // 16B chunks per C row
                constexpr int CPT = (64 * CPR) / 256;  // chunks per thread
                u8* C8 = (u8*)Cv;
                #pragma unroll
                for (int j = 0; j < CPT; ++j) {
                    int cid = j * 256 + tid;
                    int crow = cid / CPR;
                    int cb = (cid % CPR) * 16;
                    int grow = row0g + crow;
                    if (grow < M) {
                        us8 vv = *(const us8*)&Cs8[crow * SCB + cb];
                        *(us8*)(C8 + (size_t)grow * Ftot * EB + (size_t)col0 * EB + cb) = vv;
                    }
                }
            }
            if (gm + 2 < NM) {
                int g2 = gm + 2;
                int gt2 = g2 / NH, h2 = g2 % NH;
                int r0 = (blockIdx.x + gt2 * gridDim.x) * 64;
                #pragma unroll
                for (int j = 0; j < 4; ++j) {
                    int cid = j * 256 + tid;
                    int row = cid >> 4, ch = cid & 15;
                    int gr = r0 + row; if (gr > M - 1) gr = M - 1;
                    rga[j] = *(const us8*)(A + (size_t)gr * K + h2 * BK + ch * 8);
                }
            }
            __syncthreads();
            cur ^= 1; ++gm;
        }
    }
}

// ---------------- Aggregation ----------------
// agg_x: F=128 bf16. 32 lanes/node, lane owns 4 features. 8-edge unroll.
__global__ __launch_bounds__(256) void agg_x(const u16* __restrict__ in,
                                             u16* __restrict__ outp,
                                             const int* __restrict__ row_ptr,
                                             const int* __restrict__ csr_src,
                                             const float* __restrict__ dinv,
                                             int nnodes) {
    int tid = threadIdx.x;
    int wv = tid >> 6, lane = tid & 63;
    int half = lane >> 5, l32 = lane & 31;
    int node = (blockIdx.x * 4 + wv) * 2 + half;
    if (node >= nnodes) return;
    int off = l32 * 4;
    const u16* bp = in + off;
    us4 su = *(const us4*)(in + (size_t)node * 128 + off);
    float a0 = bf2f(su.x), a1 = bf2f(su.y), a2 = bf2f(su.z), a3 = bf2f(su.w);
    int e = row_ptr[node], e1 = row_ptr[node + 1];
    for (; e + 8 <= e1; e += 8) {
        int sx[8];
        #pragma unroll
        for (int q = 0; q < 8; ++q) sx[q] = csr_src[e + q];
        us4 vv[8];
        #pragma unroll
        for (int q = 0; q < 8; ++q) vv[q] = *(const us4*)(bp + (size_t)sx[q] * 128);
        #pragma unroll
        for (int q = 0; q < 8; ++q) {
            a0 += bf2f(vv[q].x); a1 += bf2f(vv[q].y);
            a2 += bf2f(vv[q].z); a3 += bf2f(vv[q].w);
        }
    }
    for (; e < e1; ++e) {
        int s0 = csr_src[e];
        us4 v0 = *(const us4*)(bp + (size_t)s0 * 128);
        a0 += bf2f(v0.x); a1 += bf2f(v0.y);
        a2 += bf2f(v0.z); a3 += bf2f(v0.w);
    }
    float d = dinv[node];
    us4 o;
    o.x = f2bf(a0 * d); o.y = f2bf(a1 * d); o.z = f2bf(a2 * d); o.w = f2bf(a3 * d);
    *(us4*)(outp + (size_t)node * 128 + off) = o;
}

// agg_h: F=256 fp8 in, bf16 out. 32 lanes/node, lane owns 8 features (8B).
__global__ __launch_bounds__(256) void agg_h(const u8* __restrict__ in,
                                             u16* __restrict__ outp,
                                             const int* __restrict__ row_ptr,
                                             const int* __restrict__ csr_src,
                                             const float* __restrict__ dinv,
                                             int nnodes) {
    int tid = threadIdx.x;
    int wv = tid >> 6, lane = tid & 63;
    int half = lane >> 5, l32 = lane & 31;
    int node = (blockIdx.x * 4 + wv) * 2 + half;
    if (node >= nnodes) return;
    int off = l32 * 8;   // byte offset, 8 fp8 features per lane
    const u8* bp = in + off;
    float acc[8];
    {
        uint2 q = *(const uint2*)(in + (size_t)node * 256 + off);
        f32x2 p;
        p = __builtin_amdgcn_cvt_pk_f32_fp8(q.x, false); acc[0] = p[0]; acc[1] = p[1];
        p = __builtin_amdgcn_cvt_pk_f32_fp8(q.x, true);  acc[2] = p[0]; acc[3] = p[1];
        p = __builtin_amdgcn_cvt_pk_f32_fp8(q.y, false); acc[4] = p[0]; acc[5] = p[1];
        p = __builtin_amdgcn_cvt_pk_f32_fp8(q.y, true);  acc[6] = p[0]; acc[7] = p[1];
    }
    int e = row_ptr[node], e1 = row_ptr[node + 1];
    for (; e + 8 <= e1; e += 8) {
        int sx[8];
        #pragma unroll
        for (int q = 0; q < 8; ++q) sx[q] = csr_src[e + q];
        uint2 vv[8];
        #pragma unroll
        for (int q = 0; q < 8; ++q) vv[q] = *(const uint2*)(bp + (size_t)sx[q] * 256);
        #pragma unroll
        for (int q = 0; q < 8; ++q) {
            f32x2 p;
            p = __builtin_amdgcn_cvt_pk_f32_fp8(vv[q].x, false); acc[0] += p[0]; acc[1] += p[1];
            p = __builtin_amdgcn_cvt_pk_f32_fp8(vv[q].x, true);  acc[2] += p[0]; acc[3] += p[1];
            p = __builtin_amdgcn_cvt_pk_f32_fp8(vv[q].y, false); acc[4] += p[0]; acc[5] += p[1];
            p = __builtin_amdgcn_cvt_pk_f32_fp8(vv[q].y, true);  acc[6] += p[0]; acc[7] += p[1];
        }
    }
    for (; e < e1; ++e) {
        int s0 = csr_src[e];
        uint2 v0 = *(const uint2*)(bp + (size_t)s0 * 256);
        f32x2 p;
        p = __builtin_amdgcn_cvt_pk_f32_fp8(v0.x, false); acc[0] += p[0]; acc[1] += p[1];
        p = __builtin_amdgcn_cvt_pk_f32_fp8(v0.x, true);  acc[2] += p[0]; acc[3] += p[1];
        p = __builtin_amdgcn_cvt_pk_f32_fp8(v0.y, false); acc[4] += p[0]; acc[5] += p[1];
        p = __builtin_amdgcn_cvt_pk_f32_fp8(v0.y, true);  acc[6] += p[0]; acc[7] += p[1];
    }
    float d = dinv[node];
    us8 o;
    #pragma unroll
    for (int j = 0; j < 8; ++j) o[j] = f2bf(acc[j] * d);
    *(us8*)(outp + (size_t)node * 256 + off) = o;
}

// agg32: F=32 bf16 in, f32 sigmoid out. 32 lanes/node, 2 nodes/wave.
__global__ __launch_bounds__(256) void agg32_sig(const u16* __restrict__ z,
                                                 float* __restrict__ out,
                                                 const int* __restrict__ row_ptr,
                                                 const int* __restrict__ csr_src,
                                                 const float* __restrict__ dinv,
                                                 const float* __restrict__ b3,
                                                 int nnodes) {
    int tid = threadIdx.x;
    int wv = tid >> 6, lane = tid & 63;
    int half = lane >> 5, l32 = lane & 31;
    int node = (blockIdx.x * 4 + wv) * 2 + half;
    if (node >= nnodes) return;
    float acc = bf2f(z[(size_t)node * 32 + l32]);
    int e = row_ptr[node], e1 = row_ptr[node + 1];
    for (; e + 4 <= e1; e += 4) {
        int s0 = csr_src[e], s1 = csr_src[e + 1], s2 = csr_src[e + 2], s3 = csr_src[e + 3];
        float z0 = bf2f(z[(size_t)s0 * 32 + l32]);
        float z1 = bf2f(z[(size_t)s1 * 32 + l32]);
        float z2 = bf2f(z[(size_t)s2 * 32 + l32]);
        float z3v = bf2f(z[(size_t)s3 * 32 + l32]);
        acc += z0 + z1 + z2 + z3v;
    }
    for (; e < e1; ++e) {
        acc += bf2f(z[(size_t)csr_src[e] * 32 + l32]);
    }
    acc = acc * dinv[node] + b3[l32];
    out[(size_t)node * 32 + l32] = 1.f / (1.f + expf(-acc));
}

// ---------------- launch ----------------

extern "C" void kernel_launch(void* const* d_in, const int* in_sizes, int n_in,
                              void* d_out, int out_size, void* d_ws, size_t ws_size,
                              hipStream_t stream) {
    const float* x  = (const float*)d_in[0];
    const int*   ei = (const int*)d_in[1];
    const float* W1 = (const float*)d_in[2];
    const float* b1 = (const float*)d_in[3];
    const float* g1 = (const float*)d_in[4];
    const float* be1 = (const float*)d_in[5];
    const float* m1 = (const float*)d_in[6];
    const float* v1 = (const float*)d_in[7];
    const float* W2 = (const float*)d_in[8];
    const float* b2 = (const float*)d_in[9];
    const float* g2 = (const float*)d_in[10];
    const float* be2 = (const float*)d_in[11];
    const float* m2 = (const float*)d_in[12];
    const float* v2 = (const float*)d_in[13];
    const float* W3 = (const float*)d_in[14];
    const float* b3 = (const float*)d_in[15];
    float* out = (float*)d_out;

    const int N = in_sizes[0] / 128;   // 100000
    const int E = in_sizes[1] / 2;     // 1600000

    char* w = (char*)d_ws;
    auto alloc = [&](size_t bytes) -> void* {
        void* p = (void*)w;
        w += (bytes + 255) & ~(size_t)255;
        return p;
    };
    int* cnt      = (int*)alloc((size_t)N * 4);
    int* row_ptr  = (int*)alloc((size_t)(N + 1) * 4);
    int* lo       = (int*)alloc((size_t)E * 4);
    float* dinv   = (float*)alloc((size_t)N * 4);
    int* partials = (int*)alloc(256 * 4);
    int* blkoff   = (int*)alloc(256 * 4);
    float* s1 = (float*)alloc(256 * 4);
    float* t1 = (float*)alloc(256 * 4);
    float* s2 = (float*)alloc(256 * 4);
    float* t2 = (float*)alloc(256 * 4);
    u16* Wt1 = (u16*)alloc((size_t)128 * 256 * 2);
    u16* Wt2 = (u16*)alloc((size_t)256 * 256 * 2);
    u16* Wt3 = (u16*)alloc((size_t)256 * 32 * 2);
    int* csr_src = (int*)alloc((size_t)E * 4);
    u16* xbf  = (u16*)alloc((size_t)N * 128 * 2);   // x*dinv bf16; later reused as z3
    u16* bufA = (u16*)alloc((size_t)N * 256 * 2);   // agg outputs (bf16)
    u16* bufB = (u16*)alloc((size_t)N * 256 * 2);   // h2s (bf16)
    u8*  h1q  = (u8*)alloc((size_t)N * 256);        // h1s fp8
    u16* z3 = xbf;   // N*32 bf16, xbf dead after layer 1

    int nb = (N + 511) / 512;
    int nT = (N + 63) / 64;
    int gagg = (N + 7) / 8;
    int ge4 = (E / 4 + 255) / 256;

    // CSR build: one atomic pass + scan + atomic-free placement
    k_zero_int<<<(N + 255) / 256, 256, 0, stream>>>(cnt, N);
    k_count_loc<<<ge4, 256, 0, stream>>>(ei, cnt, lo, E);
    k_partial<<<nb, 256, 0, stream>>>(cnt, partials, N);
    k_scan_top<<<1, 256, 0, stream>>>(partials, blkoff, nb);
    k_apply<<<nb, 512, 0, stream>>>(cnt, blkoff, row_ptr, dinv, N, E);
    k_place<<<ge4, 256, 0, stream>>>(ei, row_ptr, lo, csr_src, E);

    // param prep
    k_bnfold<<<1, 256, 0, stream>>>(b1, g1, be1, m1, v1, s1, t1, 256);
    k_bnfold<<<1, 256, 0, stream>>>(b2, g2, be2, m2, v2, s2, t2, 256);
    k_w2bf<<<(128 * 256 + 255) / 256, 256, 0, stream>>>(W1, Wt1, 128, 256);
    k_w2bf<<<(256 * 256 + 255) / 256, 256, 0, stream>>>(W2, Wt2, 256, 256);
    k_w2bf<<<(256 * 32 + 255) / 256, 256, 0, stream>>>(W3, Wt3, 256, 32);
    k_x2bf<<<(N * 128 / 4 + 255) / 256, 256, 0, stream>>>(x, xbf, dinv, N * 128 / 4);

    // Layer 1: agg(xs,128) -> GEMM(128->256)+BN+ReLU+dinv -> fp8 h1q
    agg_x<<<gagg, 256, 0, stream>>>(xbf, bufA, row_ptr, csr_src, dinv, N);
    g_mfma_lds<128, 64, 3, 2><<<dim3(128, 4), 256, 0, stream>>>(
        bufA, Wt1, (void*)h1q, N, 256, s1, t1, dinv, nT);

    // Layer 2: agg(h1q fp8,256) -> bf16 bufA -> GEMM(256->256)+BN+ReLU+dinv -> bf16
    agg_h<<<gagg, 256, 0, stream>>>(h1q, bufA, row_ptr, csr_src, dinv, N);
    g_mfma_lds<256, 64, 1, 2><<<dim3(128, 4), 256, 0, stream>>>(
        bufA, Wt2, (void*)bufB, N, 256, s2, t2, dinv, nT);

    // Layer 3: GEMM(256->32) -> bf16 z3, then agg + b3 + sigmoid
    g_mfma_lds<256, 32, 2, 2><<<dim3(512, 1), 256, 0, stream>>>(
        bufB, Wt3, (void*)z3, N, 32, (const float*)nullptr, (const float*)nullptr,
        (const float*)nullptr, nT);
    agg32_sig<<<gagg, 256, 0, stream>>>(z3, out, row_ptr, csr_src, dinv, b3, N);
}

// Round 11
// 347.787 us; speedup vs baseline: 1.2557x; 1.0578x over previous
//
#include <hip/hip_runtime.h>
#include <math.h>

typedef unsigned short u16;
typedef unsigned char u8;
typedef __attribute__((ext_vector_type(8))) __bf16 bfx8;
typedef __attribute__((ext_vector_type(4))) float f32x4;
typedef __attribute__((ext_vector_type(2))) float f32x2;
typedef __attribute__((ext_vector_type(8))) unsigned short us8;
typedef __attribute__((ext_vector_type(4))) unsigned short us4;

__device__ inline float bf2f(u16 u) {
    union { unsigned int i; float f; } v;
    v.i = ((unsigned int)u) << 16;
    return v.f;
}
__device__ inline u16 f2bf(float f) {
    union { float f; unsigned int i; } v;
    v.f = f;
    unsigned int b = v.i;
    return (u16)((b + 0x7FFFu + ((b >> 16) & 1u)) >> 16);
}

// ---------------- CSR build ----------------

__global__ void k_zero_int(int* __restrict__ p, int n) {
    int i = blockIdx.x * blockDim.x + threadIdx.x;
    if (i < n) p[i] = 0;
}

__global__ __launch_bounds__(256) void k_count_loc(const int* __restrict__ ei,
                                                   int* __restrict__ cnt,
                                                   int* __restrict__ lo, int E) {
    int base = (blockIdx.x * blockDim.x + threadIdx.x) * 4;
    if (base + 4 <= E) {
        int4 d = *(const int4*)(ei + E + base);
        int l0 = atomicAdd(&cnt[d.x], 1);
        int l1 = atomicAdd(&cnt[d.y], 1);
        int l2 = atomicAdd(&cnt[d.z], 1);
        int l3 = atomicAdd(&cnt[d.w], 1);
        *(int4*)(lo + base) = make_int4(l0, l1, l2, l3);
    } else {
        for (int e = base; e < E; ++e) {
            lo[e] = atomicAdd(&cnt[ei[E + e]], 1);
        }
    }
}

__global__ __launch_bounds__(256) void k_partial(const int* __restrict__ cnt,
                                                 int* __restrict__ partials, int n) {
    __shared__ int sdata[256];
    int base = blockIdx.x * 512;
    int t = threadIdx.x;
    int v = 0;
    if (base + t < n) v += cnt[base + t];
    if (base + 256 + t < n) v += cnt[base + 256 + t];
    sdata[t] = v;
    __syncthreads();
    for (int s = 128; s > 0; s >>= 1) {
        if (t < s) sdata[t] += sdata[t + s];
        __syncthreads();
    }
    if (t == 0) partials[blockIdx.x] = sdata[0];
}

__global__ __launch_bounds__(256) void k_scan_top(const int* __restrict__ partials,
                                                  int* __restrict__ blkoff, int nb) {
    __shared__ int lds[256];
    int t = threadIdx.x;
    int v = (t < nb) ? partials[t] : 0;
    lds[t] = v;
    __syncthreads();
    for (int off = 1; off < 256; off <<= 1) {
        int x = lds[t];
        int y = (t >= off) ? lds[t - off] : 0;
        __syncthreads();
        lds[t] = x + y;
        __syncthreads();
    }
    if (t < nb) blkoff[t] = lds[t] - v;   // exclusive
}

__global__ __launch_bounds__(512) void k_apply(const int* __restrict__ cnt,
                                               const int* __restrict__ blkoff,
                                               int* __restrict__ row_ptr,
                                               float* __restrict__ dinv,
                                               int n, int Etot) {
    __shared__ int lds[512];
    int b = blockIdx.x, t = threadIdx.x;
    int i = b * 512 + t;
    int v = (i < n) ? cnt[i] : 0;
    lds[t] = v;
    __syncthreads();
    for (int off = 1; off < 512; off <<= 1) {
        int x = lds[t];
        int y = (t >= off) ? lds[t - off] : 0;
        __syncthreads();
        lds[t] = x + y;
        __syncthreads();
    }
    if (i < n) {
        int excl = blkoff[b] + lds[t] - v;
        row_ptr[i] = excl;
        dinv[i] = rsqrtf((float)v + 1.0f);
    }
    if (i == 0) row_ptr[n] = Etot;
}

__global__ __launch_bounds__(256) void k_place(const int* __restrict__ ei,
                                               const int* __restrict__ row_ptr,
                                               const int* __restrict__ lo,
                                               int* __restrict__ csr_src, int E) {
    int base = (blockIdx.x * blockDim.x + threadIdx.x) * 4;
    if (base + 4 <= E) {
        int4 s = *(const int4*)(ei + base);
        int4 d = *(const int4*)(ei + E + base);
        int4 l = *(const int4*)(lo + base);
        int p0 = row_ptr[d.x] + l.x;
        int p1 = row_ptr[d.y] + l.y;
        int p2 = row_ptr[d.z] + l.z;
        int p3 = row_ptr[d.w] + l.w;
        csr_src[p0] = s.x;
        csr_src[p1] = s.y;
        csr_src[p2] = s.z;
        csr_src[p3] = s.w;
    } else {
        for (int e = base; e < E; ++e) {
            csr_src[row_ptr[ei[E + e]] + lo[e]] = ei[e];
        }
    }
}

// ---------------- small converts ----------------

__global__ void k_bnfold(const float* __restrict__ b, const float* __restrict__ g,
                         const float* __restrict__ be, const float* __restrict__ m,
                         const float* __restrict__ v, float* __restrict__ s,
                         float* __restrict__ t, int H) {
    int i = blockIdx.x * blockDim.x + threadIdx.x;
    if (i < H) {
        float sc = g[i] * rsqrtf(v[i] + 1e-5f);
        s[i] = sc;
        t[i] = (b[i] - m[i]) * sc + be[i];
    }
}

// W[K,F] f32 -> Wt[F,K] bf16
__global__ void k_w2bf(const float* __restrict__ W, u16* __restrict__ Wt, int K, int F) {
    int i = blockIdx.x * blockDim.x + threadIdx.x;
    if (i < K * F) {
        int k = i / F, f = i % F;
        Wt[(size_t)f * K + k] = f2bf(W[i]);
    }
}

// x f32 -> fp8(e4m3) pre-scaled by dinv[row]  (row = i4/32 for F=128)
__global__ void k_x2f8(const float* __restrict__ x, u8* __restrict__ xq,
                       const float* __restrict__ dinv, int n4) {
    int i = blockIdx.x * blockDim.x + threadIdx.x;
    if (i < n4) {
        float d = dinv[i >> 5];
        float4 v = *(const float4*)(x + (size_t)i * 4);
        unsigned int pk = 0;
        pk = __builtin_amdgcn_cvt_pk_fp8_f32(v.x * d, v.y * d, pk, false);
        pk = __builtin_amdgcn_cvt_pk_fp8_f32(v.z * d, v.w * d, pk, true);
        *(unsigned int*)(xq + (size_t)i * 4) = pk;
    }
}

// ---------------- MFMA GEMM: persistent blocks, B in registers, A via LDS ---
// MODE 1: BN+ReLU then * dinv[row], bf16 store.
// MODE 2: plain bf16 store.
// MODE 3: BN+ReLU then * dinv[row], fp8(e4m3 HW cvt) store.
template<int K, int FT, int MODE, int MINW>
__global__ __launch_bounds__(256, MINW) void g_mfma_lds(
    const u16* __restrict__ A, const u16* __restrict__ Wt,
    void* __restrict__ Cv, int M, int Ftot,
    const float* __restrict__ s, const float* __restrict__ t,
    const float* __restrict__ dinv, int nTiles)
{
    constexpr int BK  = 128;
    constexpr int SA  = BK + 8;
    constexpr int NH  = K / BK;
    constexpr int NKH = BK / 32;
    constexpr int NF  = FT / 16;
    constexpr int EB  = (MODE == 3) ? 1 : 2;       // bytes per C element
    constexpr int SCB = FT * EB + 16;              // padded C row stride (bytes)

    __shared__ u16 Asmem[2][64 * SA];
    __shared__ u8  Cs8[64 * SCB];

    int tid = threadIdx.x;
    int w = tid >> 6, l = tid & 63;
    int lr = l & 15, koff8 = (l >> 4) * 8;
    int col0 = blockIdx.y * FT;

    bfx8 bfr[NH][NKH][NF];
    {
        const u16* wp = Wt + (size_t)(col0 + lr) * K + koff8;
        #pragma unroll
        for (int h = 0; h < NH; ++h)
            #pragma unroll
            for (int kk = 0; kk < NKH; ++kk)
                #pragma unroll
                for (int c = 0; c < NF; ++c)
                    bfr[h][kk][c] = *(const bfx8*)(wp + (size_t)c * 16 * K + h * BK + kk * 32);
    }

    int myT = (blockIdx.x < nTiles) ? ((nTiles - 1 - (int)blockIdx.x) / (int)gridDim.x + 1) : 0;
    int NM = myT * NH;
    if (NM == 0) return;

    f32x4 acc[NF];
    #pragma unroll
    for (int c = 0; c < NF; ++c) acc[c] = (f32x4){0.f, 0.f, 0.f, 0.f};

    us8 rga[4];

    {
        int row0 = blockIdx.x * 64;
        #pragma unroll
        for (int j = 0; j < 4; ++j) {
            int cid = j * 256 + tid;
            int row = cid >> 4, ch = cid & 15;
            int gr = row0 + row; if (gr > M - 1) gr = M - 1;
            rga[j] = *(const us8*)(A + (size_t)gr * K + 0 * BK + ch * 8);
        }
        #pragma unroll
        for (int j = 0; j < 4; ++j) {
            int cid = j * 256 + tid;
            int row = cid >> 4, ch = cid & 15;
            *(us8*)&Asmem[0][row * SA + ch * 8] = rga[j];
        }
        if (NM > 1) {
            constexpr int gt1 = 1 / NH, h1 = 1 % NH;
            int r0 = (blockIdx.x + gt1 * gridDim.x) * 64;
            #pragma unroll
            for (int j = 0; j < 4; ++j) {
                int cid = j * 256 + tid;
                int row = cid >> 4, ch = cid & 15;
                int gr = r0 + row; if (gr > M - 1) gr = M - 1;
                rga[j] = *(const us8*)(A + (size_t)gr * K + h1 * BK + ch * 8);
            }
        }
    }
    __syncthreads();

    int cur = 0, gm = 0;
    for (int ti = 0; ti < myT; ++ti) {
        int row0g = (blockIdx.x + ti * gridDim.x) * 64;
        #pragma unroll
        for (int h = 0; h < NH; ++h) {
            const u16* ab = &Asmem[cur][0];
            #pragma unroll
            for (int kk = 0; kk < NKH; ++kk) {
                bfx8 af = *(const bfx8*)(ab + (w * 16 + lr) * SA + koff8 + kk * 32);
                #pragma unroll
                for (int c = 0; c < NF; ++c)
                    acc[c] = __builtin_amdgcn_mfma_f32_16x16x32_bf16(af, bfr[h][kk][c], acc[c], 0, 0, 0);
            }
            if (h == NH - 1) {
                int orow = w * 16 + (l >> 4) * 4;
                float dr[4];
                #pragma unroll
                for (int r = 0; r < 4; ++r) {
                    int grow = row0g + orow + r;
                    dr[r] = (MODE == 2) ? 1.f : ((grow < M) ? dinv[grow] : 0.f);
                }
                #pragma unroll
                for (int c = 0; c < NF; ++c) {
                    int gc = col0 + c * 16 + lr;
                    float sc = (MODE == 2) ? 0.f : s[gc];
                    float tc = (MODE == 2) ? 0.f : t[gc];
                    #pragma unroll
                    for (int r = 0; r < 4; ++r) {
                        float v = acc[c][r];
                        if (MODE != 2) v = fmaxf(v * sc + tc, 0.f) * dr[r];
                        if (MODE == 3) {
                            int enc = __builtin_amdgcn_cvt_pk_fp8_f32(v, v, 0, false);
                            Cs8[(orow + r) * SCB + (c * 16 + lr)] = (u8)(enc & 0xff);
                        } else {
                            *(u16*)&Cs8[(orow + r) * SCB + (c * 16 + lr) * 2] = f2bf(v);
                        }
                    }
                    acc[c] = (f32x4){0.f, 0.f, 0.f, 0.f};
                }
            }
            __syncthreads();
            if (gm + 1 < NM) {
                #pragma unroll
                for (int j = 0; j < 4; ++j) {
                    int cid = j * 256 + tid;
                    int row = cid >> 4, ch = cid & 15;
                    *(us8*)&Asmem[cur ^ 1][row * SA + ch * 8] = rga[j];
                }
            }
            if (h == NH - 1) {
                constexpr int CPR = (FT * EB) / 16;
                constexpr int CPT = (64 * CPR) / 256;
                u8* C8 = (u8*)Cv;
                #pragma unroll
                for (int j = 0; j < CPT; ++j) {
                    int cid = j * 256 + tid;
                    int crow = cid / CPR;
                    int cb = (cid % CPR) * 16;
                    int grow = row0g + crow;
                    if (grow < M) {
                        us8 vv = *(const us8*)&Cs8[crow * SCB + cb];
                        *(us8*)(C8 + (size_t)grow * Ftot * EB + (size_t)col0 * EB + cb) = vv;
                    }
                }
            }
            if (gm + 2 < NM) {
                int g2 = gm + 2;
                int gt2 = g2 / NH, h2 = g2 % NH;
                int r0 = (blockIdx.x + gt2 * gridDim.x) * 64;
                #pragma unroll
                for (int j = 0; j < 4; ++j) {
                    int cid = j * 256 + tid;
                    int row = cid >> 4, ch = cid & 15;
                    int gr = r0 + row; if (gr > M - 1) gr = M - 1;
                    rga[j] = *(const us8*)(A + (size_t)gr * K + h2 * BK + ch * 8);
                }
            }
            __syncthreads();
            cur ^= 1; ++gm;
        }
    }
}

// ---------------- Aggregation ----------------
// agg_x: F=128 fp8 in, bf16 out. 32 lanes/node, lane owns 4 fp8 (4B). 8-edge unroll.
__global__ __launch_bounds__(256) void agg_x(const u8* __restrict__ in,
                                             u16* __restrict__ outp,
                                             const int* __restrict__ row_ptr,
                                             const int* __restrict__ csr_src,
                                             const float* __restrict__ dinv,
                                             int nnodes) {
    int tid = threadIdx.x;
    int wv = tid >> 6, lane = tid & 63;
    int half = lane >> 5, l32 = lane & 31;
    int node = (blockIdx.x * 4 + wv) * 2 + half;
    if (node >= nnodes) return;
    int off = l32 * 4;   // byte offset, 4 fp8 features per lane
    const u8* bp = in + off;
    float a0, a1, a2, a3;
    {
        unsigned int q = *(const unsigned int*)(in + (size_t)node * 128 + off);
        f32x2 p;
        p = __builtin_amdgcn_cvt_pk_f32_fp8(q, false); a0 = p[0]; a1 = p[1];
        p = __builtin_amdgcn_cvt_pk_f32_fp8(q, true);  a2 = p[0]; a3 = p[1];
    }
    int e = row_ptr[node], e1 = row_ptr[node + 1];
    for (; e + 8 <= e1; e += 8) {
        int sx[8];
        #pragma unroll
        for (int q = 0; q < 8; ++q) sx[q] = csr_src[e + q];
        unsigned int vv[8];
        #pragma unroll
        for (int q = 0; q < 8; ++q) vv[q] = *(const unsigned int*)(bp + (size_t)sx[q] * 128);
        #pragma unroll
        for (int q = 0; q < 8; ++q) {
            f32x2 p;
            p = __builtin_amdgcn_cvt_pk_f32_fp8(vv[q], false); a0 += p[0]; a1 += p[1];
            p = __builtin_amdgcn_cvt_pk_f32_fp8(vv[q], true);  a2 += p[0]; a3 += p[1];
        }
    }
    for (; e < e1; ++e) {
        int s0 = csr_src[e];
        unsigned int v0 = *(const unsigned int*)(bp + (size_t)s0 * 128);
        f32x2 p;
        p = __builtin_amdgcn_cvt_pk_f32_fp8(v0, false); a0 += p[0]; a1 += p[1];
        p = __builtin_amdgcn_cvt_pk_f32_fp8(v0, true);  a2 += p[0]; a3 += p[1];
    }
    float d = dinv[node];
    us4 o;
    o.x = f2bf(a0 * d); o.y = f2bf(a1 * d); o.z = f2bf(a2 * d); o.w = f2bf(a3 * d);
    *(us4*)(outp + (size_t)node * 128 + off * 0 + l32 * 4) = o;
}

// agg_h: F=256 fp8 in, bf16 out. 32 lanes/node, lane owns 8 features (8B).
__global__ __launch_bounds__(256) void agg_h(const u8* __restrict__ in,
                                             u16* __restrict__ outp,
                                             const int* __restrict__ row_ptr,
                                             const int* __restrict__ csr_src,
                                             const float* __restrict__ dinv,
                                             int nnodes) {
    int tid = threadIdx.x;
    int wv = tid >> 6, lane = tid & 63;
    int half = lane >> 5, l32 = lane & 31;
    int node = (blockIdx.x * 4 + wv) * 2 + half;
    if (node >= nnodes) return;
    int off = l32 * 8;
    const u8* bp = in + off;
    float acc[8];
    {
        uint2 q = *(const uint2*)(in + (size_t)node * 256 + off);
        f32x2 p;
        p = __builtin_amdgcn_cvt_pk_f32_fp8(q.x, false); acc[0] = p[0]; acc[1] = p[1];
        p = __builtin_amdgcn_cvt_pk_f32_fp8(q.x, true);  acc[2] = p[0]; acc[3] = p[1];
        p = __builtin_amdgcn_cvt_pk_f32_fp8(q.y, false); acc[4] = p[0]; acc[5] = p[1];
        p = __builtin_amdgcn_cvt_pk_f32_fp8(q.y, true);  acc[6] = p[0]; acc[7] = p[1];
    }
    int e = row_ptr[node], e1 = row_ptr[node + 1];
    for (; e + 8 <= e1; e += 8) {
        int sx[8];
        #pragma unroll
        for (int q = 0; q < 8; ++q) sx[q] = csr_src[e + q];
        uint2 vv[8];
        #pragma unroll
        for (int q = 0; q < 8; ++q) vv[q] = *(const uint2*)(bp + (size_t)sx[q] * 256);
        #pragma unroll
        for (int q = 0; q < 8; ++q) {
            f32x2 p;
            p = __builtin_amdgcn_cvt_pk_f32_fp8(vv[q].x, false); acc[0] += p[0]; acc[1] += p[1];
            p = __builtin_amdgcn_cvt_pk_f32_fp8(vv[q].x, true);  acc[2] += p[0]; acc[3] += p[1];
            p = __builtin_amdgcn_cvt_pk_f32_fp8(vv[q].y, false); acc[4] += p[0]; acc[5] += p[1];
            p = __builtin_amdgcn_cvt_pk_f32_fp8(vv[q].y, true);  acc[6] += p[0]; acc[7] += p[1];
        }
    }
    for (; e < e1; ++e) {
        int s0 = csr_src[e];
        uint2 v0 = *(const uint2*)(bp + (size_t)s0 * 256);
        f32x2 p;
        p = __builtin_amdgcn_cvt_pk_f32_fp8(v0.x, false); acc[0] += p[0]; acc[1] += p[1];
        p = __builtin_amdgcn_cvt_pk_f32_fp8(v0.x, true);  acc[2] += p[0]; acc[3] += p[1];
        p = __builtin_amdgcn_cvt_pk_f32_fp8(v0.y, false); acc[4] += p[0]; acc[5] += p[1];
        p = __builtin_amdgcn_cvt_pk_f32_fp8(v0.y, true);  acc[6] += p[0]; acc[7] += p[1];
    }
    float d = dinv[node];
    us8 o;
    #pragma unroll
    for (int j = 0; j < 8; ++j) o[j] = f2bf(acc[j] * d);
    *(us8*)(outp + (size_t)node * 256 + off) = o;
}

// agg32: F=32 bf16 in, f32 sigmoid out. 32 lanes/node, 2 nodes/wave.
__global__ __launch_bounds__(256) void agg32_sig(const u16* __restrict__ z,
                                                 float* __restrict__ out,
                                                 const int* __restrict__ row_ptr,
                                                 const int* __restrict__ csr_src,
                                                 const float* __restrict__ dinv,
                                                 const float* __restrict__ b3,
                                                 int nnodes) {
    int tid = threadIdx.x;
    int wv = tid >> 6, lane = tid & 63;
    int half = lane >> 5, l32 = lane & 31;
    int node = (blockIdx.x * 4 + wv) * 2 + half;
    if (node >= nnodes) return;
    float acc = bf2f(z[(size_t)node * 32 + l32]);
    int e = row_ptr[node], e1 = row_ptr[node + 1];
    for (; e + 4 <= e1; e += 4) {
        int s0 = csr_src[e], s1 = csr_src[e + 1], s2 = csr_src[e + 2], s3 = csr_src[e + 3];
        float z0 = bf2f(z[(size_t)s0 * 32 + l32]);
        float z1 = bf2f(z[(size_t)s1 * 32 + l32]);
        float z2 = bf2f(z[(size_t)s2 * 32 + l32]);
        float z3v = bf2f(z[(size_t)s3 * 32 + l32]);
        acc += z0 + z1 + z2 + z3v;
    }
    for (; e < e1; ++e) {
        acc += bf2f(z[(size_t)csr_src[e] * 32 + l32]);
    }
    acc = acc * dinv[node] + b3[l32];
    out[(size_t)node * 32 + l32] = 1.f / (1.f + expf(-acc));
}

// ---------------- launch ----------------

extern "C" void kernel_launch(void* const* d_in, const int* in_sizes, int n_in,
                              void* d_out, int out_size, void* d_ws, size_t ws_size,
                              hipStream_t stream) {
    const float* x  = (const float*)d_in[0];
    const int*   ei = (const int*)d_in[1];
    const float* W1 = (const float*)d_in[2];
    const float* b1 = (const float*)d_in[3];
    const float* g1 = (const float*)d_in[4];
    const float* be1 = (const float*)d_in[5];
    const float* m1 = (const float*)d_in[6];
    const float* v1 = (const float*)d_in[7];
    const float* W2 = (const float*)d_in[8];
    const float* b2 = (const float*)d_in[9];
    const float* g2 = (const float*)d_in[10];
    const float* be2 = (const float*)d_in[11];
    const float* m2 = (const float*)d_in[12];
    const float* v2 = (const float*)d_in[13];
    const float* W3 = (const float*)d_in[14];
    const float* b3 = (const float*)d_in[15];
    float* out = (float*)d_out;

    const int N = in_sizes[0] / 128;   // 100000
    const int E = in_sizes[1] / 2;     // 1600000

    char* w = (char*)d_ws;
    auto alloc = [&](size_t bytes) -> void* {
        void* p = (void*)w;
        w += (bytes + 255) & ~(size_t)255;
        return p;
    };
    int* cnt      = (int*)alloc((size_t)N * 4);
    int* row_ptr  = (int*)alloc((size_t)(N + 1) * 4);
    int* lo       = (int*)alloc((size_t)E * 4);
    float* dinv   = (float*)alloc((size_t)N * 4);
    int* partials = (int*)alloc(256 * 4);
    int* blkoff   = (int*)alloc(256 * 4);
    float* s1 = (float*)alloc(256 * 4);
    float* t1 = (float*)alloc(256 * 4);
    float* s2 = (float*)alloc(256 * 4);
    float* t2 = (float*)alloc(256 * 4);
    u16* Wt1 = (u16*)alloc((size_t)128 * 256 * 2);
    u16* Wt2 = (u16*)alloc((size_t)256 * 256 * 2);
    u16* Wt3 = (u16*)alloc((size_t)256 * 32 * 2);
    int* csr_src = (int*)alloc((size_t)E * 4);
    u8*  xq   = (u8*)alloc((size_t)N * 128);        // x*dinv fp8; later reused as z3
    u16* bufA = (u16*)alloc((size_t)N * 256 * 2);   // agg outputs (bf16)
    u16* bufB = (u16*)alloc((size_t)N * 256 * 2);   // h2s (bf16)
    u8*  h1q  = (u8*)alloc((size_t)N * 256);        // h1s fp8
    u16* z3 = (u16*)xq;   // N*32 bf16 = 6.4MB <= 12.8MB, xq dead after layer 1

    int nb = (N + 511) / 512;
    int nT = (N + 63) / 64;
    int gagg = (N + 7) / 8;
    int ge4 = (E / 4 + 255) / 256;

    // CSR build: one atomic pass + scan + atomic-free placement
    k_zero_int<<<(N + 255) / 256, 256, 0, stream>>>(cnt, N);
    k_count_loc<<<ge4, 256, 0, stream>>>(ei, cnt, lo, E);
    k_partial<<<nb, 256, 0, stream>>>(cnt, partials, N);
    k_scan_top<<<1, 256, 0, stream>>>(partials, blkoff, nb);
    k_apply<<<nb, 512, 0, stream>>>(cnt, blkoff, row_ptr, dinv, N, E);
    k_place<<<ge4, 256, 0, stream>>>(ei, row_ptr, lo, csr_src, E);

    // param prep
    k_bnfold<<<1, 256, 0, stream>>>(b1, g1, be1, m1, v1, s1, t1, 256);
    k_bnfold<<<1, 256, 0, stream>>>(b2, g2, be2, m2, v2, s2, t2, 256);
    k_w2bf<<<(128 * 256 + 255) / 256, 256, 0, stream>>>(W1, Wt1, 128, 256);
    k_w2bf<<<(256 * 256 + 255) / 256, 256, 0, stream>>>(W2, Wt2, 256, 256);
    k_w2bf<<<(256 * 32 + 255) / 256, 256, 0, stream>>>(W3, Wt3, 256, 32);
    k_x2f8<<<(N * 128 / 4 + 255) / 256, 256, 0, stream>>>(x, xq, dinv, N * 128 / 4);

    // Layer 1: agg(xq fp8,128) -> bf16 -> GEMM(128->256)+BN+ReLU+dinv -> fp8 h1q
    agg_x<<<gagg, 256, 0, stream>>>(xq, bufA, row_ptr, csr_src, dinv, N);
    g_mfma_lds<128, 64, 3, 2><<<dim3(128, 4), 256, 0, stream>>>(
        bufA, Wt1, (void*)h1q, N, 256, s1, t1, dinv, nT);

    // Layer 2: agg(h1q fp8,256) -> bf16 -> GEMM(256->256)+BN+ReLU+dinv -> bf16
    agg_h<<<gagg, 256, 0, stream>>>(h1q, bufA, row_ptr, csr_src, dinv, N);
    g_mfma_lds<256, 64, 1, 2><<<dim3(128, 4), 256, 0, stream>>>(
        bufA, Wt2, (void*)bufB, N, 256, s2, t2, dinv, nT);

    // Layer 3: GEMM(256->32) -> bf16 z3, then agg + b3 + sigmoid
    g_mfma_lds<256, 32, 2, 2><<<dim3(512, 1), 256, 0, stream>>>(
        bufB, Wt3, (void*)z3, N, 32, (const float*)nullptr, (const float*)nullptr,
        (const float*)nullptr, nT);
    agg32_sig<<<gagg, 256, 0, stream>>>(z3, out, row_ptr, csr_src, dinv, b3, N);
}

// Round 12
// 283.514 us; speedup vs baseline: 1.5404x; 1.2267x over previous
//
#include <hip/hip_runtime.h>
#include <math.h>

typedef unsigned short u16;
typedef unsigned char u8;
typedef unsigned int u32;
typedef __attribute__((ext_vector_type(8))) __bf16 bfx8;
typedef __attribute__((ext_vector_type(4))) float f32x4;
typedef __attribute__((ext_vector_type(2))) float f32x2;
typedef __attribute__((ext_vector_type(8))) unsigned short us8;
typedef __attribute__((ext_vector_type(4))) unsigned short us4;

__device__ inline float bf2f(u16 u) {
    union { unsigned int i; float f; } v;
    v.i = ((unsigned int)u) << 16;
    return v.f;
}
__device__ inline u16 f2bf(float f) {
    union { float f; unsigned int i; } v;
    v.f = f;
    unsigned int b = v.i;
    return (u16)((b + 0x7FFFu + ((b >> 16) & 1u)) >> 16);
}

// ---------------- CSR build: bucket sort, LDS atomics only ----------------
// Buckets of W=512 nodes (bucket = dst >> 9). NB = ceil(N/512) <= 256.
// EPB = 2048 edges per histogram block.

// Pass 1: per-block LDS histogram -> cnt_pb[bucket][block] (non-atomic store)
__global__ __launch_bounds__(256) void k_hist(const int* __restrict__ ei,
                                              u32* __restrict__ cnt_pb,
                                              int E, int NB, int NBLK) {
    __shared__ u32 h[256];
    int blk = blockIdx.x, tid = threadIdx.x;
    h[tid] = 0;
    __syncthreads();
    int eend = min(E, (blk + 1) * 2048);
    for (int e = blk * 2048 + tid; e < eend; e += 256) {
        int d = ei[E + e];
        atomicAdd(&h[d >> 9], 1u);
    }
    __syncthreads();
    if (tid < NB) cnt_pb[(size_t)tid * NBLK + blk] = h[tid];
}

// Pass 2: per-bucket exclusive scan over blocks; total per bucket.
__global__ __launch_bounds__(1024) void k_scanb(const u32* __restrict__ cnt_pb,
                                                u32* __restrict__ bases_pb,
                                                u32* __restrict__ bkt_tot,
                                                int NBLK) {
    __shared__ u32 lds[1024];
    int b = blockIdx.x, t = threadIdx.x;
    u32 v = (t < NBLK) ? cnt_pb[(size_t)b * NBLK + t] : 0u;
    lds[t] = v;
    __syncthreads();
    for (int off = 1; off < 1024; off <<= 1) {
        u32 x = lds[t];
        u32 y = (t >= off) ? lds[t - off] : 0u;
        __syncthreads();
        lds[t] = x + y;
        __syncthreads();
    }
    if (t < NBLK) bases_pb[(size_t)b * NBLK + t] = lds[t] - v;
    if (t == NBLK - 1) bkt_tot[b] = lds[t];
}

// Pass 3: exclusive scan of bucket totals -> bkt_base; row_ptr[N] = E.
__global__ __launch_bounds__(256) void k_scant(const u32* __restrict__ bkt_tot,
                                               u32* __restrict__ bkt_base,
                                               int* __restrict__ row_ptr,
                                               int NB, int N, int E) {
    __shared__ u32 lds[256];
    int t = threadIdx.x;
    u32 v = (t < NB) ? bkt_tot[t] : 0u;
    lds[t] = v;
    __syncthreads();
    for (int off = 1; off < 256; off <<= 1) {
        u32 x = lds[t];
        u32 y = (t >= off) ? lds[t - off] : 0u;
        __syncthreads();
        lds[t] = x + y;
        __syncthreads();
    }
    if (t < NB) bkt_base[t] = lds[t] - v;
    if (t == 0) row_ptr[N] = E;
}

// Pass 4: scatter edges into bucket-contiguous regions (packed src|dl<<17).
__global__ __launch_bounds__(256) void k_scatter2(const int* __restrict__ ei,
                                                  const u32* __restrict__ bases_pb,
                                                  const u32* __restrict__ bkt_base,
                                                  u32* __restrict__ bkt_edges,
                                                  int E, int NB, int NBLK) {
    __shared__ u32 cur[256];
    __shared__ u32 bb[256];
    int blk = blockIdx.x, tid = threadIdx.x;
    if (tid < NB) {
        cur[tid] = bases_pb[(size_t)tid * NBLK + blk];
        bb[tid] = bkt_base[tid];
    }
    __syncthreads();
    int eend = min(E, (blk + 1) * 2048);
    for (int e = blk * 2048 + tid; e < eend; e += 256) {
        int s = ei[e];
        int d = ei[E + e];
        int b = d >> 9;
        int dl = d & 511;
        u32 off = atomicAdd(&cur[b], 1u);
        bkt_edges[bb[b] + off] = (u32)s | ((u32)dl << 17);
    }
}

// Pass 5: per-bucket CSR build (count, scan, row_ptr/dinv, place).
__global__ __launch_bounds__(512) void k_bucket(const u32* __restrict__ bkt_edges,
                                                const u32* __restrict__ bkt_base,
                                                const u32* __restrict__ bkt_tot,
                                                int* __restrict__ row_ptr,
                                                float* __restrict__ dinv,
                                                int* __restrict__ csr_src,
                                                int N) {
    __shared__ u32 lcnt[512];
    __shared__ u32 lscan[512];
    int b = blockIdx.x, t = threadIdx.x;
    int node0 = b << 9;
    int es = (int)bkt_base[b];
    int ce = (int)bkt_tot[b];
    lcnt[t] = 0;
    __syncthreads();
    for (int i = t; i < ce; i += 512) {
        u32 p = bkt_edges[es + i];
        atomicAdd(&lcnt[p >> 17], 1u);
    }
    __syncthreads();
    // inclusive scan of lcnt into lscan
    lscan[t] = lcnt[t];
    __syncthreads();
    for (int off = 1; off < 512; off <<= 1) {
        u32 x = lscan[t];
        u32 y = (t >= off) ? lscan[t - off] : 0u;
        __syncthreads();
        lscan[t] = x + y;
        __syncthreads();
    }
    u32 excl = lscan[t] - lcnt[t];
    int node = node0 + t;
    if (node < N) {
        row_ptr[node] = es + (int)excl;
        dinv[node] = rsqrtf((float)lcnt[t] + 1.0f);
    }
    __syncthreads();
    lscan[t] = excl;   // becomes running cursor
    __syncthreads();
    for (int i = t; i < ce; i += 512) {
        u32 p = bkt_edges[es + i];
        int dl = (int)(p >> 17);
        int src = (int)(p & 0x1FFFFu);
        u32 pos = atomicAdd(&lscan[dl], 1u);
        csr_src[es + pos] = src;
    }
}

// ---------------- small converts ----------------

__global__ void k_bnfold(const float* __restrict__ b, const float* __restrict__ g,
                         const float* __restrict__ be, const float* __restrict__ m,
                         const float* __restrict__ v, float* __restrict__ s,
                         float* __restrict__ t, int H) {
    int i = blockIdx.x * blockDim.x + threadIdx.x;
    if (i < H) {
        float sc = g[i] * rsqrtf(v[i] + 1e-5f);
        s[i] = sc;
        t[i] = (b[i] - m[i]) * sc + be[i];
    }
}

// W[K,F] f32 -> Wt[F,K] bf16
__global__ void k_w2bf(const float* __restrict__ W, u16* __restrict__ Wt, int K, int F) {
    int i = blockIdx.x * blockDim.x + threadIdx.x;
    if (i < K * F) {
        int k = i / F, f = i % F;
        Wt[(size_t)f * K + k] = f2bf(W[i]);
    }
}

// x f32 -> fp8(e4m3) pre-scaled by dinv[row]  (row = i4/32 for F=128)
__global__ void k_x2f8(const float* __restrict__ x, u8* __restrict__ xq,
                       const float* __restrict__ dinv, int n4) {
    int i = blockIdx.x * blockDim.x + threadIdx.x;
    if (i < n4) {
        float d = dinv[i >> 5];
        float4 v = *(const float4*)(x + (size_t)i * 4);
        unsigned int pk = 0;
        pk = __builtin_amdgcn_cvt_pk_fp8_f32(v.x * d, v.y * d, pk, false);
        pk = __builtin_amdgcn_cvt_pk_fp8_f32(v.z * d, v.w * d, pk, true);
        *(unsigned int*)(xq + (size_t)i * 4) = pk;
    }
}

// ---------------- MFMA GEMM: persistent blocks, B in registers, A via LDS ---
// MODE 1: BN+ReLU then * dinv[row], bf16 store.
// MODE 2: plain bf16 store.
// MODE 3: BN+ReLU then * dinv[row], fp8(e4m3 HW cvt) store.
template<int K, int FT, int MODE, int MINW>
__global__ __launch_bounds__(256, MINW) void g_mfma_lds(
    const u16* __restrict__ A, const u16* __restrict__ Wt,
    void* __restrict__ Cv, int M, int Ftot,
    const float* __restrict__ s, const float* __restrict__ t,
    const float* __restrict__ dinv, int nTiles)
{
    constexpr int BK  = 128;
    constexpr int SA  = BK + 8;
    constexpr int NH  = K / BK;
    constexpr int NKH = BK / 32;
    constexpr int NF  = FT / 16;
    constexpr int EB  = (MODE == 3) ? 1 : 2;
    constexpr int SCB = FT * EB + 16;

    __shared__ u16 Asmem[2][64 * SA];
    __shared__ u8  Cs8[64 * SCB];

    int tid = threadIdx.x;
    int w = tid >> 6, l = tid & 63;
    int lr = l & 15, koff8 = (l >> 4) * 8;
    int col0 = blockIdx.y * FT;

    bfx8 bfr[NH][NKH][NF];
    {
        const u16* wp = Wt + (size_t)(col0 + lr) * K + koff8;
        #pragma unroll
        for (int h = 0; h < NH; ++h)
            #pragma unroll
            for (int kk = 0; kk < NKH; ++kk)
                #pragma unroll
                for (int c = 0; c < NF; ++c)
                    bfr[h][kk][c] = *(const bfx8*)(wp + (size_t)c * 16 * K + h * BK + kk * 32);
    }

    int myT = (blockIdx.x < nTiles) ? ((nTiles - 1 - (int)blockIdx.x) / (int)gridDim.x + 1) : 0;
    int NM = myT * NH;
    if (NM == 0) return;

    f32x4 acc[NF];
    #pragma unroll
    for (int c = 0; c < NF; ++c) acc[c] = (f32x4){0.f, 0.f, 0.f, 0.f};

    us8 rga[4];

    {
        int row0 = blockIdx.x * 64;
        #pragma unroll
        for (int j = 0; j < 4; ++j) {
            int cid = j * 256 + tid;
            int row = cid >> 4, ch = cid & 15;
            int gr = row0 + row; if (gr > M - 1) gr = M - 1;
            rga[j] = *(const us8*)(A + (size_t)gr * K + 0 * BK + ch * 8);
        }
        #pragma unroll
        for (int j = 0; j < 4; ++j) {
            int cid = j * 256 + tid;
            int row = cid >> 4, ch = cid & 15;
            *(us8*)&Asmem[0][row * SA + ch * 8] = rga[j];
        }
        if (NM > 1) {
            constexpr int gt1 = 1 / NH, h1 = 1 % NH;
            int r0 = (blockIdx.x + gt1 * gridDim.x) * 64;
            #pragma unroll
            for (int j = 0; j < 4; ++j) {
                int cid = j * 256 + tid;
                int row = cid >> 4, ch = cid & 15;
                int gr = r0 + row; if (gr > M - 1) gr = M - 1;
                rga[j] = *(const us8*)(A + (size_t)gr * K + h1 * BK + ch * 8);
            }
        }
    }
    __syncthreads();

    int cur = 0, gm = 0;
    for (int ti = 0; ti < myT; ++ti) {
        int row0g = (blockIdx.x + ti * gridDim.x) * 64;
        #pragma unroll
        for (int h = 0; h < NH; ++h) {
            const u16* ab = &Asmem[cur][0];
            #pragma unroll
            for (int kk = 0; kk < NKH; ++kk) {
                bfx8 af = *(const bfx8*)(ab + (w * 16 + lr) * SA + koff8 + kk * 32);
                #pragma unroll
                for (int c = 0; c < NF; ++c)
                    acc[c] = __builtin_amdgcn_mfma_f32_16x16x32_bf16(af, bfr[h][kk][c], acc[c], 0, 0, 0);
            }
            if (h == NH - 1) {
                int orow = w * 16 + (l >> 4) * 4;
                float dr[4];
                #pragma unroll
                for (int r = 0; r < 4; ++r) {
                    int grow = row0g + orow + r;
                    dr[r] = (MODE == 2) ? 1.f : ((grow < M) ? dinv[grow] : 0.f);
                }
                #pragma unroll
                for (int c = 0; c < NF; ++c) {
                    int gc = col0 + c * 16 + lr;
                    float sc = (MODE == 2) ? 0.f : s[gc];
                    float tc = (MODE == 2) ? 0.f : t[gc];
                    #pragma unroll
                    for (int r = 0; r < 4; ++r) {
                        float v = acc[c][r];
                        if (MODE != 2) v = fmaxf(v * sc + tc, 0.f) * dr[r];
                        if (MODE == 3) {
                            int enc = __builtin_amdgcn_cvt_pk_fp8_f32(v, v, 0, false);
                            Cs8[(orow + r) * SCB + (c * 16 + lr)] = (u8)(enc & 0xff);
                        } else {
                            *(u16*)&Cs8[(orow + r) * SCB + (c * 16 + lr) * 2] = f2bf(v);
                        }
                    }
                    acc[c] = (f32x4){0.f, 0.f, 0.f, 0.f};
                }
            }
            __syncthreads();
            if (gm + 1 < NM) {
                #pragma unroll
                for (int j = 0; j < 4; ++j) {
                    int cid = j * 256 + tid;
                    int row = cid >> 4, ch = cid & 15;
                    *(us8*)&Asmem[cur ^ 1][row * SA + ch * 8] = rga[j];
                }
            }
            if (h == NH - 1) {
                constexpr int CPR = (FT * EB) / 16;
                constexpr int CPT = (64 * CPR) / 256;
                u8* C8 = (u8*)Cv;
                #pragma unroll
                for (int j = 0; j < CPT; ++j) {
                    int cid = j * 256 + tid;
                    int crow = cid / CPR;
                    int cb = (cid % CPR) * 16;
                    int grow = row0g + crow;
                    if (grow < M) {
                        us8 vv = *(const us8*)&Cs8[crow * SCB + cb];
                        *(us8*)(C8 + (size_t)grow * Ftot * EB + (size_t)col0 * EB + cb) = vv;
                    }
                }
            }
            if (gm + 2 < NM) {
                int g2 = gm + 2;
                int gt2 = g2 / NH, h2 = g2 % NH;
                int r0 = (blockIdx.x + gt2 * gridDim.x) * 64;
                #pragma unroll
                for (int j = 0; j < 4; ++j) {
                    int cid = j * 256 + tid;
                    int row = cid >> 4, ch = cid & 15;
                    int gr = r0 + row; if (gr > M - 1) gr = M - 1;
                    rga[j] = *(const us8*)(A + (size_t)gr * K + h2 * BK + ch * 8);
                }
            }
            __syncthreads();
            cur ^= 1; ++gm;
        }
    }
}

// ---------------- Aggregation ----------------
// agg_x: F=128 fp8 in, bf16 out. 32 lanes/node, lane owns 4 fp8. 8-edge unroll.
__global__ __launch_bounds__(256) void agg_x(const u8* __restrict__ in,
                                             u16* __restrict__ outp,
                                             const int* __restrict__ row_ptr,
                                             const int* __restrict__ csr_src,
                                             const float* __restrict__ dinv,
                                             int nnodes) {
    int tid = threadIdx.x;
    int wv = tid >> 6, lane = tid & 63;
    int half = lane >> 5, l32 = lane & 31;
    int node = (blockIdx.x * 4 + wv) * 2 + half;
    if (node >= nnodes) return;
    int off = l32 * 4;
    const u8* bp = in + off;
    float a0, a1, a2, a3;
    {
        unsigned int q = *(const unsigned int*)(in + (size_t)node * 128 + off);
        f32x2 p;
        p = __builtin_amdgcn_cvt_pk_f32_fp8(q, false); a0 = p[0]; a1 = p[1];
        p = __builtin_amdgcn_cvt_pk_f32_fp8(q, true);  a2 = p[0]; a3 = p[1];
    }
    int e = row_ptr[node], e1 = row_ptr[node + 1];
    for (; e + 8 <= e1; e += 8) {
        int sx[8];
        #pragma unroll
        for (int q = 0; q < 8; ++q) sx[q] = csr_src[e + q];
        unsigned int vv[8];
        #pragma unroll
        for (int q = 0; q < 8; ++q) vv[q] = *(const unsigned int*)(bp + (size_t)sx[q] * 128);
        #pragma unroll
        for (int q = 0; q < 8; ++q) {
            f32x2 p;
            p = __builtin_amdgcn_cvt_pk_f32_fp8(vv[q], false); a0 += p[0]; a1 += p[1];
            p = __builtin_amdgcn_cvt_pk_f32_fp8(vv[q], true);  a2 += p[0]; a3 += p[1];
        }
    }
    for (; e < e1; ++e) {
        int s0 = csr_src[e];
        unsigned int v0 = *(const unsigned int*)(bp + (size_t)s0 * 128);
        f32x2 p;
        p = __builtin_amdgcn_cvt_pk_f32_fp8(v0, false); a0 += p[0]; a1 += p[1];
        p = __builtin_amdgcn_cvt_pk_f32_fp8(v0, true);  a2 += p[0]; a3 += p[1];
    }
    float d = dinv[node];
    us4 o;
    o.x = f2bf(a0 * d); o.y = f2bf(a1 * d); o.z = f2bf(a2 * d); o.w = f2bf(a3 * d);
    *(us4*)(outp + (size_t)node * 128 + l32 * 4) = o;
}

// agg_h: F=256 fp8 in, bf16 out. 32 lanes/node, lane owns 8 features (8B).
__global__ __launch_bounds__(256) void agg_h(const u8* __restrict__ in,
                                             u16* __restrict__ outp,
                                             const int* __restrict__ row_ptr,
                                             const int* __restrict__ csr_src,
                                             const float* __restrict__ dinv,
                                             int nnodes) {
    int tid = threadIdx.x;
    int wv = tid >> 6, lane = tid & 63;
    int half = lane >> 5, l32 = lane & 31;
    int node = (blockIdx.x * 4 + wv) * 2 + half;
    if (node >= nnodes) return;
    int off = l32 * 8;
    const u8* bp = in + off;
    float acc[8];
    {
        uint2 q = *(const uint2*)(in + (size_t)node * 256 + off);
        f32x2 p;
        p = __builtin_amdgcn_cvt_pk_f32_fp8(q.x, false); acc[0] = p[0]; acc[1] = p[1];
        p = __builtin_amdgcn_cvt_pk_f32_fp8(q.x, true);  acc[2] = p[0]; acc[3] = p[1];
        p = __builtin_amdgcn_cvt_pk_f32_fp8(q.y, false); acc[4] = p[0]; acc[5] = p[1];
        p = __builtin_amdgcn_cvt_pk_f32_fp8(q.y, true);  acc[6] = p[0]; acc[7] = p[1];
    }
    int e = row_ptr[node], e1 = row_ptr[node + 1];
    for (; e + 8 <= e1; e += 8) {
        int sx[8];
        #pragma unroll
        for (int q = 0; q < 8; ++q) sx[q] = csr_src[e + q];
        uint2 vv[8];
        #pragma unroll
        for (int q = 0; q < 8; ++q) vv[q] = *(const uint2*)(bp + (size_t)sx[q] * 256);
        #pragma unroll
        for (int q = 0; q < 8; ++q) {
            f32x2 p;
            p = __builtin_amdgcn_cvt_pk_f32_fp8(vv[q].x, false); acc[0] += p[0]; acc[1] += p[1];
            p = __builtin_amdgcn_cvt_pk_f32_fp8(vv[q].x, true);  acc[2] += p[0]; acc[3] += p[1];
            p = __builtin_amdgcn_cvt_pk_f32_fp8(vv[q].y, false); acc[4] += p[0]; acc[5] += p[1];
            p = __builtin_amdgcn_cvt_pk_f32_fp8(vv[q].y, true);  acc[6] += p[0]; acc[7] += p[1];
        }
    }
    for (; e < e1; ++e) {
        int s0 = csr_src[e];
        uint2 v0 = *(const uint2*)(bp + (size_t)s0 * 256);
        f32x2 p;
        p = __builtin_amdgcn_cvt_pk_f32_fp8(v0.x, false); acc[0] += p[0]; acc[1] += p[1];
        p = __builtin_amdgcn_cvt_pk_f32_fp8(v0.x, true);  acc[2] += p[0]; acc[3] += p[1];
        p = __builtin_amdgcn_cvt_pk_f32_fp8(v0.y, false); acc[4] += p[0]; acc[5] += p[1];
        p = __builtin_amdgcn_cvt_pk_f32_fp8(v0.y, true);  acc[6] += p[0]; acc[7] += p[1];
    }
    float d = dinv[node];
    us8 o;
    #pragma unroll
    for (int j = 0; j < 8; ++j) o[j] = f2bf(acc[j] * d);
    *(us8*)(outp + (size_t)node * 256 + off) = o;
}

// agg32: F=32 bf16 in, f32 sigmoid out. 32 lanes/node, 2 nodes/wave.
__global__ __launch_bounds__(256) void agg32_sig(const u16* __restrict__ z,
                                                 float* __restrict__ out,
                                                 const int* __restrict__ row_ptr,
                                                 const int* __restrict__ csr_src,
                                                 const float* __restrict__ dinv,
                                                 const float* __restrict__ b3,
                                                 int nnodes) {
    int tid = threadIdx.x;
    int wv = tid >> 6, lane = tid & 63;
    int half = lane >> 5, l32 = lane & 31;
    int node = (blockIdx.x * 4 + wv) * 2 + half;
    if (node >= nnodes) return;
    float acc = bf2f(z[(size_t)node * 32 + l32]);
    int e = row_ptr[node], e1 = row_ptr[node + 1];
    for (; e + 4 <= e1; e += 4) {
        int s0 = csr_src[e], s1 = csr_src[e + 1], s2 = csr_src[e + 2], s3 = csr_src[e + 3];
        float z0 = bf2f(z[(size_t)s0 * 32 + l32]);
        float z1 = bf2f(z[(size_t)s1 * 32 + l32]);
        float z2 = bf2f(z[(size_t)s2 * 32 + l32]);
        float z3v = bf2f(z[(size_t)s3 * 32 + l32]);
        acc += z0 + z1 + z2 + z3v;
    }
    for (; e < e1; ++e) {
        acc += bf2f(z[(size_t)csr_src[e] * 32 + l32]);
    }
    acc = acc * dinv[node] + b3[l32];
    out[(size_t)node * 32 + l32] = 1.f / (1.f + expf(-acc));
}

// ---------------- launch ----------------

extern "C" void kernel_launch(void* const* d_in, const int* in_sizes, int n_in,
                              void* d_out, int out_size, void* d_ws, size_t ws_size,
                              hipStream_t stream) {
    const float* x  = (const float*)d_in[0];
    const int*   ei = (const int*)d_in[1];
    const float* W1 = (const float*)d_in[2];
    const float* b1 = (const float*)d_in[3];
    const float* g1 = (const float*)d_in[4];
    const float* be1 = (const float*)d_in[5];
    const float* m1 = (const float*)d_in[6];
    const float* v1 = (const float*)d_in[7];
    const float* W2 = (const float*)d_in[8];
    const float* b2 = (const float*)d_in[9];
    const float* g2 = (const float*)d_in[10];
    const float* be2 = (const float*)d_in[11];
    const float* m2 = (const float*)d_in[12];
    const float* v2 = (const float*)d_in[13];
    const float* W3 = (const float*)d_in[14];
    const float* b3 = (const float*)d_in[15];
    float* out = (float*)d_out;

    const int N = in_sizes[0] / 128;   // 100000
    const int E = in_sizes[1] / 2;     // 1600000

    const int NB = (N + 511) >> 9;           // buckets of 512 nodes (196)
    const int NBLK = (E + 2047) / 2048;      // histogram blocks (782)

    char* w = (char*)d_ws;
    auto alloc = [&](size_t bytes) -> void* {
        void* p = (void*)w;
        w += (bytes + 255) & ~(size_t)255;
        return p;
    };
    int* row_ptr   = (int*)alloc((size_t)(N + 1) * 4);
    float* dinv    = (float*)alloc((size_t)N * 4);
    u32* cnt_pb    = (u32*)alloc((size_t)NB * NBLK * 4);
    u32* bases_pb  = (u32*)alloc((size_t)NB * NBLK * 4);
    u32* bkt_tot   = (u32*)alloc((size_t)NB * 4);
    u32* bkt_base  = (u32*)alloc((size_t)NB * 4);
    u32* bkt_edges = (u32*)alloc((size_t)E * 4);
    float* s1 = (float*)alloc(256 * 4);
    float* t1 = (float*)alloc(256 * 4);
    float* s2 = (float*)alloc(256 * 4);
    float* t2 = (float*)alloc(256 * 4);
    u16* Wt1 = (u16*)alloc((size_t)128 * 256 * 2);
    u16* Wt2 = (u16*)alloc((size_t)256 * 256 * 2);
    u16* Wt3 = (u16*)alloc((size_t)256 * 32 * 2);
    int* csr_src = (int*)alloc((size_t)E * 4);
    u8*  xq   = (u8*)alloc((size_t)N * 128);        // x*dinv fp8; later reused as z3
    u16* bufA = (u16*)alloc((size_t)N * 256 * 2);
    u16* bufB = (u16*)alloc((size_t)N * 256 * 2);
    u8*  h1q  = (u8*)alloc((size_t)N * 256);
    u16* z3 = (u16*)xq;

    int nT = (N + 63) / 64;
    int gagg = (N + 7) / 8;

    // CSR build: bucket sort, no global atomics
    k_hist<<<NBLK, 256, 0, stream>>>(ei, cnt_pb, E, NB, NBLK);
    k_scanb<<<NB, 1024, 0, stream>>>(cnt_pb, bases_pb, bkt_tot, NBLK);
    k_scant<<<1, 256, 0, stream>>>(bkt_tot, bkt_base, row_ptr, NB, N, E);
    k_scatter2<<<NBLK, 256, 0, stream>>>(ei, bases_pb, bkt_base, bkt_edges, E, NB, NBLK);
    k_bucket<<<NB, 512, 0, stream>>>(bkt_edges, bkt_base, bkt_tot, row_ptr, dinv, csr_src, N);

    // param prep
    k_bnfold<<<1, 256, 0, stream>>>(b1, g1, be1, m1, v1, s1, t1, 256);
    k_bnfold<<<1, 256, 0, stream>>>(b2, g2, be2, m2, v2, s2, t2, 256);
    k_w2bf<<<(128 * 256 + 255) / 256, 256, 0, stream>>>(W1, Wt1, 128, 256);
    k_w2bf<<<(256 * 256 + 255) / 256, 256, 0, stream>>>(W2, Wt2, 256, 256);
    k_w2bf<<<(256 * 32 + 255) / 256, 256, 0, stream>>>(W3, Wt3, 256, 32);
    k_x2f8<<<(N * 128 / 4 + 255) / 256, 256, 0, stream>>>(x, xq, dinv, N * 128 / 4);

    // Layer 1: agg(xq fp8,128) -> bf16 -> GEMM(128->256)+BN+ReLU+dinv -> fp8 h1q
    agg_x<<<gagg, 256, 0, stream>>>(xq, bufA, row_ptr, csr_src, dinv, N);
    g_mfma_lds<128, 64, 3, 2><<<dim3(128, 4), 256, 0, stream>>>(
        bufA, Wt1, (void*)h1q, N, 256, s1, t1, dinv, nT);

    // Layer 2: agg(h1q fp8,256) -> bf16 -> GEMM(256->256)+BN+ReLU+dinv -> bf16
    agg_h<<<gagg, 256, 0, stream>>>(h1q, bufA, row_ptr, csr_src, dinv, N);
    g_mfma_lds<256, 64, 1, 2><<<dim3(128, 4), 256, 0, stream>>>(
        bufA, Wt2, (void*)bufB, N, 256, s2, t2, dinv, nT);

    // Layer 3: GEMM(256->32) -> bf16 z3, then agg + b3 + sigmoid
    g_mfma_lds<256, 32, 2, 2><<<dim3(512, 1), 256, 0, stream>>>(
        bufB, Wt3, (void*)z3, N, 32, (const float*)nullptr, (const float*)nullptr,
        (const float*)nullptr, nT);
    agg32_sig<<<gagg, 256, 0, stream>>>(z3, out, row_ptr, csr_src, dinv, b3, N);
}

// Round 13
// 282.484 us; speedup vs baseline: 1.5460x; 1.0036x over previous
//
#include <hip/hip_runtime.h>
#include <math.h>

typedef unsigned short u16;
typedef unsigned char u8;
typedef unsigned int u32;
typedef __attribute__((ext_vector_type(8))) __bf16 bfx8;
typedef __attribute__((ext_vector_type(4))) float f32x4;
typedef __attribute__((ext_vector_type(2))) float f32x2;
typedef __attribute__((ext_vector_type(8))) unsigned short us8;
typedef __attribute__((ext_vector_type(4))) unsigned short us4;

__device__ inline float bf2f(u16 u) {
    union { unsigned int i; float f; } v;
    v.i = ((unsigned int)u) << 16;
    return v.f;
}
__device__ inline u16 f2bf(float f) {
    union { float f; unsigned int i; } v;
    v.f = f;
    unsigned int b = v.i;
    return (u16)((b + 0x7FFFu + ((b >> 16) & 1u)) >> 16);
}
__device__ inline u32 bits_of(float f) {
    union { float f; u32 i; } v; v.f = f; return v.i;
}
// pack two f32 (exactly bf16-representable) into one u32 of 2 bf16 by truncation
__device__ inline u32 pkbf(float a, float b) {
    return (bits_of(a) >> 16) | (bits_of(b) & 0xffff0000u);
}
// decode 4 fp8 (one dword) -> 2 u32 of packed bf16 (exact)
__device__ inline void dec4(u32 d, u32& lo, u32& hi) {
    f32x2 a = __builtin_amdgcn_cvt_pk_f32_fp8(d, false);
    f32x2 b = __builtin_amdgcn_cvt_pk_f32_fp8(d, true);
    lo = pkbf(a[0], a[1]);
    hi = pkbf(b[0], b[1]);
}

// ---------------- CSR build: bucket sort, LDS atomics only ----------------

__global__ __launch_bounds__(256) void k_hist(const int* __restrict__ ei,
                                              u32* __restrict__ cnt_pb,
                                              int E, int NB, int NBLK) {
    __shared__ u32 h[256];
    int blk = blockIdx.x, tid = threadIdx.x;
    h[tid] = 0;
    __syncthreads();
    int eend = min(E, (blk + 1) * 2048);
    for (int e = blk * 2048 + tid; e < eend; e += 256) {
        int d = ei[E + e];
        atomicAdd(&h[d >> 9], 1u);
    }
    __syncthreads();
    if (tid < NB) cnt_pb[(size_t)tid * NBLK + blk] = h[tid];
}

__global__ __launch_bounds__(1024) void k_scanb(const u32* __restrict__ cnt_pb,
                                                u32* __restrict__ bases_pb,
                                                u32* __restrict__ bkt_tot,
                                                int NBLK) {
    __shared__ u32 lds[1024];
    int b = blockIdx.x, t = threadIdx.x;
    u32 v = (t < NBLK) ? cnt_pb[(size_t)b * NBLK + t] : 0u;
    lds[t] = v;
    __syncthreads();
    for (int off = 1; off < 1024; off <<= 1) {
        u32 x = lds[t];
        u32 y = (t >= off) ? lds[t - off] : 0u;
        __syncthreads();
        lds[t] = x + y;
        __syncthreads();
    }
    if (t < NBLK) bases_pb[(size_t)b * NBLK + t] = lds[t] - v;
    if (t == NBLK - 1) bkt_tot[b] = lds[t];
}

__global__ __launch_bounds__(256) void k_scant(const u32* __restrict__ bkt_tot,
                                               u32* __restrict__ bkt_base,
                                               int* __restrict__ row_ptr,
                                               int NB, int N, int E) {
    __shared__ u32 lds[256];
    int t = threadIdx.x;
    u32 v = (t < NB) ? bkt_tot[t] : 0u;
    lds[t] = v;
    __syncthreads();
    for (int off = 1; off < 256; off <<= 1) {
        u32 x = lds[t];
        u32 y = (t >= off) ? lds[t - off] : 0u;
        __syncthreads();
        lds[t] = x + y;
        __syncthreads();
    }
    if (t < NB) bkt_base[t] = lds[t] - v;
    if (t == 0) row_ptr[N] = E;
}

__global__ __launch_bounds__(256) void k_scatter2(const int* __restrict__ ei,
                                                  const u32* __restrict__ bases_pb,
                                                  const u32* __restrict__ bkt_base,
                                                  u32* __restrict__ bkt_edges,
                                                  int E, int NB, int NBLK) {
    __shared__ u32 cur[256];
    __shared__ u32 bb[256];
    int blk = blockIdx.x, tid = threadIdx.x;
    if (tid < NB) {
        cur[tid] = bases_pb[(size_t)tid * NBLK + blk];
        bb[tid] = bkt_base[tid];
    }
    __syncthreads();
    int eend = min(E, (blk + 1) * 2048);
    for (int e = blk * 2048 + tid; e < eend; e += 256) {
        int s = ei[e];
        int d = ei[E + e];
        int b = d >> 9;
        int dl = d & 511;
        u32 off = atomicAdd(&cur[b], 1u);
        bkt_edges[bb[b] + off] = (u32)s | ((u32)dl << 17);
    }
}

__global__ __launch_bounds__(512) void k_bucket(const u32* __restrict__ bkt_edges,
                                                const u32* __restrict__ bkt_base,
                                                const u32* __restrict__ bkt_tot,
                                                int* __restrict__ row_ptr,
                                                float* __restrict__ dinv,
                                                int* __restrict__ csr_src,
                                                int N) {
    __shared__ u32 lcnt[512];
    __shared__ u32 lscan[512];
    int b = blockIdx.x, t = threadIdx.x;
    int node0 = b << 9;
    int es = (int)bkt_base[b];
    int ce = (int)bkt_tot[b];
    lcnt[t] = 0;
    __syncthreads();
    for (int i = t; i < ce; i += 512) {
        u32 p = bkt_edges[es + i];
        atomicAdd(&lcnt[p >> 17], 1u);
    }
    __syncthreads();
    lscan[t] = lcnt[t];
    __syncthreads();
    for (int off = 1; off < 512; off <<= 1) {
        u32 x = lscan[t];
        u32 y = (t >= off) ? lscan[t - off] : 0u;
        __syncthreads();
        lscan[t] = x + y;
        __syncthreads();
    }
    u32 excl = lscan[t] - lcnt[t];
    int node = node0 + t;
    if (node < N) {
        row_ptr[node] = es + (int)excl;
        dinv[node] = rsqrtf((float)lcnt[t] + 1.0f);
    }
    __syncthreads();
    lscan[t] = excl;
    __syncthreads();
    for (int i = t; i < ce; i += 512) {
        u32 p = bkt_edges[es + i];
        int dl = (int)(p >> 17);
        int src = (int)(p & 0x1FFFFu);
        u32 pos = atomicAdd(&lscan[dl], 1u);
        csr_src[es + pos] = src;
    }
}

// ---------------- small converts ----------------

__global__ void k_bnfold(const float* __restrict__ b, const float* __restrict__ g,
                         const float* __restrict__ be, const float* __restrict__ m,
                         const float* __restrict__ v, float* __restrict__ s,
                         float* __restrict__ t, int H) {
    int i = blockIdx.x * blockDim.x + threadIdx.x;
    if (i < H) {
        float sc = g[i] * rsqrtf(v[i] + 1e-5f);
        s[i] = sc;
        t[i] = (b[i] - m[i]) * sc + be[i];
    }
}

__global__ void k_w2bf(const float* __restrict__ W, u16* __restrict__ Wt, int K, int F) {
    int i = blockIdx.x * blockDim.x + threadIdx.x;
    if (i < K * F) {
        int k = i / F, f = i % F;
        Wt[(size_t)f * K + k] = f2bf(W[i]);
    }
}

__global__ void k_x2f8(const float* __restrict__ x, u8* __restrict__ xq,
                       const float* __restrict__ dinv, int n4) {
    int i = blockIdx.x * blockDim.x + threadIdx.x;
    if (i < n4) {
        float d = dinv[i >> 5];
        float4 v = *(const float4*)(x + (size_t)i * 4);
        unsigned int pk = 0;
        pk = __builtin_amdgcn_cvt_pk_fp8_f32(v.x * d, v.y * d, pk, false);
        pk = __builtin_amdgcn_cvt_pk_fp8_f32(v.z * d, v.w * d, pk, true);
        *(unsigned int*)(xq + (size_t)i * 4) = pk;
    }
}

// ---------------- MFMA GEMM: persistent blocks, B in regs, A via LDS -------
// AFP8: A stored fp8 e4m3, decoded (exactly) to bf16 during LDS staging.
// MODE 1: BN+ReLU*dinv bf16. MODE 2: plain bf16. MODE 3: BN+ReLU*dinv fp8.
template<int K, int FT, int MODE, bool AFP8, int MINW>
__global__ __launch_bounds__(256, MINW) void g_mfma_lds(
    const void* __restrict__ Av, const u16* __restrict__ Wt,
    void* __restrict__ Cv, int M, int Ftot,
    const float* __restrict__ s, const float* __restrict__ t,
    const float* __restrict__ dinv, int nTiles)
{
    constexpr int BK  = 128;
    constexpr int SA  = BK + 8;
    constexpr int NH  = K / BK;
    constexpr int NKH = BK / 32;
    constexpr int NF  = FT / 16;
    constexpr int EB  = (MODE == 3) ? 1 : 2;
    constexpr int SCB = FT * EB + 16;
    constexpr int EBa = AFP8 ? 1 : 2;           // A bytes/elem
    constexpr int CR  = (BK * EBa) / 16;        // 16B chunks per mini-row
    constexpr int LIT = (64 * CR) / 256;        // load iters (2 or 4)

    __shared__ u16 Asmem[2][64 * SA];
    __shared__ u8  Cs8[64 * SCB];

    const u8* Ab = (const u8*)Av;
    int tid = threadIdx.x;
    int w = tid >> 6, l = tid & 63;
    int lr = l & 15, koff8 = (l >> 4) * 8;
    int col0 = blockIdx.y * FT;

    bfx8 bfr[NH][NKH][NF];
    {
        const u16* wp = Wt + (size_t)(col0 + lr) * K + koff8;
        #pragma unroll
        for (int h = 0; h < NH; ++h)
            #pragma unroll
            for (int kk = 0; kk < NKH; ++kk)
                #pragma unroll
                for (int c = 0; c < NF; ++c)
                    bfr[h][kk][c] = *(const bfx8*)(wp + (size_t)c * 16 * K + h * BK + kk * 32);
    }

    int myT = (blockIdx.x < nTiles) ? ((nTiles - 1 - (int)blockIdx.x) / (int)gridDim.x + 1) : 0;
    int NM = myT * NH;
    if (NM == 0) return;

    f32x4 acc[NF];
    #pragma unroll
    for (int c = 0; c < NF; ++c) acc[c] = (f32x4){0.f, 0.f, 0.f, 0.f};

    uint4 rga[LIT];

    auto loadA = [&](int r0, int hh) {
        #pragma unroll
        for (int j = 0; j < LIT; ++j) {
            int cid = j * 256 + tid;
            int row = cid / CR, ch = cid % CR;
            int gr = r0 + row; if (gr > M - 1) gr = M - 1;
            rga[j] = *(const uint4*)(Ab + (size_t)gr * K * EBa + (size_t)hh * BK * EBa + ch * 16);
        }
    };
    auto writeA = [&](int buf) {
        #pragma unroll
        for (int j = 0; j < LIT; ++j) {
            int cid = j * 256 + tid;
            int row = cid / CR, ch = cid % CR;
            if (!AFP8) {
                *(uint4*)&Asmem[buf][row * SA + ch * 8] = rga[j];
            } else {
                u32 w0, w1, w2, w3, w4, w5, w6, w7;
                dec4(rga[j].x, w0, w1);
                dec4(rga[j].y, w2, w3);
                dec4(rga[j].z, w4, w5);
                dec4(rga[j].w, w6, w7);
                uint4 lo4; lo4.x = w0; lo4.y = w1; lo4.z = w2; lo4.w = w3;
                uint4 hi4; hi4.x = w4; hi4.y = w5; hi4.z = w6; hi4.w = w7;
                *(uint4*)&Asmem[buf][row * SA + ch * 16] = lo4;
                *(uint4*)&Asmem[buf][row * SA + ch * 16 + 8] = hi4;
            }
        }
    };

    // prologue: stage mini 0, prefetch mini 1
    loadA(blockIdx.x * 64, 0);
    writeA(0);
    if (NM > 1) {
        constexpr int gt1 = 1 / NH, h1 = 1 % NH;
        loadA((blockIdx.x + gt1 * gridDim.x) * 64, h1);
    }
    __syncthreads();

    int cur = 0, gm = 0;
    for (int ti = 0; ti < myT; ++ti) {
        int row0g = (blockIdx.x + ti * gridDim.x) * 64;
        #pragma unroll
        for (int h = 0; h < NH; ++h) {
            const u16* ab = &Asmem[cur][0];
            #pragma unroll
            for (int kk = 0; kk < NKH; ++kk) {
                bfx8 af = *(const bfx8*)(ab + (w * 16 + lr) * SA + koff8 + kk * 32);
                #pragma unroll
                for (int c = 0; c < NF; ++c)
                    acc[c] = __builtin_amdgcn_mfma_f32_16x16x32_bf16(af, bfr[h][kk][c], acc[c], 0, 0, 0);
            }
            if (h == NH - 1) {
                int orow = w * 16 + (l >> 4) * 4;
                float dr[4];
                #pragma unroll
                for (int r = 0; r < 4; ++r) {
                    int grow = row0g + orow + r;
                    dr[r] = (MODE == 2) ? 1.f : ((grow < M) ? dinv[grow] : 0.f);
                }
                #pragma unroll
                for (int c = 0; c < NF; ++c) {
                    int gc = col0 + c * 16 + lr;
                    float sc = (MODE == 2) ? 0.f : s[gc];
                    float tc = (MODE == 2) ? 0.f : t[gc];
                    #pragma unroll
                    for (int r = 0; r < 4; ++r) {
                        float v = acc[c][r];
                        if (MODE != 2) v = fmaxf(v * sc + tc, 0.f) * dr[r];
                        if (MODE == 3) {
                            int enc = __builtin_amdgcn_cvt_pk_fp8_f32(v, v, 0, false);
                            Cs8[(orow + r) * SCB + (c * 16 + lr)] = (u8)(enc & 0xff);
                        } else {
                            *(u16*)&Cs8[(orow + r) * SCB + (c * 16 + lr) * 2] = f2bf(v);
                        }
                    }
                    acc[c] = (f32x4){0.f, 0.f, 0.f, 0.f};
                }
            }
            __syncthreads();
            if (gm + 1 < NM) writeA(cur ^ 1);
            if (h == NH - 1) {
                constexpr int CPR = (FT * EB) / 16;
                constexpr int CPT = (64 * CPR) / 256;
                u8* C8 = (u8*)Cv;
                #pragma unroll
                for (int j = 0; j < CPT; ++j) {
                    int cid = j * 256 + tid;
                    int crow = cid / CPR;
                    int cb = (cid % CPR) * 16;
                    int grow = row0g + crow;
                    if (grow < M) {
                        us8 vv = *(const us8*)&Cs8[crow * SCB + cb];
                        *(us8*)(C8 + (size_t)grow * Ftot * EB + (size_t)col0 * EB + cb) = vv;
                    }
                }
            }
            if (gm + 2 < NM) {
                int g2 = gm + 2;
                int gt2 = g2 / NH, h2 = g2 % NH;
                loadA((blockIdx.x + gt2 * gridDim.x) * 64, h2);
            }
            __syncthreads();
            cur ^= 1; ++gm;
        }
    }
}

// ---------------- Aggregation ----------------
// agg_x: F=128 fp8 in, fp8 out. 32 lanes/node, lane owns 4 fp8. 8-edge unroll.
__global__ __launch_bounds__(256) void agg_x(const u8* __restrict__ in,
                                             u8* __restrict__ outp,
                                             const int* __restrict__ row_ptr,
                                             const int* __restrict__ csr_src,
                                             const float* __restrict__ dinv,
                                             int nnodes) {
    int tid = threadIdx.x;
    int wv = tid >> 6, lane = tid & 63;
    int half = lane >> 5, l32 = lane & 31;
    int node = (blockIdx.x * 4 + wv) * 2 + half;
    if (node >= nnodes) return;
    int off = l32 * 4;
    const u8* bp = in + off;
    float a0, a1, a2, a3;
    {
        unsigned int q = *(const unsigned int*)(in + (size_t)node * 128 + off);
        f32x2 p;
        p = __builtin_amdgcn_cvt_pk_f32_fp8(q, false); a0 = p[0]; a1 = p[1];
        p = __builtin_amdgcn_cvt_pk_f32_fp8(q, true);  a2 = p[0]; a3 = p[1];
    }
    int e = row_ptr[node], e1 = row_ptr[node + 1];
    for (; e + 8 <= e1; e += 8) {
        int sx[8];
        #pragma unroll
        for (int q = 0; q < 8; ++q) sx[q] = csr_src[e + q];
        unsigned int vv[8];
        #pragma unroll
        for (int q = 0; q < 8; ++q) vv[q] = *(const unsigned int*)(bp + (size_t)sx[q] * 128);
        #pragma unroll
        for (int q = 0; q < 8; ++q) {
            f32x2 p;
            p = __builtin_amdgcn_cvt_pk_f32_fp8(vv[q], false); a0 += p[0]; a1 += p[1];
            p = __builtin_amdgcn_cvt_pk_f32_fp8(vv[q], true);  a2 += p[0]; a3 += p[1];
        }
    }
    for (; e < e1; ++e) {
        int s0 = csr_src[e];
        unsigned int v0 = *(const unsigned int*)(bp + (size_t)s0 * 128);
        f32x2 p;
        p = __builtin_amdgcn_cvt_pk_f32_fp8(v0, false); a0 += p[0]; a1 += p[1];
        p = __builtin_amdgcn_cvt_pk_f32_fp8(v0, true);  a2 += p[0]; a3 += p[1];
    }
    float d = dinv[node];
    u32 pk = 0;
    pk = __builtin_amdgcn_cvt_pk_fp8_f32(a0 * d, a1 * d, pk, false);
    pk = __builtin_amdgcn_cvt_pk_fp8_f32(a2 * d, a3 * d, pk, true);
    *(u32*)(outp + (size_t)node * 128 + off) = pk;
}

// agg_h: F=256 fp8 in, fp8 out. 32 lanes/node, lane owns 8 features (8B).
__global__ __launch_bounds__(256) void agg_h(const u8* __restrict__ in,
                                             u8* __restrict__ outp,
                                             const int* __restrict__ row_ptr,
                                             const int* __restrict__ csr_src,
                                             const float* __restrict__ dinv,
                                             int nnodes) {
    int tid = threadIdx.x;
    int wv = tid >> 6, lane = tid & 63;
    int half = lane >> 5, l32 = lane & 31;
    int node = (blockIdx.x * 4 + wv) * 2 + half;
    if (node >= nnodes) return;
    int off = l32 * 8;
    const u8* bp = in + off;
    float acc[8];
    {
        uint2 q = *(const uint2*)(in + (size_t)node * 256 + off);
        f32x2 p;
        p = __builtin_amdgcn_cvt_pk_f32_fp8(q.x, false); acc[0] = p[0]; acc[1] = p[1];
        p = __builtin_amdgcn_cvt_pk_f32_fp8(q.x, true);  acc[2] = p[0]; acc[3] = p[1];
        p = __builtin_amdgcn_cvt_pk_f32_fp8(q.y, false); acc[4] = p[0]; acc[5] = p[1];
        p = __builtin_amdgcn_cvt_pk_f32_fp8(q.y, true);  acc[6] = p[0]; acc[7] = p[1];
    }
    int e = row_ptr[node], e1 = row_ptr[node + 1];
    for (; e + 8 <= e1; e += 8) {
        int sx[8];
        #pragma unroll
        for (int q = 0; q < 8; ++q) sx[q] = csr_src[e + q];
        uint2 vv[8];
        #pragma unroll
        for (int q = 0; q < 8; ++q) vv[q] = *(const uint2*)(bp + (size_t)sx[q] * 256);
        #pragma unroll
        for (int q = 0; q < 8; ++q) {
            f32x2 p;
            p = __builtin_amdgcn_cvt_pk_f32_fp8(vv[q].x, false); acc[0] += p[0]; acc[1] += p[1];
            p = __builtin_amdgcn_cvt_pk_f32_fp8(vv[q].x, true);  acc[2] += p[0]; acc[3] += p[1];
            p = __builtin_amdgcn_cvt_pk_f32_fp8(vv[q].y, false); acc[4] += p[0]; acc[5] += p[1];
            p = __builtin_amdgcn_cvt_pk_f32_fp8(vv[q].y, true);  acc[6] += p[0]; acc[7] += p[1];
        }
    }
    for (; e < e1; ++e) {
        int s0 = csr_src[e];
        uint2 v0 = *(const uint2*)(bp + (size_t)s0 * 256);
        f32x2 p;
        p = __builtin_amdgcn_cvt_pk_f32_fp8(v0.x, false); acc[0] += p[0]; acc[1] += p[1];
        p = __builtin_amdgcn_cvt_pk_f32_fp8(v0.x, true);  acc[2] += p[0]; acc[3] += p[1];
        p = __builtin_amdgcn_cvt_pk_f32_fp8(v0.y, false); acc[4] += p[0]; acc[5] += p[1];
        p = __builtin_amdgcn_cvt_pk_f32_fp8(v0.y, true);  acc[6] += p[0]; acc[7] += p[1];
    }
    float d = dinv[node];
    u32 w0 = 0, w1 = 0;
    w0 = __builtin_amdgcn_cvt_pk_fp8_f32(acc[0] * d, acc[1] * d, w0, false);
    w0 = __builtin_amdgcn_cvt_pk_fp8_f32(acc[2] * d, acc[3] * d, w0, true);
    w1 = __builtin_amdgcn_cvt_pk_fp8_f32(acc[4] * d, acc[5] * d, w1, false);
    w1 = __builtin_amdgcn_cvt_pk_fp8_f32(acc[6] * d, acc[7] * d, w1, true);
    uint2 o; o.x = w0; o.y = w1;
    *(uint2*)(outp + (size_t)node * 256 + off) = o;
}

// agg32: F=32 bf16 in, f32 sigmoid out. 32 lanes/node, 2 nodes/wave.
__global__ __launch_bounds__(256) void agg32_sig(const u16* __restrict__ z,
                                                 float* __restrict__ out,
                                                 const int* __restrict__ row_ptr,
                                                 const int* __restrict__ csr_src,
                                                 const float* __restrict__ dinv,
                                                 const float* __restrict__ b3,
                                                 int nnodes) {
    int tid = threadIdx.x;
    int wv = tid >> 6, lane = tid & 63;
    int half = lane >> 5, l32 = lane & 31;
    int node = (blockIdx.x * 4 + wv) * 2 + half;
    if (node >= nnodes) return;
    float acc = bf2f(z[(size_t)node * 32 + l32]);
    int e = row_ptr[node], e1 = row_ptr[node + 1];
    for (; e + 4 <= e1; e += 4) {
        int s0 = csr_src[e], s1 = csr_src[e + 1], s2 = csr_src[e + 2], s3 = csr_src[e + 3];
        float z0 = bf2f(z[(size_t)s0 * 32 + l32]);
        float z1 = bf2f(z[(size_t)s1 * 32 + l32]);
        float z2 = bf2f(z[(size_t)s2 * 32 + l32]);
        float z3v = bf2f(z[(size_t)s3 * 32 + l32]);
        acc += z0 + z1 + z2 + z3v;
    }
    for (; e < e1; ++e) {
        acc += bf2f(z[(size_t)csr_src[e] * 32 + l32]);
    }
    acc = acc * dinv[node] + b3[l32];
    out[(size_t)node * 32 + l32] = 1.f / (1.f + expf(-acc));
}

// ---------------- launch ----------------

extern "C" void kernel_launch(void* const* d_in, const int* in_sizes, int n_in,
                              void* d_out, int out_size, void* d_ws, size_t ws_size,
                              hipStream_t stream) {
    const float* x  = (const float*)d_in[0];
    const int*   ei = (const int*)d_in[1];
    const float* W1 = (const float*)d_in[2];
    const float* b1 = (const float*)d_in[3];
    const float* g1 = (const float*)d_in[4];
    const float* be1 = (const float*)d_in[5];
    const float* m1 = (const float*)d_in[6];
    const float* v1 = (const float*)d_in[7];
    const float* W2 = (const float*)d_in[8];
    const float* b2 = (const float*)d_in[9];
    const float* g2 = (const float*)d_in[10];
    const float* be2 = (const float*)d_in[11];
    const float* m2 = (const float*)d_in[12];
    const float* v2 = (const float*)d_in[13];
    const float* W3 = (const float*)d_in[14];
    const float* b3 = (const float*)d_in[15];
    float* out = (float*)d_out;

    const int N = in_sizes[0] / 128;   // 100000
    const int E = in_sizes[1] / 2;     // 1600000

    const int NB = (N + 511) >> 9;
    const int NBLK = (E + 2047) / 2048;

    char* w = (char*)d_ws;
    auto alloc = [&](size_t bytes) -> void* {
        void* p = (void*)w;
        w += (bytes + 255) & ~(size_t)255;
        return p;
    };
    int* row_ptr   = (int*)alloc((size_t)(N + 1) * 4);
    float* dinv    = (float*)alloc((size_t)N * 4);
    u32* cnt_pb    = (u32*)alloc((size_t)NB * NBLK * 4);
    u32* bases_pb  = (u32*)alloc((size_t)NB * NBLK * 4);
    u32* bkt_tot   = (u32*)alloc((size_t)NB * 4);
    u32* bkt_base  = (u32*)alloc((size_t)NB * 4);
    u32* bkt_edges = (u32*)alloc((size_t)E * 4);
    float* s1 = (float*)alloc(256 * 4);
    float* t1 = (float*)alloc(256 * 4);
    float* s2 = (float*)alloc(256 * 4);
    float* t2 = (float*)alloc(256 * 4);
    u16* Wt1 = (u16*)alloc((size_t)128 * 256 * 2);
    u16* Wt2 = (u16*)alloc((size_t)256 * 256 * 2);
    u16* Wt3 = (u16*)alloc((size_t)256 * 32 * 2);
    int* csr_src = (int*)alloc((size_t)E * 4);
    u8*  xq   = (u8*)alloc((size_t)N * 128);   // x*dinv fp8; reused as z3 bf16
    u8*  xa   = (u8*)alloc((size_t)N * 128);   // agg_x out fp8
    u8*  h1q  = (u8*)alloc((size_t)N * 256);   // GEMM1 out fp8
    u8*  h1a  = (u8*)alloc((size_t)N * 256);   // agg_h out fp8
    u8*  h2q  = (u8*)alloc((size_t)N * 256);   // GEMM2 out fp8
    u16* z3 = (u16*)xq;                        // N*32 bf16 = 6.4MB <= 12.8MB

    int nT = (N + 63) / 64;
    int gagg = (N + 7) / 8;

    // CSR build: bucket sort, no global atomics
    k_hist<<<NBLK, 256, 0, stream>>>(ei, cnt_pb, E, NB, NBLK);
    k_scanb<<<NB, 1024, 0, stream>>>(cnt_pb, bases_pb, bkt_tot, NBLK);
    k_scant<<<1, 256, 0, stream>>>(bkt_tot, bkt_base, row_ptr, NB, N, E);
    k_scatter2<<<NBLK, 256, 0, stream>>>(ei, bases_pb, bkt_base, bkt_edges, E, NB, NBLK);
    k_bucket<<<NB, 512, 0, stream>>>(bkt_edges, bkt_base, bkt_tot, row_ptr, dinv, csr_src, N);

    // param prep
    k_bnfold<<<1, 256, 0, stream>>>(b1, g1, be1, m1, v1, s1, t1, 256);
    k_bnfold<<<1, 256, 0, stream>>>(b2, g2, be2, m2, v2, s2, t2, 256);
    k_w2bf<<<(128 * 256 + 255) / 256, 256, 0, stream>>>(W1, Wt1, 128, 256);
    k_w2bf<<<(256 * 256 + 255) / 256, 256, 0, stream>>>(W2, Wt2, 256, 256);
    k_w2bf<<<(256 * 32 + 255) / 256, 256, 0, stream>>>(W3, Wt3, 256, 32);
    k_x2f8<<<(N * 128 / 4 + 255) / 256, 256, 0, stream>>>(x, xq, dinv, N * 128 / 4);

    // Layer 1: agg(xq fp8) -> fp8 xa -> GEMM(128->256)+BN+ReLU+dinv -> fp8 h1q
    agg_x<<<gagg, 256, 0, stream>>>(xq, xa, row_ptr, csr_src, dinv, N);
    g_mfma_lds<128, 64, 3, true, 2><<<dim3(128, 4), 256, 0, stream>>>(
        (const void*)xa, Wt1, (void*)h1q, N, 256, s1, t1, dinv, nT);

    // Layer 2: agg(h1q fp8) -> fp8 h1a -> GEMM(256->256)+BN+ReLU+dinv -> fp8 h2q
    agg_h<<<gagg, 256, 0, stream>>>(h1q, h1a, row_ptr, csr_src, dinv, N);
    g_mfma_lds<256, 64, 3, true, 2><<<dim3(128, 4), 256, 0, stream>>>(
        (const void*)h1a, Wt2, (void*)h2q, N, 256, s2, t2, dinv, nT);

    // Layer 3: GEMM(256->32) fp8 A -> bf16 z3, then agg + b3 + sigmoid
    g_mfma_lds<256, 32, 2, true, 2><<<dim3(512, 1), 256, 0, stream>>>(
        (const void*)h2q, Wt3, (void*)z3, N, 32, (const float*)nullptr,
        (const float*)nullptr, (const float*)nullptr, nT);
    agg32_sig<<<gagg, 256, 0, stream>>>(z3, out, row_ptr, csr_src, dinv, b3, N);
}

// Round 14
// 251.589 us; speedup vs baseline: 1.7358x; 1.1228x over previous
//
#include <hip/hip_runtime.h>
#include <math.h>

typedef unsigned short u16;
typedef unsigned char u8;
typedef unsigned int u32;
typedef __attribute__((ext_vector_type(8))) __bf16 bfx8;
typedef __attribute__((ext_vector_type(4))) float f32x4;
typedef __attribute__((ext_vector_type(2))) float f32x2;
typedef __attribute__((ext_vector_type(8))) unsigned short us8;
typedef __attribute__((ext_vector_type(4))) unsigned short us4;

__device__ inline float bf2f(u16 u) {
    union { unsigned int i; float f; } v;
    v.i = ((unsigned int)u) << 16;
    return v.f;
}
__device__ inline u16 f2bf(float f) {
    union { float f; unsigned int i; } v;
    v.f = f;
    unsigned int b = v.i;
    return (u16)((b + 0x7FFFu + ((b >> 16) & 1u)) >> 16);
}
__device__ inline u32 bits_of(float f) {
    union { float f; u32 i; } v; v.f = f; return v.i;
}
__device__ inline u32 pkbf(float a, float b) {
    return (bits_of(a) >> 16) | (bits_of(b) & 0xffff0000u);
}
// decode 4 fp8 (one dword) -> 2 u32 of packed bf16 (exact)
__device__ inline void dec4(u32 d, u32& lo, u32& hi) {
    f32x2 a = __builtin_amdgcn_cvt_pk_f32_fp8(d, false);
    f32x2 b = __builtin_amdgcn_cvt_pk_f32_fp8(d, true);
    lo = pkbf(a[0], a[1]);
    hi = pkbf(b[0], b[1]);
}

// ---------------- CSR build: bucket sort, LDS atomics only ----------------

__global__ __launch_bounds__(256) void k_hist(const int* __restrict__ ei,
                                              u32* __restrict__ cnt_pb,
                                              int E, int NB, int NBLK) {
    __shared__ u32 h[256];
    int blk = blockIdx.x, tid = threadIdx.x;
    h[tid] = 0;
    __syncthreads();
    int eend = min(E, (blk + 1) * 2048);
    for (int e = blk * 2048 + tid; e < eend; e += 256) {
        int d = ei[E + e];
        atomicAdd(&h[d >> 9], 1u);
    }
    __syncthreads();
    if (tid < NB) cnt_pb[(size_t)tid * NBLK + blk] = h[tid];
}

__global__ __launch_bounds__(1024) void k_scanb(const u32* __restrict__ cnt_pb,
                                                u32* __restrict__ bases_pb,
                                                u32* __restrict__ bkt_tot,
                                                int NBLK) {
    __shared__ u32 lds[1024];
    int b = blockIdx.x, t = threadIdx.x;
    u32 v = (t < NBLK) ? cnt_pb[(size_t)b * NBLK + t] : 0u;
    lds[t] = v;
    __syncthreads();
    for (int off = 1; off < 1024; off <<= 1) {
        u32 x = lds[t];
        u32 y = (t >= off) ? lds[t - off] : 0u;
        __syncthreads();
        lds[t] = x + y;
        __syncthreads();
    }
    if (t < NBLK) bases_pb[(size_t)b * NBLK + t] = lds[t] - v;
    if (t == NBLK - 1) bkt_tot[b] = lds[t];
}

// scatter edges into bucket-contiguous regions; bucket bases recomputed in LDS
__global__ __launch_bounds__(256) void k_scatter2(const int* __restrict__ ei,
                                                  const u32* __restrict__ bases_pb,
                                                  const u32* __restrict__ bkt_tot,
                                                  u32* __restrict__ bkt_edges,
                                                  int E, int NB, int NBLK) {
    __shared__ u32 cur[256];
    __shared__ u32 bb[256];
    int blk = blockIdx.x, tid = threadIdx.x;
    // exclusive scan of bkt_tot -> bb
    u32 v = (tid < NB) ? bkt_tot[tid] : 0u;
    bb[tid] = v;
    __syncthreads();
    for (int off = 1; off < 256; off <<= 1) {
        u32 x = bb[tid];
        u32 y = (tid >= off) ? bb[tid - off] : 0u;
        __syncthreads();
        bb[tid] = x + y;
        __syncthreads();
    }
    u32 excl = bb[tid] - v;
    __syncthreads();
    bb[tid] = excl;
    if (tid < NB) cur[tid] = bases_pb[(size_t)tid * NBLK + blk];
    __syncthreads();
    int eend = min(E, (blk + 1) * 2048);
    for (int e = blk * 2048 + tid; e < eend; e += 256) {
        int s = ei[e];
        int d = ei[E + e];
        int b = d >> 9;
        int dl = d & 511;
        u32 off = atomicAdd(&cur[b], 1u);
        bkt_edges[bb[b] + off] = (u32)s | ((u32)dl << 17);
    }
}

// per-bucket CSR build; bucket base recomputed in LDS
__global__ __launch_bounds__(512) void k_bucket(const u32* __restrict__ bkt_edges,
                                                const u32* __restrict__ bkt_tot,
                                                int* __restrict__ row_ptr,
                                                float* __restrict__ dinv,
                                                int* __restrict__ csr_src,
                                                int N, int NB, int E) {
    __shared__ u32 sb[256];
    __shared__ u32 lcnt[512];
    __shared__ u32 lscan[512];
    int b = blockIdx.x, t = threadIdx.x;
    // inclusive scan of bkt_tot (256-wide, first 256 threads)
    if (t < 256) sb[t] = (t < NB) ? bkt_tot[t] : 0u;
    __syncthreads();
    for (int off = 1; off < 256; off <<= 1) {
        u32 x = 0, y = 0;
        if (t < 256) { x = sb[t]; y = (t >= off) ? sb[t - off] : 0u; }
        __syncthreads();
        if (t < 256) sb[t] = x + y;
        __syncthreads();
    }
    int ce = (int)bkt_tot[b];
    int es = (int)sb[b] - ce;
    int node0 = b << 9;
    lcnt[t] = 0;
    __syncthreads();
    for (int i = t; i < ce; i += 512) {
        u32 p = bkt_edges[es + i];
        atomicAdd(&lcnt[p >> 17], 1u);
    }
    __syncthreads();
    lscan[t] = lcnt[t];
    __syncthreads();
    for (int off = 1; off < 512; off <<= 1) {
        u32 x = lscan[t];
        u32 y = (t >= off) ? lscan[t - off] : 0u;
        __syncthreads();
        lscan[t] = x + y;
        __syncthreads();
    }
    u32 excl = lscan[t] - lcnt[t];
    int node = node0 + t;
    if (node < N) {
        row_ptr[node] = es + (int)excl;
        dinv[node] = rsqrtf((float)lcnt[t] + 1.0f);
    }
    if (b == 0 && t == 0) row_ptr[N] = E;
    __syncthreads();
    lscan[t] = excl;
    __syncthreads();
    for (int i = t; i < ce; i += 512) {
        u32 p = bkt_edges[es + i];
        int dl = (int)(p >> 17);
        int src = (int)(p & 0x1FFFFu);
        u32 pos = atomicAdd(&lscan[dl], 1u);
        csr_src[es + pos] = src;
    }
}

// ---------------- fused param prep: x->fp8, W->Wt bf16 x3, bnfold x2 -------
__global__ __launch_bounds__(256) void k_prep(
    const float* __restrict__ x, u8* __restrict__ xq, const float* __restrict__ dinv, int n4,
    const float* __restrict__ W1, u16* __restrict__ Wt1,
    const float* __restrict__ W2, u16* __restrict__ Wt2,
    const float* __restrict__ W3, u16* __restrict__ Wt3,
    const float* __restrict__ b1, const float* __restrict__ g1, const float* __restrict__ be1,
    const float* __restrict__ m1, const float* __restrict__ v1,
    float* __restrict__ s1, float* __restrict__ t1,
    const float* __restrict__ b2, const float* __restrict__ g2, const float* __restrict__ be2,
    const float* __restrict__ m2, const float* __restrict__ v2,
    float* __restrict__ s2, float* __restrict__ t2)
{
    int i = blockIdx.x * blockDim.x + threadIdx.x;
    if (i < n4) {
        float d = dinv[i >> 5];
        float4 v = *(const float4*)(x + (size_t)i * 4);
        u32 pk = 0;
        pk = __builtin_amdgcn_cvt_pk_fp8_f32(v.x * d, v.y * d, pk, false);
        pk = __builtin_amdgcn_cvt_pk_fp8_f32(v.z * d, v.w * d, pk, true);
        *(u32*)(xq + (size_t)i * 4) = pk;
        return;
    }
    int j = i - n4;
    if (j < 128 * 256) {
        int k = j / 256, f = j % 256;
        Wt1[(size_t)f * 128 + k] = f2bf(W1[j]);
    } else if (j < 128 * 256 + 256 * 256) {
        int j2 = j - 128 * 256;
        int k = j2 / 256, f = j2 % 256;
        Wt2[(size_t)f * 256 + k] = f2bf(W2[j2]);
    } else if (j < 128 * 256 + 256 * 256 + 256 * 32) {
        int j3 = j - (128 * 256 + 256 * 256);
        int k = j3 / 32, f = j3 % 32;
        Wt3[(size_t)f * 256 + k] = f2bf(W3[j3]);
    } else {
        int k = j - (128 * 256 + 256 * 256 + 256 * 32);
        if (k < 256) {
            float sc = g1[k] * rsqrtf(v1[k] + 1e-5f);
            s1[k] = sc;
            t1[k] = (b1[k] - m1[k]) * sc + be1[k];
        } else if (k < 512) {
            int kk = k - 256;
            float sc = g2[kk] * rsqrtf(v2[kk] + 1e-5f);
            s2[kk] = sc;
            t2[kk] = (b2[kk] - m2[kk]) * sc + be2[kk];
        }
    }
}

// ---------------- MFMA GEMM: persistent blocks, B in regs, A via LDS -------
// AFP8: A stored fp8 e4m3, decoded (exactly) to bf16 during LDS staging.
// MODE 1: BN+ReLU*dinv bf16. MODE 2: plain bf16.
// MODE 3: BN+ReLU*dinv fp8. MODE 4: plain fp8.
template<int K, int FT, int MODE, bool AFP8, int MINW>
__global__ __launch_bounds__(256, MINW) void g_mfma_lds(
    const void* __restrict__ Av, const u16* __restrict__ Wt,
    void* __restrict__ Cv, int M, int Ftot,
    const float* __restrict__ s, const float* __restrict__ t,
    const float* __restrict__ dinv, int nTiles)
{
    constexpr bool DOBN = (MODE == 1) || (MODE == 3);
    constexpr bool CF8  = (MODE >= 3);
    constexpr int BK  = 128;
    constexpr int SA  = BK + 8;
    constexpr int NH  = K / BK;
    constexpr int NKH = BK / 32;
    constexpr int NF  = FT / 16;
    constexpr int EB  = CF8 ? 1 : 2;
    constexpr int SCB = FT * EB + 16;
    constexpr int EBa = AFP8 ? 1 : 2;
    constexpr int CR  = (BK * EBa) / 16;
    constexpr int LIT = (64 * CR) / 256;

    __shared__ u16 Asmem[2][64 * SA];
    __shared__ u8  Cs8[64 * SCB];

    const u8* Ab = (const u8*)Av;
    int tid = threadIdx.x;
    int w = tid >> 6, l = tid & 63;
    int lr = l & 15, koff8 = (l >> 4) * 8;
    int col0 = blockIdx.y * FT;

    bfx8 bfr[NH][NKH][NF];
    {
        const u16* wp = Wt + (size_t)(col0 + lr) * K + koff8;
        #pragma unroll
        for (int h = 0; h < NH; ++h)
            #pragma unroll
            for (int kk = 0; kk < NKH; ++kk)
                #pragma unroll
                for (int c = 0; c < NF; ++c)
                    bfr[h][kk][c] = *(const bfx8*)(wp + (size_t)c * 16 * K + h * BK + kk * 32);
    }

    int myT = (blockIdx.x < nTiles) ? ((nTiles - 1 - (int)blockIdx.x) / (int)gridDim.x + 1) : 0;
    int NM = myT * NH;
    if (NM == 0) return;

    f32x4 acc[NF];
    #pragma unroll
    for (int c = 0; c < NF; ++c) acc[c] = (f32x4){0.f, 0.f, 0.f, 0.f};

    uint4 rga[LIT];

    auto loadA = [&](int r0, int hh) {
        #pragma unroll
        for (int j = 0; j < LIT; ++j) {
            int cid = j * 256 + tid;
            int row = cid / CR, ch = cid % CR;
            int gr = r0 + row; if (gr > M - 1) gr = M - 1;
            rga[j] = *(const uint4*)(Ab + (size_t)gr * K * EBa + (size_t)hh * BK * EBa + ch * 16);
        }
    };
    auto writeA = [&](int buf) {
        #pragma unroll
        for (int j = 0; j < LIT; ++j) {
            int cid = j * 256 + tid;
            int row = cid / CR, ch = cid % CR;
            if (!AFP8) {
                *(uint4*)&Asmem[buf][row * SA + ch * 8] = rga[j];
            } else {
                u32 w0, w1, w2, w3, w4, w5, w6, w7;
                dec4(rga[j].x, w0, w1);
                dec4(rga[j].y, w2, w3);
                dec4(rga[j].z, w4, w5);
                dec4(rga[j].w, w6, w7);
                uint4 lo4; lo4.x = w0; lo4.y = w1; lo4.z = w2; lo4.w = w3;
                uint4 hi4; hi4.x = w4; hi4.y = w5; hi4.z = w6; hi4.w = w7;
                *(uint4*)&Asmem[buf][row * SA + ch * 16] = lo4;
                *(uint4*)&Asmem[buf][row * SA + ch * 16 + 8] = hi4;
            }
        }
    };

    loadA(blockIdx.x * 64, 0);
    writeA(0);
    if (NM > 1) {
        constexpr int gt1 = 1 / NH, h1 = 1 % NH;
        loadA((blockIdx.x + gt1 * gridDim.x) * 64, h1);
    }
    __syncthreads();

    int cur = 0, gm = 0;
    for (int ti = 0; ti < myT; ++ti) {
        int row0g = (blockIdx.x + ti * gridDim.x) * 64;
        #pragma unroll
        for (int h = 0; h < NH; ++h) {
            const u16* ab = &Asmem[cur][0];
            #pragma unroll
            for (int kk = 0; kk < NKH; ++kk) {
                bfx8 af = *(const bfx8*)(ab + (w * 16 + lr) * SA + koff8 + kk * 32);
                #pragma unroll
                for (int c = 0; c < NF; ++c)
                    acc[c] = __builtin_amdgcn_mfma_f32_16x16x32_bf16(af, bfr[h][kk][c], acc[c], 0, 0, 0);
            }
            if (h == NH - 1) {
                int orow = w * 16 + (l >> 4) * 4;
                float dr[4];
                #pragma unroll
                for (int r = 0; r < 4; ++r) {
                    int grow = row0g + orow + r;
                    dr[r] = DOBN ? ((grow < M) ? dinv[grow] : 0.f) : 1.f;
                }
                #pragma unroll
                for (int c = 0; c < NF; ++c) {
                    int gc = col0 + c * 16 + lr;
                    float sc = DOBN ? s[gc] : 0.f;
                    float tc = DOBN ? t[gc] : 0.f;
                    #pragma unroll
                    for (int r = 0; r < 4; ++r) {
                        float v = acc[c][r];
                        if (DOBN) v = fmaxf(v * sc + tc, 0.f) * dr[r];
                        if (CF8) {
                            int enc = __builtin_amdgcn_cvt_pk_fp8_f32(v, v, 0, false);
                            Cs8[(orow + r) * SCB + (c * 16 + lr)] = (u8)(enc & 0xff);
                        } else {
                            *(u16*)&Cs8[(orow + r) * SCB + (c * 16 + lr) * 2] = f2bf(v);
                        }
                    }
                    acc[c] = (f32x4){0.f, 0.f, 0.f, 0.f};
                }
            }
            __syncthreads();
            if (gm + 1 < NM) writeA(cur ^ 1);
            if (h == NH - 1) {
                constexpr int CPR = (FT * EB) / 16;
                constexpr int TOT = 64 * CPR;
                constexpr int CPT = (TOT + 255) / 256;
                u8* C8 = (u8*)Cv;
                #pragma unroll
                for (int j = 0; j < CPT; ++j) {
                    int cid = j * 256 + tid;
                    if (cid < TOT) {
                        int crow = cid / CPR;
                        int cb = (cid % CPR) * 16;
                        int grow = row0g + crow;
                        if (grow < M) {
                            us8 vv = *(const us8*)&Cs8[crow * SCB + cb];
                            *(us8*)(C8 + (size_t)grow * Ftot * EB + (size_t)col0 * EB + cb) = vv;
                        }
                    }
                }
            }
            if (gm + 2 < NM) {
                int g2 = gm + 2;
                int gt2 = g2 / NH, h2 = g2 % NH;
                loadA((blockIdx.x + gt2 * gridDim.x) * 64, h2);
            }
            __syncthreads();
            cur ^= 1; ++gm;
        }
    }
}

// ---------------- Aggregation ----------------
// agg_x: F=128 fp8 in/out. 32 lanes/node, lane owns 4 fp8. 8-edge unroll.
__global__ __launch_bounds__(256) void agg_x(const u8* __restrict__ in,
                                             u8* __restrict__ outp,
                                             const int* __restrict__ row_ptr,
                                             const int* __restrict__ csr_src,
                                             const float* __restrict__ dinv,
                                             int nnodes) {
    int tid = threadIdx.x;
    int wv = tid >> 6, lane = tid & 63;
    int half = lane >> 5, l32 = lane & 31;
    int node = (blockIdx.x * 4 + wv) * 2 + half;
    if (node >= nnodes) return;
    int off = l32 * 4;
    const u8* bp = in + off;
    float a0, a1, a2, a3;
    {
        u32 q = *(const u32*)(in + (size_t)node * 128 + off);
        f32x2 p;
        p = __builtin_amdgcn_cvt_pk_f32_fp8(q, false); a0 = p[0]; a1 = p[1];
        p = __builtin_amdgcn_cvt_pk_f32_fp8(q, true);  a2 = p[0]; a3 = p[1];
    }
    int e = row_ptr[node], e1 = row_ptr[node + 1];
    for (; e + 8 <= e1; e += 8) {
        int sx[8];
        #pragma unroll
        for (int q = 0; q < 8; ++q) sx[q] = csr_src[e + q];
        u32 vv[8];
        #pragma unroll
        for (int q = 0; q < 8; ++q) vv[q] = *(const u32*)(bp + (size_t)sx[q] * 128);
        #pragma unroll
        for (int q = 0; q < 8; ++q) {
            f32x2 p;
            p = __builtin_amdgcn_cvt_pk_f32_fp8(vv[q], false); a0 += p[0]; a1 += p[1];
            p = __builtin_amdgcn_cvt_pk_f32_fp8(vv[q], true);  a2 += p[0]; a3 += p[1];
        }
    }
    for (; e < e1; ++e) {
        int s0 = csr_src[e];
        u32 v0 = *(const u32*)(bp + (size_t)s0 * 128);
        f32x2 p;
        p = __builtin_amdgcn_cvt_pk_f32_fp8(v0, false); a0 += p[0]; a1 += p[1];
        p = __builtin_amdgcn_cvt_pk_f32_fp8(v0, true);  a2 += p[0]; a3 += p[1];
    }
    float d = dinv[node];
    u32 pk = 0;
    pk = __builtin_amdgcn_cvt_pk_fp8_f32(a0 * d, a1 * d, pk, false);
    pk = __builtin_amdgcn_cvt_pk_fp8_f32(a2 * d, a3 * d, pk, true);
    *(u32*)(outp + (size_t)node * 128 + off) = pk;
}

// agg_h: F=256 fp8 in/out. 32 lanes/node, lane owns 8 features (8B).
__global__ __launch_bounds__(256) void agg_h(const u8* __restrict__ in,
                                             u8* __restrict__ outp,
                                             const int* __restrict__ row_ptr,
                                             const int* __restrict__ csr_src,
                                             const float* __restrict__ dinv,
                                             int nnodes) {
    int tid = threadIdx.x;
    int wv = tid >> 6, lane = tid & 63;
    int half = lane >> 5, l32 = lane & 31;
    int node = (blockIdx.x * 4 + wv) * 2 + half;
    if (node >= nnodes) return;
    int off = l32 * 8;
    const u8* bp = in + off;
    float acc[8];
    {
        uint2 q = *(const uint2*)(in + (size_t)node * 256 + off);
        f32x2 p;
        p = __builtin_amdgcn_cvt_pk_f32_fp8(q.x, false); acc[0] = p[0]; acc[1] = p[1];
        p = __builtin_amdgcn_cvt_pk_f32_fp8(q.x, true);  acc[2] = p[0]; acc[3] = p[1];
        p = __builtin_amdgcn_cvt_pk_f32_fp8(q.y, false); acc[4] = p[0]; acc[5] = p[1];
        p = __builtin_amdgcn_cvt_pk_f32_fp8(q.y, true);  acc[6] = p[0]; acc[7] = p[1];
    }
    int e = row_ptr[node], e1 = row_ptr[node + 1];
    for (; e + 8 <= e1; e += 8) {
        int sx[8];
        #pragma unroll
        for (int q = 0; q < 8; ++q) sx[q] = csr_src[e + q];
        uint2 vv[8];
        #pragma unroll
        for (int q = 0; q < 8; ++q) vv[q] = *(const uint2*)(bp + (size_t)sx[q] * 256);
        #pragma unroll
        for (int q = 0; q < 8; ++q) {
            f32x2 p;
            p = __builtin_amdgcn_cvt_pk_f32_fp8(vv[q].x, false); acc[0] += p[0]; acc[1] += p[1];
            p = __builtin_amdgcn_cvt_pk_f32_fp8(vv[q].x, true);  acc[2] += p[0]; acc[3] += p[1];
            p = __builtin_amdgcn_cvt_pk_f32_fp8(vv[q].y, false); acc[4] += p[0]; acc[5] += p[1];
            p = __builtin_amdgcn_cvt_pk_f32_fp8(vv[q].y, true);  acc[6] += p[0]; acc[7] += p[1];
        }
    }
    for (; e < e1; ++e) {
        int s0 = csr_src[e];
        uint2 v0 = *(const uint2*)(bp + (size_t)s0 * 256);
        f32x2 p;
        p = __builtin_amdgcn_cvt_pk_f32_fp8(v0.x, false); acc[0] += p[0]; acc[1] += p[1];
        p = __builtin_amdgcn_cvt_pk_f32_fp8(v0.x, true);  acc[2] += p[0]; acc[3] += p[1];
        p = __builtin_amdgcn_cvt_pk_f32_fp8(v0.y, false); acc[4] += p[0]; acc[5] += p[1];
        p = __builtin_amdgcn_cvt_pk_f32_fp8(v0.y, true);  acc[6] += p[0]; acc[7] += p[1];
    }
    float d = dinv[node];
    u32 w0 = 0, w1 = 0;
    w0 = __builtin_amdgcn_cvt_pk_fp8_f32(acc[0] * d, acc[1] * d, w0, false);
    w0 = __builtin_amdgcn_cvt_pk_fp8_f32(acc[2] * d, acc[3] * d, w0, true);
    w1 = __builtin_amdgcn_cvt_pk_fp8_f32(acc[4] * d, acc[5] * d, w1, false);
    w1 = __builtin_amdgcn_cvt_pk_fp8_f32(acc[6] * d, acc[7] * d, w1, true);
    uint2 o; o.x = w0; o.y = w1;
    *(uint2*)(outp + (size_t)node * 256 + off) = o;
}

// agg32: F=32 fp8 in, f32 sigmoid out. 8 lanes/node (4 features each).
__global__ __launch_bounds__(256) void agg32_sig(const u8* __restrict__ zq,
                                                 float* __restrict__ out,
                                                 const int* __restrict__ row_ptr,
                                                 const int* __restrict__ csr_src,
                                                 const float* __restrict__ dinv,
                                                 const float* __restrict__ b3,
                                                 int nnodes) {
    int tid = threadIdx.x;
    int grp = tid >> 3, l8 = tid & 7;
    int node = blockIdx.x * 32 + grp;
    if (node >= nnodes) return;
    int off = l8 * 4;   // byte offset = feature offset (1B/feature)
    const u8* bp = zq + off;
    float a0, a1, a2, a3;
    {
        u32 q = *(const u32*)(zq + (size_t)node * 32 + off);
        f32x2 p;
        p = __builtin_amdgcn_cvt_pk_f32_fp8(q, false); a0 = p[0]; a1 = p[1];
        p = __builtin_amdgcn_cvt_pk_f32_fp8(q, true);  a2 = p[0]; a3 = p[1];
    }
    int e = row_ptr[node], e1 = row_ptr[node + 1];
    for (; e + 8 <= e1; e += 8) {
        int sx[8];
        #pragma unroll
        for (int q = 0; q < 8; ++q) sx[q] = csr_src[e + q];
        u32 vv[8];
        #pragma unroll
        for (int q = 0; q < 8; ++q) vv[q] = *(const u32*)(bp + (size_t)sx[q] * 32);
        #pragma unroll
        for (int q = 0; q < 8; ++q) {
            f32x2 p;
            p = __builtin_amdgcn_cvt_pk_f32_fp8(vv[q], false); a0 += p[0]; a1 += p[1];
            p = __builtin_amdgcn_cvt_pk_f32_fp8(vv[q], true);  a2 += p[0]; a3 += p[1];
        }
    }
    for (; e < e1; ++e) {
        int s0 = csr_src[e];
        u32 v0 = *(const u32*)(bp + (size_t)s0 * 32);
        f32x2 p;
        p = __builtin_amdgcn_cvt_pk_f32_fp8(v0, false); a0 += p[0]; a1 += p[1];
        p = __builtin_amdgcn_cvt_pk_f32_fp8(v0, true);  a2 += p[0]; a3 += p[1];
    }
    float d = dinv[node];
    int fb = l8 * 4;
    float4 o;
    o.x = 1.f / (1.f + expf(-(a0 * d + b3[fb + 0])));
    o.y = 1.f / (1.f + expf(-(a1 * d + b3[fb + 1])));
    o.z = 1.f / (1.f + expf(-(a2 * d + b3[fb + 2])));
    o.w = 1.f / (1.f + expf(-(a3 * d + b3[fb + 3])));
    *(float4*)(out + (size_t)node * 32 + fb) = o;
}

// ---------------- launch ----------------

extern "C" void kernel_launch(void* const* d_in, const int* in_sizes, int n_in,
                              void* d_out, int out_size, void* d_ws, size_t ws_size,
                              hipStream_t stream) {
    const float* x  = (const float*)d_in[0];
    const int*   ei = (const int*)d_in[1];
    const float* W1 = (const float*)d_in[2];
    const float* b1 = (const float*)d_in[3];
    const float* g1 = (const float*)d_in[4];
    const float* be1 = (const float*)d_in[5];
    const float* m1 = (const float*)d_in[6];
    const float* v1 = (const float*)d_in[7];
    const float* W2 = (const float*)d_in[8];
    const float* b2 = (const float*)d_in[9];
    const float* g2 = (const float*)d_in[10];
    const float* be2 = (const float*)d_in[11];
    const float* m2 = (const float*)d_in[12];
    const float* v2 = (const float*)d_in[13];
    const float* W3 = (const float*)d_in[14];
    const float* b3 = (const float*)d_in[15];
    float* out = (float*)d_out;

    const int N = in_sizes[0] / 128;   // 100000
    const int E = in_sizes[1] / 2;     // 1600000

    const int NB = (N + 511) >> 9;
    const int NBLK = (E + 2047) / 2048;

    char* w = (char*)d_ws;
    auto alloc = [&](size_t bytes) -> void* {
        void* p = (void*)w;
        w += (bytes + 255) & ~(size_t)255;
        return p;
    };
    int* row_ptr   = (int*)alloc((size_t)(N + 1) * 4);
    float* dinv    = (float*)alloc((size_t)N * 4);
    u32* cnt_pb    = (u32*)alloc((size_t)NB * NBLK * 4);
    u32* bases_pb  = (u32*)alloc((size_t)NB * NBLK * 4);
    u32* bkt_tot   = (u32*)alloc((size_t)NB * 4);
    u32* bkt_edges = (u32*)alloc((size_t)E * 4);
    float* s1 = (float*)alloc(256 * 4);
    float* t1 = (float*)alloc(256 * 4);
    float* s2 = (float*)alloc(256 * 4);
    float* t2 = (float*)alloc(256 * 4);
    u16* Wt1 = (u16*)alloc((size_t)128 * 256 * 2);
    u16* Wt2 = (u16*)alloc((size_t)256 * 256 * 2);
    u16* Wt3 = (u16*)alloc((size_t)256 * 32 * 2);
    int* csr_src = (int*)alloc((size_t)E * 4);
    u8*  xq   = (u8*)alloc((size_t)N * 128);   // x*dinv fp8; reused as z3 fp8
    u8*  xa   = (u8*)alloc((size_t)N * 128);   // agg_x out fp8
    u8*  h1q  = (u8*)alloc((size_t)N * 256);   // GEMM1 out fp8
    u8*  h1a  = (u8*)alloc((size_t)N * 256);   // agg_h out fp8
    u8*  h2q  = (u8*)alloc((size_t)N * 256);   // GEMM2 out fp8
    u8*  z3 = xq;                              // N*32 fp8 = 3.2MB <= 12.8MB

    int nT = (N + 63) / 64;
    int gagg = (N + 7) / 8;
    int n4 = N * 128 / 4;
    int prepTot = n4 + 128 * 256 + 256 * 256 + 256 * 32 + 512;

    // CSR build: bucket sort, no global atomics (4 kernels)
    k_hist<<<NBLK, 256, 0, stream>>>(ei, cnt_pb, E, NB, NBLK);
    k_scanb<<<NB, 1024, 0, stream>>>(cnt_pb, bases_pb, bkt_tot, NBLK);
    k_scatter2<<<NBLK, 256, 0, stream>>>(ei, bases_pb, bkt_tot, bkt_edges, E, NB, NBLK);
    k_bucket<<<NB, 512, 0, stream>>>(bkt_edges, bkt_tot, row_ptr, dinv, csr_src, N, NB, E);

    // fused param prep (needs dinv)
    k_prep<<<(prepTot + 255) / 256, 256, 0, stream>>>(
        x, xq, dinv, n4, W1, Wt1, W2, Wt2, W3, Wt3,
        b1, g1, be1, m1, v1, s1, t1, b2, g2, be2, m2, v2, s2, t2);

    // Layer 1: agg(xq fp8) -> fp8 xa -> GEMM(128->256)+BN+ReLU+dinv -> fp8 h1q
    agg_x<<<gagg, 256, 0, stream>>>(xq, xa, row_ptr, csr_src, dinv, N);
    g_mfma_lds<128, 64, 3, true, 2><<<dim3(128, 4), 256, 0, stream>>>(
        (const void*)xa, Wt1, (void*)h1q, N, 256, s1, t1, dinv, nT);

    // Layer 2: agg(h1q fp8) -> fp8 h1a -> GEMM(256->256)+BN+ReLU+dinv -> fp8 h2q
    agg_h<<<gagg, 256, 0, stream>>>(h1q, h1a, row_ptr, csr_src, dinv, N);
    g_mfma_lds<256, 64, 3, true, 2><<<dim3(128, 4), 256, 0, stream>>>(
        (const void*)h1a, Wt2, (void*)h2q, N, 256, s2, t2, dinv, nT);

    // Layer 3: GEMM(256->32) fp8 A -> fp8 z3, then agg + b3 + sigmoid
    g_mfma_lds<256, 32, 4, true, 2><<<dim3(512, 1), 256, 0, stream>>>(
        (const void*)h2q, Wt3, (void*)z3, N, 32, (const float*)nullptr,
        (const float*)nullptr, (const float*)nullptr, nT);
    agg32_sig<<<(N + 31) / 32, 256, 0, stream>>>(z3, out, row_ptr, csr_src, dinv, b3, N);
}

// Round 15
// 231.300 us; speedup vs baseline: 1.8881x; 1.0877x over previous
//
#include <hip/hip_runtime.h>
#include <math.h>

typedef unsigned short u16;
typedef unsigned char u8;
typedef unsigned int u32;
typedef __attribute__((ext_vector_type(8))) __bf16 bfx8;
typedef __attribute__((ext_vector_type(4))) float f32x4;
typedef __attribute__((ext_vector_type(2))) float f32x2;
typedef __attribute__((ext_vector_type(8))) unsigned short us8;

__device__ inline u16 f2bf(float f) {
    union { float f; unsigned int i; } v;
    v.f = f;
    unsigned int b = v.i;
    return (u16)((b + 0x7FFFu + ((b >> 16) & 1u)) >> 16);
}
__device__ inline u32 bits_of(float f) {
    union { float f; u32 i; } v; v.f = f; return v.i;
}
__device__ inline u32 pkbf(float a, float b) {
    return (bits_of(a) >> 16) | (bits_of(b) & 0xffff0000u);
}
// decode 4 fp8 (one dword) -> 2 u32 of packed bf16 (exact)
__device__ inline void dec4(u32 d, u32& lo, u32& hi) {
    f32x2 a = __builtin_amdgcn_cvt_pk_f32_fp8(d, false);
    f32x2 b = __builtin_amdgcn_cvt_pk_f32_fp8(d, true);
    lo = pkbf(a[0], a[1]);
    hi = pkbf(b[0], b[1]);
}

// ---------------- CSR build: bucket sort, LDS atomics only ----------------
// k_hist also runs the parameter prep in extra blocks (blk >= NBLK).

__global__ __launch_bounds__(256) void k_hist(
    const int* __restrict__ ei, u32* __restrict__ cnt_pb, int E, int NB, int NBLK,
    const float* __restrict__ W1, u16* __restrict__ Wt1,
    const float* __restrict__ W2, u16* __restrict__ Wt2,
    const float* __restrict__ W3, u16* __restrict__ Wt3,
    const float* __restrict__ b1, const float* __restrict__ g1, const float* __restrict__ be1,
    const float* __restrict__ m1, const float* __restrict__ v1,
    float* __restrict__ s1, float* __restrict__ t1,
    const float* __restrict__ b2, const float* __restrict__ g2, const float* __restrict__ be2,
    const float* __restrict__ m2, const float* __restrict__ v2,
    float* __restrict__ s2, float* __restrict__ t2)
{
    int blk = blockIdx.x, tid = threadIdx.x;
    if (blk >= NBLK) {
        int j = (blk - NBLK) * 256 + tid;
        if (j < 128 * 256) {
            int k = j / 256, f = j % 256;
            Wt1[(size_t)f * 128 + k] = f2bf(W1[j]);
        } else if (j < 128 * 256 + 256 * 256) {
            int j2 = j - 128 * 256;
            int k = j2 / 256, f = j2 % 256;
            Wt2[(size_t)f * 256 + k] = f2bf(W2[j2]);
        } else if (j < 128 * 256 + 256 * 256 + 256 * 32) {
            int j3 = j - (128 * 256 + 256 * 256);
            int k = j3 / 32, f = j3 % 32;
            Wt3[(size_t)f * 256 + k] = f2bf(W3[j3]);
        } else {
            int k = j - (128 * 256 + 256 * 256 + 256 * 32);
            if (k < 256) {
                float sc = g1[k] * rsqrtf(v1[k] + 1e-5f);
                s1[k] = sc;
                t1[k] = (b1[k] - m1[k]) * sc + be1[k];
            } else if (k < 512) {
                int kk = k - 256;
                float sc = g2[kk] * rsqrtf(v2[kk] + 1e-5f);
                s2[kk] = sc;
                t2[kk] = (b2[kk] - m2[kk]) * sc + be2[kk];
            }
        }
        return;
    }
    __shared__ u32 h[256];
    h[tid] = 0;
    __syncthreads();
    int eend = min(E, (blk + 1) * 2048);
    for (int e = blk * 2048 + tid; e < eend; e += 256) {
        int d = ei[E + e];
        atomicAdd(&h[d >> 9], 1u);
    }
    __syncthreads();
    if (tid < NB) cnt_pb[(size_t)tid * NBLK + blk] = h[tid];
}

__global__ __launch_bounds__(1024) void k_scanb(const u32* __restrict__ cnt_pb,
                                                u32* __restrict__ bases_pb,
                                                u32* __restrict__ bkt_tot,
                                                int NBLK) {
    __shared__ u32 lds[1024];
    int b = blockIdx.x, t = threadIdx.x;
    u32 v = (t < NBLK) ? cnt_pb[(size_t)b * NBLK + t] : 0u;
    lds[t] = v;
    __syncthreads();
    for (int off = 1; off < 1024; off <<= 1) {
        u32 x = lds[t];
        u32 y = (t >= off) ? lds[t - off] : 0u;
        __syncthreads();
        lds[t] = x + y;
        __syncthreads();
    }
    if (t < NBLK) bases_pb[(size_t)b * NBLK + t] = lds[t] - v;
    if (t == NBLK - 1) bkt_tot[b] = lds[t];
}

__global__ __launch_bounds__(256) void k_scatter2(const int* __restrict__ ei,
                                                  const u32* __restrict__ bases_pb,
                                                  const u32* __restrict__ bkt_tot,
                                                  u32* __restrict__ bkt_edges,
                                                  int E, int NB, int NBLK) {
    __shared__ u32 cur[256];
    __shared__ u32 bb[256];
    int blk = blockIdx.x, tid = threadIdx.x;
    u32 v = (tid < NB) ? bkt_tot[tid] : 0u;
    bb[tid] = v;
    __syncthreads();
    for (int off = 1; off < 256; off <<= 1) {
        u32 x = bb[tid];
        u32 y = (tid >= off) ? bb[tid - off] : 0u;
        __syncthreads();
        bb[tid] = x + y;
        __syncthreads();
    }
    u32 excl = bb[tid] - v;
    __syncthreads();
    bb[tid] = excl;
    if (tid < NB) cur[tid] = bases_pb[(size_t)tid * NBLK + blk];
    __syncthreads();
    int eend = min(E, (blk + 1) * 2048);
    for (int e = blk * 2048 + tid; e < eend; e += 256) {
        int s = ei[e];
        int d = ei[E + e];
        int b = d >> 9;
        int dl = d & 511;
        u32 off = atomicAdd(&cur[b], 1u);
        bkt_edges[bb[b] + off] = (u32)s | ((u32)dl << 17);
    }
}

// per-bucket CSR build + x->fp8 conversion for this bucket's nodes
__global__ __launch_bounds__(512) void k_bucket(const u32* __restrict__ bkt_edges,
                                                const u32* __restrict__ bkt_tot,
                                                int* __restrict__ row_ptr,
                                                float* __restrict__ dinv,
                                                int* __restrict__ csr_src,
                                                const float* __restrict__ x,
                                                u8* __restrict__ xq,
                                                int N, int NB, int E) {
    __shared__ u32 sb[256];
    __shared__ u32 lcnt[512];
    __shared__ u32 lscan[512];
    int b = blockIdx.x, t = threadIdx.x;
    if (t < 256) sb[t] = (t < NB) ? bkt_tot[t] : 0u;
    __syncthreads();
    for (int off = 1; off < 256; off <<= 1) {
        u32 x0 = 0, y0 = 0;
        if (t < 256) { x0 = sb[t]; y0 = (t >= off) ? sb[t - off] : 0u; }
        __syncthreads();
        if (t < 256) sb[t] = x0 + y0;
        __syncthreads();
    }
    int ce = (int)bkt_tot[b];
    int es = (int)sb[b] - ce;
    int node0 = b << 9;
    lcnt[t] = 0;
    __syncthreads();
    for (int i = t; i < ce; i += 512) {
        u32 p = bkt_edges[es + i];
        atomicAdd(&lcnt[p >> 17], 1u);
    }
    __syncthreads();
    lscan[t] = lcnt[t];
    __syncthreads();
    for (int off = 1; off < 512; off <<= 1) {
        u32 x0 = lscan[t];
        u32 y0 = (t >= off) ? lscan[t - off] : 0u;
        __syncthreads();
        lscan[t] = x0 + y0;
        __syncthreads();
    }
    u32 excl = lscan[t] - lcnt[t];
    int node = node0 + t;
    float my_d = rsqrtf((float)lcnt[t] + 1.0f);
    if (node < N) {
        row_ptr[node] = es + (int)excl;
        dinv[node] = my_d;
    }
    if (b == 0 && t == 0) row_ptr[N] = E;
    __syncthreads();
    lscan[t] = excl;
    __syncthreads();
    for (int i = t; i < ce; i += 512) {
        u32 p = bkt_edges[es + i];
        int dl = (int)(p >> 17);
        int src = (int)(p & 0x1FFFFu);
        u32 pos = atomicAdd(&lscan[dl], 1u);
        csr_src[es + pos] = src;
    }
    // x -> fp8*dinv for this bucket's nodes
    __syncthreads();
    ((float*)lcnt)[t] = my_d;
    __syncthreads();
    const float* df = (const float*)lcnt;
    for (int i = t; i < 512 * 32; i += 512) {
        int r = i >> 5;
        int row = node0 + r;
        if (row < N) {
            float d = df[r];
            float4 v = *(const float4*)(x + (size_t)row * 128 + (i & 31) * 4);
            u32 pk = 0;
            pk = __builtin_amdgcn_cvt_pk_fp8_f32(v.x * d, v.y * d, pk, false);
            pk = __builtin_amdgcn_cvt_pk_fp8_f32(v.z * d, v.w * d, pk, true);
            *(u32*)(xq + (size_t)row * 128 + (i & 31) * 4) = pk;
        }
    }
    if (b == 0 && t < 32) *(u32*)(xq + (size_t)N * 128 + t * 4) = 0;  // zero pad row
}

// ---------------- MFMA GEMM: persistent blocks, B in regs, A via LDS -------
// AFP8: A stored fp8, decoded exactly to bf16 at LDS staging.
// MODE 1: BN+ReLU*dinv bf16. MODE 2: plain bf16.
// MODE 3: BN+ReLU*dinv fp8. MODE 4: plain fp8.
// fp8 C modes also zero pad-row M (for downstream gather padding).
template<int K, int FT, int MODE, bool AFP8, int MINW>
__global__ __launch_bounds__(256, MINW) void g_mfma_lds(
    const void* __restrict__ Av, const u16* __restrict__ Wt,
    void* __restrict__ Cv, int M, int Ftot,
    const float* __restrict__ s, const float* __restrict__ t,
    const float* __restrict__ dinv, int nTiles)
{
    constexpr bool DOBN = (MODE == 1) || (MODE == 3);
    constexpr bool CF8  = (MODE >= 3);
    constexpr int BK  = 128;
    constexpr int SA  = BK + 8;
    constexpr int NH  = K / BK;
    constexpr int NKH = BK / 32;
    constexpr int NF  = FT / 16;
    constexpr int EB  = CF8 ? 1 : 2;
    constexpr int SCB = FT * EB + 16;
    constexpr int EBa = AFP8 ? 1 : 2;
    constexpr int CR  = (BK * EBa) / 16;
    constexpr int LIT = (64 * CR) / 256;

    __shared__ u16 Asmem[2][64 * SA];
    __shared__ u8  Cs8[64 * SCB];

    const u8* Ab = (const u8*)Av;
    int tid = threadIdx.x;
    int w = tid >> 6, l = tid & 63;
    int lr = l & 15, koff8 = (l >> 4) * 8;
    int col0 = blockIdx.y * FT;

    // zero pad-row M (fp8 outputs only; done once by block (0,0))
    if (CF8 && blockIdx.x == 0 && blockIdx.y == 0) {
        if (tid * 4 < Ftot) *(u32*)((u8*)Cv + (size_t)M * Ftot + tid * 4) = 0;
    }

    bfx8 bfr[NH][NKH][NF];
    {
        const u16* wp = Wt + (size_t)(col0 + lr) * K + koff8;
        #pragma unroll
        for (int h = 0; h < NH; ++h)
            #pragma unroll
            for (int kk = 0; kk < NKH; ++kk)
                #pragma unroll
                for (int c = 0; c < NF; ++c)
                    bfr[h][kk][c] = *(const bfx8*)(wp + (size_t)c * 16 * K + h * BK + kk * 32);
    }

    int myT = (blockIdx.x < nTiles) ? ((nTiles - 1 - (int)blockIdx.x) / (int)gridDim.x + 1) : 0;
    int NM = myT * NH;
    if (NM == 0) return;

    f32x4 acc[NF];
    #pragma unroll
    for (int c = 0; c < NF; ++c) acc[c] = (f32x4){0.f, 0.f, 0.f, 0.f};

    uint4 rga[LIT];

    auto loadA = [&](int r0, int hh) {
        #pragma unroll
        for (int j = 0; j < LIT; ++j) {
            int cid = j * 256 + tid;
            int row = cid / CR, ch = cid % CR;
            int gr = r0 + row; if (gr > M - 1) gr = M - 1;
            rga[j] = *(const uint4*)(Ab + (size_t)gr * K * EBa + (size_t)hh * BK * EBa + ch * 16);
        }
    };
    auto writeA = [&](int buf) {
        #pragma unroll
        for (int j = 0; j < LIT; ++j) {
            int cid = j * 256 + tid;
            int row = cid / CR, ch = cid % CR;
            if (!AFP8) {
                *(uint4*)&Asmem[buf][row * SA + ch * 8] = rga[j];
            } else {
                u32 w0, w1, w2, w3, w4, w5, w6, w7;
                dec4(rga[j].x, w0, w1);
                dec4(rga[j].y, w2, w3);
                dec4(rga[j].z, w4, w5);
                dec4(rga[j].w, w6, w7);
                uint4 lo4; lo4.x = w0; lo4.y = w1; lo4.z = w2; lo4.w = w3;
                uint4 hi4; hi4.x = w4; hi4.y = w5; hi4.z = w6; hi4.w = w7;
                *(uint4*)&Asmem[buf][row * SA + ch * 16] = lo4;
                *(uint4*)&Asmem[buf][row * SA + ch * 16 + 8] = hi4;
            }
        }
    };

    loadA(blockIdx.x * 64, 0);
    writeA(0);
    if (NM > 1) {
        constexpr int gt1 = 1 / NH, h1 = 1 % NH;
        loadA((blockIdx.x + gt1 * gridDim.x) * 64, h1);
    }
    __syncthreads();

    int cur = 0, gm = 0;
    for (int ti = 0; ti < myT; ++ti) {
        int row0g = (blockIdx.x + ti * gridDim.x) * 64;
        #pragma unroll
        for (int h = 0; h < NH; ++h) {
            const u16* ab = &Asmem[cur][0];
            #pragma unroll
            for (int kk = 0; kk < NKH; ++kk) {
                bfx8 af = *(const bfx8*)(ab + (w * 16 + lr) * SA + koff8 + kk * 32);
                #pragma unroll
                for (int c = 0; c < NF; ++c)
                    acc[c] = __builtin_amdgcn_mfma_f32_16x16x32_bf16(af, bfr[h][kk][c], acc[c], 0, 0, 0);
            }
            if (h == NH - 1) {
                int orow = w * 16 + (l >> 4) * 4;
                float dr[4];
                #pragma unroll
                for (int r = 0; r < 4; ++r) {
                    int grow = row0g + orow + r;
                    dr[r] = DOBN ? ((grow < M) ? dinv[grow] : 0.f) : 1.f;
                }
                #pragma unroll
                for (int c = 0; c < NF; ++c) {
                    int gc = col0 + c * 16 + lr;
                    float sc = DOBN ? s[gc] : 0.f;
                    float tc = DOBN ? t[gc] : 0.f;
                    #pragma unroll
                    for (int r = 0; r < 4; ++r) {
                        float v = acc[c][r];
                        if (DOBN) v = fmaxf(v * sc + tc, 0.f) * dr[r];
                        if (CF8) {
                            int enc = __builtin_amdgcn_cvt_pk_fp8_f32(v, v, 0, false);
                            Cs8[(orow + r) * SCB + (c * 16 + lr)] = (u8)(enc & 0xff);
                        } else {
                            *(u16*)&Cs8[(orow + r) * SCB + (c * 16 + lr) * 2] = f2bf(v);
                        }
                    }
                    acc[c] = (f32x4){0.f, 0.f, 0.f, 0.f};
                }
            }
            __syncthreads();
            if (gm + 1 < NM) writeA(cur ^ 1);
            if (h == NH - 1) {
                constexpr int CPR = (FT * EB) / 16;
                constexpr int TOT = 64 * CPR;
                constexpr int CPT = (TOT + 255) / 256;
                u8* C8 = (u8*)Cv;
                #pragma unroll
                for (int j = 0; j < CPT; ++j) {
                    int cid = j * 256 + tid;
                    if (cid < TOT) {
                        int crow = cid / CPR;
                        int cb = (cid % CPR) * 16;
                        int grow = row0g + crow;
                        if (grow < M) {
                            us8 vv = *(const us8*)&Cs8[crow * SCB + cb];
                            *(us8*)(C8 + (size_t)grow * Ftot * EB + (size_t)col0 * EB + cb) = vv;
                        }
                    }
                }
            }
            if (gm + 2 < NM) {
                int g2 = gm + 2;
                int gt2 = g2 / NH, h2 = g2 % NH;
                loadA((blockIdx.x + gt2 * gridDim.x) * 64, h2);
            }
            __syncthreads();
            cur ^= 1; ++gm;
        }
    }
}

// ---------------- Aggregation (masked 8-batches, zero-row padding) ---------
// agg_x: F=128 fp8 in/out. 32 lanes/node, lane owns 4 fp8.
__global__ __launch_bounds__(256) void agg_x(const u8* __restrict__ in,
                                             u8* __restrict__ outp,
                                             const int* __restrict__ row_ptr,
                                             const int* __restrict__ csr_src,
                                             const float* __restrict__ dinv,
                                             int nnodes) {
    int tid = threadIdx.x;
    int wv = tid >> 6, lane = tid & 63;
    int half = lane >> 5, l32 = lane & 31;
    int node = (blockIdx.x * 4 + wv) * 2 + half;
    if (node >= nnodes) return;
    int off = l32 * 4;
    const u8* bp = in + off;
    float a0, a1, a2, a3;
    {
        u32 q = *(const u32*)(in + (size_t)node * 128 + off);
        f32x2 p;
        p = __builtin_amdgcn_cvt_pk_f32_fp8(q, false); a0 = p[0]; a1 = p[1];
        p = __builtin_amdgcn_cvt_pk_f32_fp8(q, true);  a2 = p[0]; a3 = p[1];
    }
    int e = row_ptr[node], e1 = row_ptr[node + 1];
    for (; e < e1; e += 8) {
        int sx[8];
        #pragma unroll
        for (int q = 0; q < 8; ++q) {
            int ee = e + q;
            int vsrc = csr_src[ee < e1 ? ee : e];
            sx[q] = (ee < e1) ? vsrc : nnodes;
        }
        u32 vv[8];
        #pragma unroll
        for (int q = 0; q < 8; ++q) vv[q] = *(const u32*)(bp + (size_t)sx[q] * 128);
        #pragma unroll
        for (int q = 0; q < 8; ++q) {
            f32x2 p;
            p = __builtin_amdgcn_cvt_pk_f32_fp8(vv[q], false); a0 += p[0]; a1 += p[1];
            p = __builtin_amdgcn_cvt_pk_f32_fp8(vv[q], true);  a2 += p[0]; a3 += p[1];
        }
    }
    float d = dinv[node];
    u32 pk = 0;
    pk = __builtin_amdgcn_cvt_pk_fp8_f32(a0 * d, a1 * d, pk, false);
    pk = __builtin_amdgcn_cvt_pk_fp8_f32(a2 * d, a3 * d, pk, true);
    *(u32*)(outp + (size_t)node * 128 + off) = pk;
}

// agg_h: F=256 fp8 in/out. 32 lanes/node, lane owns 8 features (8B).
__global__ __launch_bounds__(256) void agg_h(const u8* __restrict__ in,
                                             u8* __restrict__ outp,
                                             const int* __restrict__ row_ptr,
                                             const int* __restrict__ csr_src,
                                             const float* __restrict__ dinv,
                                             int nnodes) {
    int tid = threadIdx.x;
    int wv = tid >> 6, lane = tid & 63;
    int half = lane >> 5, l32 = lane & 31;
    int node = (blockIdx.x * 4 + wv) * 2 + half;
    if (node >= nnodes) return;
    int off = l32 * 8;
    const u8* bp = in + off;
    float acc[8];
    {
        uint2 q = *(const uint2*)(in + (size_t)node * 256 + off);
        f32x2 p;
        p = __builtin_amdgcn_cvt_pk_f32_fp8(q.x, false); acc[0] = p[0]; acc[1] = p[1];
        p = __builtin_amdgcn_cvt_pk_f32_fp8(q.x, true);  acc[2] = p[0]; acc[3] = p[1];
        p = __builtin_amdgcn_cvt_pk_f32_fp8(q.y, false); acc[4] = p[0]; acc[5] = p[1];
        p = __builtin_amdgcn_cvt_pk_f32_fp8(q.y, true);  acc[6] = p[0]; acc[7] = p[1];
    }
    int e = row_ptr[node], e1 = row_ptr[node + 1];
    for (; e < e1; e += 8) {
        int sx[8];
        #pragma unroll
        for (int q = 0; q < 8; ++q) {
            int ee = e + q;
            int vsrc = csr_src[ee < e1 ? ee : e];
            sx[q] = (ee < e1) ? vsrc : nnodes;
        }
        uint2 vv[8];
        #pragma unroll
        for (int q = 0; q < 8; ++q) vv[q] = *(const uint2*)(bp + (size_t)sx[q] * 256);
        #pragma unroll
        for (int q = 0; q < 8; ++q) {
            f32x2 p;
            p = __builtin_amdgcn_cvt_pk_f32_fp8(vv[q].x, false); acc[0] += p[0]; acc[1] += p[1];
            p = __builtin_amdgcn_cvt_pk_f32_fp8(vv[q].x, true);  acc[2] += p[0]; acc[3] += p[1];
            p = __builtin_amdgcn_cvt_pk_f32_fp8(vv[q].y, false); acc[4] += p[0]; acc[5] += p[1];
            p = __builtin_amdgcn_cvt_pk_f32_fp8(vv[q].y, true);  acc[6] += p[0]; acc[7] += p[1];
        }
    }
    float d = dinv[node];
    u32 w0 = 0, w1 = 0;
    w0 = __builtin_amdgcn_cvt_pk_fp8_f32(acc[0] * d, acc[1] * d, w0, false);
    w0 = __builtin_amdgcn_cvt_pk_fp8_f32(acc[2] * d, acc[3] * d, w0, true);
    w1 = __builtin_amdgcn_cvt_pk_fp8_f32(acc[4] * d, acc[5] * d, w1, false);
    w1 = __builtin_amdgcn_cvt_pk_fp8_f32(acc[6] * d, acc[7] * d, w1, true);
    uint2 o; o.x = w0; o.y = w1;
    *(uint2*)(outp + (size_t)node * 256 + off) = o;
}

// agg32: F=32 fp8 in, f32 sigmoid out. 8 lanes/node (4 features each).
__global__ __launch_bounds__(256) void agg32_sig(const u8* __restrict__ zq,
                                                 float* __restrict__ out,
                                                 const int* __restrict__ row_ptr,
                                                 const int* __restrict__ csr_src,
                                                 const float* __restrict__ dinv,
                                                 const float* __restrict__ b3,
                                                 int nnodes) {
    int tid = threadIdx.x;
    int grp = tid >> 3, l8 = tid & 7;
    int node = blockIdx.x * 32 + grp;
    if (node >= nnodes) return;
    int off = l8 * 4;
    const u8* bp = zq + off;
    float a0, a1, a2, a3;
    {
        u32 q = *(const u32*)(zq + (size_t)node * 32 + off);
        f32x2 p;
        p = __builtin_amdgcn_cvt_pk_f32_fp8(q, false); a0 = p[0]; a1 = p[1];
        p = __builtin_amdgcn_cvt_pk_f32_fp8(q, true);  a2 = p[0]; a3 = p[1];
    }
    int e = row_ptr[node], e1 = row_ptr[node + 1];
    for (; e < e1; e += 8) {
        int sx[8];
        #pragma unroll
        for (int q = 0; q < 8; ++q) {
            int ee = e + q;
            int vsrc = csr_src[ee < e1 ? ee : e];
            sx[q] = (ee < e1) ? vsrc : nnodes;
        }
        u32 vv[8];
        #pragma unroll
        for (int q = 0; q < 8; ++q) vv[q] = *(const u32*)(bp + (size_t)sx[q] * 32);
        #pragma unroll
        for (int q = 0; q < 8; ++q) {
            f32x2 p;
            p = __builtin_amdgcn_cvt_pk_f32_fp8(vv[q], false); a0 += p[0]; a1 += p[1];
            p = __builtin_amdgcn_cvt_pk_f32_fp8(vv[q], true);  a2 += p[0]; a3 += p[1];
        }
    }
    float d = dinv[node];
    int fb = l8 * 4;
    float4 o;
    o.x = 1.f / (1.f + expf(-(a0 * d + b3[fb + 0])));
    o.y = 1.f / (1.f + expf(-(a1 * d + b3[fb + 1])));
    o.z = 1.f / (1.f + expf(-(a2 * d + b3[fb + 2])));
    o.w = 1.f / (1.f + expf(-(a3 * d + b3[fb + 3])));
    *(float4*)(out + (size_t)node * 32 + fb) = o;
}

// ---------------- launch ----------------

extern "C" void kernel_launch(void* const* d_in, const int* in_sizes, int n_in,
                              void* d_out, int out_size, void* d_ws, size_t ws_size,
                              hipStream_t stream) {
    const float* x  = (const float*)d_in[0];
    const int*   ei = (const int*)d_in[1];
    const float* W1 = (const float*)d_in[2];
    const float* b1 = (const float*)d_in[3];
    const float* g1 = (const float*)d_in[4];
    const float* be1 = (const float*)d_in[5];
    const float* m1 = (const float*)d_in[6];
    const float* v1 = (const float*)d_in[7];
    const float* W2 = (const float*)d_in[8];
    const float* b2 = (const float*)d_in[9];
    const float* g2 = (const float*)d_in[10];
    const float* be2 = (const float*)d_in[11];
    const float* m2 = (const float*)d_in[12];
    const float* v2 = (const float*)d_in[13];
    const float* W3 = (const float*)d_in[14];
    const float* b3 = (const float*)d_in[15];
    float* out = (float*)d_out;

    const int N = in_sizes[0] / 128;   // 100000
    const int E = in_sizes[1] / 2;     // 1600000

    const int NB = (N + 511) >> 9;
    const int NBLK = (E + 2047) / 2048;
    const int PREPB = (128 * 256 + 256 * 256 + 256 * 32 + 512 + 255) / 256;

    char* w = (char*)d_ws;
    auto alloc = [&](size_t bytes) -> void* {
        void* p = (void*)w;
        w += (bytes + 255) & ~(size_t)255;
        return p;
    };
    int* row_ptr   = (int*)alloc((size_t)(N + 1) * 4);
    float* dinv    = (float*)alloc((size_t)N * 4);
    u32* cnt_pb    = (u32*)alloc((size_t)NB * NBLK * 4);
    u32* bases_pb  = (u32*)alloc((size_t)NB * NBLK * 4);
    u32* bkt_tot   = (u32*)alloc((size_t)NB * 4);
    u32* bkt_edges = (u32*)alloc((size_t)E * 4);
    float* s1 = (float*)alloc(256 * 4);
    float* t1 = (float*)alloc(256 * 4);
    float* s2 = (float*)alloc(256 * 4);
    float* t2 = (float*)alloc(256 * 4);
    u16* Wt1 = (u16*)alloc((size_t)128 * 256 * 2);
    u16* Wt2 = (u16*)alloc((size_t)256 * 256 * 2);
    u16* Wt3 = (u16*)alloc((size_t)256 * 32 * 2);
    int* csr_src = (int*)alloc((size_t)E * 4);
    u8*  xq   = (u8*)alloc((size_t)(N + 1) * 128);  // +pad row; reused as z3
    u8*  xa   = (u8*)alloc((size_t)N * 128);
    u8*  h1q  = (u8*)alloc((size_t)(N + 1) * 256);  // +pad row
    u8*  h1a  = (u8*)alloc((size_t)N * 256);
    u8*  h2q  = (u8*)alloc((size_t)(N + 1) * 256);  // +pad row (unused, safe)
    u8*  z3 = xq;                                   // (N+1)*32 fp8 fits

    int nT = (N + 63) / 64;
    int gagg = (N + 7) / 8;

    // CSR build (+prep overlapped): 4 kernels
    k_hist<<<NBLK + PREPB, 256, 0, stream>>>(ei, cnt_pb, E, NB, NBLK,
        W1, Wt1, W2, Wt2, W3, Wt3,
        b1, g1, be1, m1, v1, s1, t1, b2, g2, be2, m2, v2, s2, t2);
    k_scanb<<<NB, 1024, 0, stream>>>(cnt_pb, bases_pb, bkt_tot, NBLK);
    k_scatter2<<<NBLK, 256, 0, stream>>>(ei, bases_pb, bkt_tot, bkt_edges, E, NB, NBLK);
    k_bucket<<<NB, 512, 0, stream>>>(bkt_edges, bkt_tot, row_ptr, dinv, csr_src,
                                     x, xq, N, NB, E);

    // Layer 1
    agg_x<<<gagg, 256, 0, stream>>>(xq, xa, row_ptr, csr_src, dinv, N);
    g_mfma_lds<128, 64, 3, true, 2><<<dim3(128, 4), 256, 0, stream>>>(
        (const void*)xa, Wt1, (void*)h1q, N, 256, s1, t1, dinv, nT);

    // Layer 2
    agg_h<<<gagg, 256, 0, stream>>>(h1q, h1a, row_ptr, csr_src, dinv, N);
    g_mfma_lds<256, 64, 3, true, 2><<<dim3(128, 4), 256, 0, stream>>>(
        (const void*)h1a, Wt2, (void*)h2q, N, 256, s2, t2, dinv, nT);

    // Layer 3
    g_mfma_lds<256, 32, 4, true, 2><<<dim3(512, 1), 256, 0, stream>>>(
        (const void*)h2q, Wt3, (void*)z3, N, 32, (const float*)nullptr,
        (const float*)nullptr, (const float*)nullptr, nT);
    agg32_sig<<<(N + 31) / 32, 256, 0, stream>>>(z3, out, row_ptr, csr_src, dinv, b3, N);
}

// Round 16
// 229.232 us; speedup vs baseline: 1.9051x; 1.0090x over previous
//
#include <hip/hip_runtime.h>
#include <math.h>

typedef unsigned short u16;
typedef unsigned char u8;
typedef unsigned int u32;
typedef __attribute__((ext_vector_type(8))) __bf16 bfx8;
typedef __attribute__((ext_vector_type(4))) float f32x4;
typedef __attribute__((ext_vector_type(2))) float f32x2;
typedef __attribute__((ext_vector_type(8))) unsigned short us8;

__device__ inline u16 f2bf(float f) {
    union { float f; unsigned int i; } v;
    v.f = f;
    unsigned int b = v.i;
    return (u16)((b + 0x7FFFu + ((b >> 16) & 1u)) >> 16);
}
__device__ inline u32 bits_of(float f) {
    union { float f; u32 i; } v; v.f = f; return v.i;
}
__device__ inline u32 pkbf(float a, float b) {
    return (bits_of(a) >> 16) | (bits_of(b) & 0xffff0000u);
}
// decode 4 fp8 (one dword) -> 2 u32 of packed bf16 (exact)
__device__ inline void dec4(u32 d, u32& lo, u32& hi) {
    f32x2 a = __builtin_amdgcn_cvt_pk_f32_fp8(d, false);
    f32x2 b = __builtin_amdgcn_cvt_pk_f32_fp8(d, true);
    lo = pkbf(a[0], a[1]);
    hi = pkbf(b[0], b[1]);
}

// ---------------- CSR build: bucket sort, LDS atomics only ----------------
// k_hist also runs the parameter prep in extra blocks (blk >= NBLK).

__global__ __launch_bounds__(256) void k_hist(
    const int* __restrict__ ei, u32* __restrict__ cnt_pb, int E, int NB, int NBLK,
    const float* __restrict__ W1, u16* __restrict__ Wt1,
    const float* __restrict__ W2, u16* __restrict__ Wt2,
    const float* __restrict__ W3, u16* __restrict__ Wt3,
    const float* __restrict__ b1, const float* __restrict__ g1, const float* __restrict__ be1,
    const float* __restrict__ m1, const float* __restrict__ v1,
    float* __restrict__ s1, float* __restrict__ t1,
    const float* __restrict__ b2, const float* __restrict__ g2, const float* __restrict__ be2,
    const float* __restrict__ m2, const float* __restrict__ v2,
    float* __restrict__ s2, float* __restrict__ t2)
{
    int blk = blockIdx.x, tid = threadIdx.x;
    if (blk >= NBLK) {
        int j = (blk - NBLK) * 256 + tid;
        if (j < 128 * 256) {
            int k = j / 256, f = j % 256;
            Wt1[(size_t)f * 128 + k] = f2bf(W1[j]);
        } else if (j < 128 * 256 + 256 * 256) {
            int j2 = j - 128 * 256;
            int k = j2 / 256, f = j2 % 256;
            Wt2[(size_t)f * 256 + k] = f2bf(W2[j2]);
        } else if (j < 128 * 256 + 256 * 256 + 256 * 32) {
            int j3 = j - (128 * 256 + 256 * 256);
            int k = j3 / 32, f = j3 % 32;
            Wt3[(size_t)f * 256 + k] = f2bf(W3[j3]);
        } else {
            int k = j - (128 * 256 + 256 * 256 + 256 * 32);
            if (k < 256) {
                float sc = g1[k] * rsqrtf(v1[k] + 1e-5f);
                s1[k] = sc;
                t1[k] = (b1[k] - m1[k]) * sc + be1[k];
            } else if (k < 512) {
                int kk = k - 256;
                float sc = g2[kk] * rsqrtf(v2[kk] + 1e-5f);
                s2[kk] = sc;
                t2[kk] = (b2[kk] - m2[kk]) * sc + be2[kk];
            }
        }
        return;
    }
    __shared__ u32 h[256];
    h[tid] = 0;
    __syncthreads();
    int eend = min(E, (blk + 1) * 2048);
    for (int e = blk * 2048 + tid; e < eend; e += 256) {
        int d = ei[E + e];
        atomicAdd(&h[d >> 9], 1u);
    }
    __syncthreads();
    if (tid < NB) cnt_pb[(size_t)tid * NBLK + blk] = h[tid];
}

__global__ __launch_bounds__(1024) void k_scanb(const u32* __restrict__ cnt_pb,
                                                u32* __restrict__ bases_pb,
                                                u32* __restrict__ bkt_tot,
                                                int NBLK) {
    __shared__ u32 lds[1024];
    int b = blockIdx.x, t = threadIdx.x;
    u32 v = (t < NBLK) ? cnt_pb[(size_t)b * NBLK + t] : 0u;
    lds[t] = v;
    __syncthreads();
    for (int off = 1; off < 1024; off <<= 1) {
        u32 x = lds[t];
        u32 y = (t >= off) ? lds[t - off] : 0u;
        __syncthreads();
        lds[t] = x + y;
        __syncthreads();
    }
    if (t < NBLK) bases_pb[(size_t)b * NBLK + t] = lds[t] - v;
    if (t == NBLK - 1) bkt_tot[b] = lds[t];
}

__global__ __launch_bounds__(256) void k_scatter2(const int* __restrict__ ei,
                                                  const u32* __restrict__ bases_pb,
                                                  const u32* __restrict__ bkt_tot,
                                                  u32* __restrict__ bkt_edges,
                                                  int E, int NB, int NBLK) {
    __shared__ u32 cur[256];
    __shared__ u32 bb[256];
    int blk = blockIdx.x, tid = threadIdx.x;
    u32 v = (tid < NB) ? bkt_tot[tid] : 0u;
    bb[tid] = v;
    __syncthreads();
    for (int off = 1; off < 256; off <<= 1) {
        u32 x = bb[tid];
        u32 y = (tid >= off) ? bb[tid - off] : 0u;
        __syncthreads();
        bb[tid] = x + y;
        __syncthreads();
    }
    u32 excl = bb[tid] - v;
    __syncthreads();
    bb[tid] = excl;
    if (tid < NB) cur[tid] = bases_pb[(size_t)tid * NBLK + blk];
    __syncthreads();
    int eend = min(E, (blk + 1) * 2048);
    for (int e = blk * 2048 + tid; e < eend; e += 256) {
        int s = ei[e];
        int d = ei[E + e];
        int b = d >> 9;
        int dl = d & 511;
        u32 off = atomicAdd(&cur[b], 1u);
        bkt_edges[bb[b] + off] = (u32)s | ((u32)dl << 17);
    }
}

// per-bucket CSR build + x->fp8 conversion for this bucket's nodes
__global__ __launch_bounds__(512) void k_bucket(const u32* __restrict__ bkt_edges,
                                                const u32* __restrict__ bkt_tot,
                                                int* __restrict__ row_ptr,
                                                float* __restrict__ dinv,
                                                int* __restrict__ csr_src,
                                                const float* __restrict__ x,
                                                u8* __restrict__ xq,
                                                int N, int NB, int E) {
    __shared__ u32 sb[256];
    __shared__ u32 lcnt[512];
    __shared__ u32 lscan[512];
    int b = blockIdx.x, t = threadIdx.x;
    if (t < 256) sb[t] = (t < NB) ? bkt_tot[t] : 0u;
    __syncthreads();
    for (int off = 1; off < 256; off <<= 1) {
        u32 x0 = 0, y0 = 0;
        if (t < 256) { x0 = sb[t]; y0 = (t >= off) ? sb[t - off] : 0u; }
        __syncthreads();
        if (t < 256) sb[t] = x0 + y0;
        __syncthreads();
    }
    int ce = (int)bkt_tot[b];
    int es = (int)sb[b] - ce;
    int node0 = b << 9;
    lcnt[t] = 0;
    __syncthreads();
    for (int i = t; i < ce; i += 512) {
        u32 p = bkt_edges[es + i];
        atomicAdd(&lcnt[p >> 17], 1u);
    }
    __syncthreads();
    lscan[t] = lcnt[t];
    __syncthreads();
    for (int off = 1; off < 512; off <<= 1) {
        u32 x0 = lscan[t];
        u32 y0 = (t >= off) ? lscan[t - off] : 0u;
        __syncthreads();
        lscan[t] = x0 + y0;
        __syncthreads();
    }
    u32 excl = lscan[t] - lcnt[t];
    int node = node0 + t;
    float my_d = rsqrtf((float)lcnt[t] + 1.0f);
    if (node < N) {
        row_ptr[node] = es + (int)excl;
        dinv[node] = my_d;
    }
    if (b == 0 && t == 0) row_ptr[N] = E;
    __syncthreads();
    lscan[t] = excl;
    __syncthreads();
    for (int i = t; i < ce; i += 512) {
        u32 p = bkt_edges[es + i];
        int dl = (int)(p >> 17);
        int src = (int)(p & 0x1FFFFu);
        u32 pos = atomicAdd(&lscan[dl], 1u);
        csr_src[es + pos] = src;
    }
    // x -> fp8*dinv for this bucket's nodes
    __syncthreads();
    ((float*)lcnt)[t] = my_d;
    __syncthreads();
    const float* df = (const float*)lcnt;
    for (int i = t; i < 512 * 32; i += 512) {
        int r = i >> 5;
        int row = node0 + r;
        if (row < N) {
            float d = df[r];
            float4 v = *(const float4*)(x + (size_t)row * 128 + (i & 31) * 4);
            u32 pk = 0;
            pk = __builtin_amdgcn_cvt_pk_fp8_f32(v.x * d, v.y * d, pk, false);
            pk = __builtin_amdgcn_cvt_pk_fp8_f32(v.z * d, v.w * d, pk, true);
            *(u32*)(xq + (size_t)row * 128 + (i & 31) * 4) = pk;
        }
    }
    if (b == 0 && t < 32) *(u32*)(xq + (size_t)N * 128 + t * 4) = 0;  // zero pad row
}

// ---------------- MFMA GEMM: persistent blocks, B in regs, A via LDS -------
// AFP8: A stored fp8, decoded exactly to bf16 at LDS staging.
// MODE 1: BN+ReLU*dinv bf16. MODE 2: plain bf16.
// MODE 3: BN+ReLU*dinv fp8. MODE 4: plain fp8.
// fp8 C modes also zero pad-row M (for downstream gather padding).
template<int K, int FT, int MODE, bool AFP8, int MINW>
__global__ __launch_bounds__(256, MINW) void g_mfma_lds(
    const void* __restrict__ Av, const u16* __restrict__ Wt,
    void* __restrict__ Cv, int M, int Ftot,
    const float* __restrict__ s, const float* __restrict__ t,
    const float* __restrict__ dinv, int nTiles)
{
    constexpr bool DOBN = (MODE == 1) || (MODE == 3);
    constexpr bool CF8  = (MODE >= 3);
    constexpr int BK  = 128;
    constexpr int SA  = BK + 8;
    constexpr int NH  = K / BK;
    constexpr int NKH = BK / 32;
    constexpr int NF  = FT / 16;
    constexpr int EB  = CF8 ? 1 : 2;
    constexpr int SCB = FT * EB + 16;
    constexpr int EBa = AFP8 ? 1 : 2;
    constexpr int CR  = (BK * EBa) / 16;
    constexpr int LIT = (64 * CR) / 256;

    __shared__ u16 Asmem[2][64 * SA];
    __shared__ u8  Cs8[64 * SCB];

    const u8* Ab = (const u8*)Av;
    int tid = threadIdx.x;
    int w = tid >> 6, l = tid & 63;
    int lr = l & 15, koff8 = (l >> 4) * 8;
    int col0 = blockIdx.y * FT;

    if (CF8 && blockIdx.x == 0 && blockIdx.y == 0) {
        if (tid * 4 < Ftot) *(u32*)((u8*)Cv + (size_t)M * Ftot + tid * 4) = 0;
    }

    bfx8 bfr[NH][NKH][NF];
    {
        const u16* wp = Wt + (size_t)(col0 + lr) * K + koff8;
        #pragma unroll
        for (int h = 0; h < NH; ++h)
            #pragma unroll
            for (int kk = 0; kk < NKH; ++kk)
                #pragma unroll
                for (int c = 0; c < NF; ++c)
                    bfr[h][kk][c] = *(const bfx8*)(wp + (size_t)c * 16 * K + h * BK + kk * 32);
    }

    int myT = (blockIdx.x < nTiles) ? ((nTiles - 1 - (int)blockIdx.x) / (int)gridDim.x + 1) : 0;
    int NM = myT * NH;
    if (NM == 0) return;

    f32x4 acc[NF];
    #pragma unroll
    for (int c = 0; c < NF; ++c) acc[c] = (f32x4){0.f, 0.f, 0.f, 0.f};

    uint4 rga[LIT];

    auto loadA = [&](int r0, int hh) {
        #pragma unroll
        for (int j = 0; j < LIT; ++j) {
            int cid = j * 256 + tid;
            int row = cid / CR, ch = cid % CR;
            int gr = r0 + row; if (gr > M - 1) gr = M - 1;
            rga[j] = *(const uint4*)(Ab + (size_t)gr * K * EBa + (size_t)hh * BK * EBa + ch * 16);
        }
    };
    auto writeA = [&](int buf) {
        #pragma unroll
        for (int j = 0; j < LIT; ++j) {
            int cid = j * 256 + tid;
            int row = cid / CR, ch = cid % CR;
            if (!AFP8) {
                *(uint4*)&Asmem[buf][row * SA + ch * 8] = rga[j];
            } else {
                u32 w0, w1, w2, w3, w4, w5, w6, w7;
                dec4(rga[j].x, w0, w1);
                dec4(rga[j].y, w2, w3);
                dec4(rga[j].z, w4, w5);
                dec4(rga[j].w, w6, w7);
                uint4 lo4; lo4.x = w0; lo4.y = w1; lo4.z = w2; lo4.w = w3;
                uint4 hi4; hi4.x = w4; hi4.y = w5; hi4.z = w6; hi4.w = w7;
                *(uint4*)&Asmem[buf][row * SA + ch * 16] = lo4;
                *(uint4*)&Asmem[buf][row * SA + ch * 16 + 8] = hi4;
            }
        }
    };

    loadA(blockIdx.x * 64, 0);
    writeA(0);
    if (NM > 1) {
        constexpr int gt1 = 1 / NH, h1 = 1 % NH;
        loadA((blockIdx.x + gt1 * gridDim.x) * 64, h1);
    }
    __syncthreads();

    int cur = 0, gm = 0;
    for (int ti = 0; ti < myT; ++ti) {
        int row0g = (blockIdx.x + ti * gridDim.x) * 64;
        #pragma unroll
        for (int h = 0; h < NH; ++h) {
            const u16* ab = &Asmem[cur][0];
            #pragma unroll
            for (int kk = 0; kk < NKH; ++kk) {
                bfx8 af = *(const bfx8*)(ab + (w * 16 + lr) * SA + koff8 + kk * 32);
                #pragma unroll
                for (int c = 0; c < NF; ++c)
                    acc[c] = __builtin_amdgcn_mfma_f32_16x16x32_bf16(af, bfr[h][kk][c], acc[c], 0, 0, 0);
            }
            if (h == NH - 1) {
                int orow = w * 16 + (l >> 4) * 4;
                float dr[4];
                #pragma unroll
                for (int r = 0; r < 4; ++r) {
                    int grow = row0g + orow + r;
                    dr[r] = DOBN ? ((grow < M) ? dinv[grow] : 0.f) : 1.f;
                }
                #pragma unroll
                for (int c = 0; c < NF; ++c) {
                    int gc = col0 + c * 16 + lr;
                    float sc = DOBN ? s[gc] : 0.f;
                    float tc = DOBN ? t[gc] : 0.f;
                    #pragma unroll
                    for (int r = 0; r < 4; ++r) {
                        float v = acc[c][r];
                        if (DOBN) v = fmaxf(v * sc + tc, 0.f) * dr[r];
                        if (CF8) {
                            int enc = __builtin_amdgcn_cvt_pk_fp8_f32(v, v, 0, false);
                            Cs8[(orow + r) * SCB + (c * 16 + lr)] = (u8)(enc & 0xff);
                        } else {
                            *(u16*)&Cs8[(orow + r) * SCB + (c * 16 + lr) * 2] = f2bf(v);
                        }
                    }
                    acc[c] = (f32x4){0.f, 0.f, 0.f, 0.f};
                }
            }
            __syncthreads();
            if (gm + 1 < NM) writeA(cur ^ 1);
            if (h == NH - 1) {
                constexpr int CPR = (FT * EB) / 16;
                constexpr int TOT = 64 * CPR;
                constexpr int CPT = (TOT + 255) / 256;
                u8* C8 = (u8*)Cv;
                #pragma unroll
                for (int j = 0; j < CPT; ++j) {
                    int cid = j * 256 + tid;
                    if (cid < TOT) {
                        int crow = cid / CPR;
                        int cb = (cid % CPR) * 16;
                        int grow = row0g + crow;
                        if (grow < M) {
                            us8 vv = *(const us8*)&Cs8[crow * SCB + cb];
                            *(us8*)(C8 + (size_t)grow * Ftot * EB + (size_t)col0 * EB + cb) = vv;
                        }
                    }
                }
            }
            if (gm + 2 < NM) {
                int g2 = gm + 2;
                int gt2 = g2 / NH, h2 = g2 % NH;
                loadA((blockIdx.x + gt2 * gridDim.x) * 64, h2);
            }
            __syncthreads();
            cur ^= 1; ++gm;
        }
    }
}

// ---------------- Aggregation (16 lanes/node, wide loads, zero-row pad) ----
// agg_x: F=128 fp8 in/out. 16 lanes/node (8B uint2), 4 nodes/wave.
__global__ __launch_bounds__(256) void agg_x(const u8* __restrict__ in,
                                             u8* __restrict__ outp,
                                             const int* __restrict__ row_ptr,
                                             const int* __restrict__ csr_src,
                                             const float* __restrict__ dinv,
                                             int nnodes) {
    int tid = threadIdx.x;
    int wv = tid >> 6, lane = tid & 63;
    int quarter = lane >> 4, l16 = lane & 15;
    int node = (blockIdx.x * 4 + wv) * 4 + quarter;
    if (node >= nnodes) return;
    int off = l16 * 8;   // byte offset
    const u8* bp = in + off;
    float a0, a1, a2, a3, a4, a5, a6, a7;
    {
        uint2 q = *(const uint2*)(in + (size_t)node * 128 + off);
        f32x2 p;
        p = __builtin_amdgcn_cvt_pk_f32_fp8(q.x, false); a0 = p[0]; a1 = p[1];
        p = __builtin_amdgcn_cvt_pk_f32_fp8(q.x, true);  a2 = p[0]; a3 = p[1];
        p = __builtin_amdgcn_cvt_pk_f32_fp8(q.y, false); a4 = p[0]; a5 = p[1];
        p = __builtin_amdgcn_cvt_pk_f32_fp8(q.y, true);  a6 = p[0]; a7 = p[1];
    }
    int e = row_ptr[node], e1 = row_ptr[node + 1];
    for (; e < e1; e += 8) {
        int sx[8];
        #pragma unroll
        for (int q = 0; q < 8; ++q) {
            int ee = e + q;
            int vsrc = csr_src[ee < e1 ? ee : e];
            sx[q] = (ee < e1) ? vsrc : nnodes;
        }
        uint2 vv[8];
        #pragma unroll
        for (int q = 0; q < 8; ++q) vv[q] = *(const uint2*)(bp + (size_t)sx[q] * 128);
        #pragma unroll
        for (int q = 0; q < 8; ++q) {
            f32x2 p;
            p = __builtin_amdgcn_cvt_pk_f32_fp8(vv[q].x, false); a0 += p[0]; a1 += p[1];
            p = __builtin_amdgcn_cvt_pk_f32_fp8(vv[q].x, true);  a2 += p[0]; a3 += p[1];
            p = __builtin_amdgcn_cvt_pk_f32_fp8(vv[q].y, false); a4 += p[0]; a5 += p[1];
            p = __builtin_amdgcn_cvt_pk_f32_fp8(vv[q].y, true);  a6 += p[0]; a7 += p[1];
        }
    }
    float d = dinv[node];
    u32 w0 = 0, w1 = 0;
    w0 = __builtin_amdgcn_cvt_pk_fp8_f32(a0 * d, a1 * d, w0, false);
    w0 = __builtin_amdgcn_cvt_pk_fp8_f32(a2 * d, a3 * d, w0, true);
    w1 = __builtin_amdgcn_cvt_pk_fp8_f32(a4 * d, a5 * d, w1, false);
    w1 = __builtin_amdgcn_cvt_pk_fp8_f32(a6 * d, a7 * d, w1, true);
    uint2 o; o.x = w0; o.y = w1;
    *(uint2*)(outp + (size_t)node * 128 + off) = o;
}

// agg_h: F=256 fp8 in/out. 16 lanes/node (16B uint4), 4 nodes/wave.
__global__ __launch_bounds__(256) void agg_h(const u8* __restrict__ in,
                                             u8* __restrict__ outp,
                                             const int* __restrict__ row_ptr,
                                             const int* __restrict__ csr_src,
                                             const float* __restrict__ dinv,
                                             int nnodes) {
    int tid = threadIdx.x;
    int wv = tid >> 6, lane = tid & 63;
    int quarter = lane >> 4, l16 = lane & 15;
    int node = (blockIdx.x * 4 + wv) * 4 + quarter;
    if (node >= nnodes) return;
    int off = l16 * 16;   // byte offset, 16 fp8 per lane
    const u8* bp = in + off;
    float acc[16];
    {
        uint4 q = *(const uint4*)(in + (size_t)node * 256 + off);
        f32x2 p;
        p = __builtin_amdgcn_cvt_pk_f32_fp8(q.x, false); acc[0] = p[0]; acc[1] = p[1];
        p = __builtin_amdgcn_cvt_pk_f32_fp8(q.x, true);  acc[2] = p[0]; acc[3] = p[1];
        p = __builtin_amdgcn_cvt_pk_f32_fp8(q.y, false); acc[4] = p[0]; acc[5] = p[1];
        p = __builtin_amdgcn_cvt_pk_f32_fp8(q.y, true);  acc[6] = p[0]; acc[7] = p[1];
        p = __builtin_amdgcn_cvt_pk_f32_fp8(q.z, false); acc[8] = p[0]; acc[9] = p[1];
        p = __builtin_amdgcn_cvt_pk_f32_fp8(q.z, true);  acc[10] = p[0]; acc[11] = p[1];
        p = __builtin_amdgcn_cvt_pk_f32_fp8(q.w, false); acc[12] = p[0]; acc[13] = p[1];
        p = __builtin_amdgcn_cvt_pk_f32_fp8(q.w, true);  acc[14] = p[0]; acc[15] = p[1];
    }
    int e = row_ptr[node], e1 = row_ptr[node + 1];
    for (; e < e1; e += 8) {
        int sx[8];
        #pragma unroll
        for (int q = 0; q < 8; ++q) {
            int ee = e + q;
            int vsrc = csr_src[ee < e1 ? ee : e];
            sx[q] = (ee < e1) ? vsrc : nnodes;
        }
        uint4 vv[8];
        #pragma unroll
        for (int q = 0; q < 8; ++q) vv[q] = *(const uint4*)(bp + (size_t)sx[q] * 256);
        #pragma unroll
        for (int q = 0; q < 8; ++q) {
            f32x2 p;
            p = __builtin_amdgcn_cvt_pk_f32_fp8(vv[q].x, false); acc[0] += p[0]; acc[1] += p[1];
            p = __builtin_amdgcn_cvt_pk_f32_fp8(vv[q].x, true);  acc[2] += p[0]; acc[3] += p[1];
            p = __builtin_amdgcn_cvt_pk_f32_fp8(vv[q].y, false); acc[4] += p[0]; acc[5] += p[1];
            p = __builtin_amdgcn_cvt_pk_f32_fp8(vv[q].y, true);  acc[6] += p[0]; acc[7] += p[1];
            p = __builtin_amdgcn_cvt_pk_f32_fp8(vv[q].z, false); acc[8] += p[0]; acc[9] += p[1];
            p = __builtin_amdgcn_cvt_pk_f32_fp8(vv[q].z, true);  acc[10] += p[0]; acc[11] += p[1];
            p = __builtin_amdgcn_cvt_pk_f32_fp8(vv[q].w, false); acc[12] += p[0]; acc[13] += p[1];
            p = __builtin_amdgcn_cvt_pk_f32_fp8(vv[q].w, true);  acc[14] += p[0]; acc[15] += p[1];
        }
    }
    float d = dinv[node];
    u32 w0 = 0, w1 = 0, w2 = 0, w3 = 0;
    w0 = __builtin_amdgcn_cvt_pk_fp8_f32(acc[0] * d, acc[1] * d, w0, false);
    w0 = __builtin_amdgcn_cvt_pk_fp8_f32(acc[2] * d, acc[3] * d, w0, true);
    w1 = __builtin_amdgcn_cvt_pk_fp8_f32(acc[4] * d, acc[5] * d, w1, false);
    w1 = __builtin_amdgcn_cvt_pk_fp8_f32(acc[6] * d, acc[7] * d, w1, true);
    w2 = __builtin_amdgcn_cvt_pk_fp8_f32(acc[8] * d, acc[9] * d, w2, false);
    w2 = __builtin_amdgcn_cvt_pk_fp8_f32(acc[10] * d, acc[11] * d, w2, true);
    w3 = __builtin_amdgcn_cvt_pk_fp8_f32(acc[12] * d, acc[13] * d, w3, false);
    w3 = __builtin_amdgcn_cvt_pk_fp8_f32(acc[14] * d, acc[15] * d, w3, true);
    uint4 o; o.x = w0; o.y = w1; o.z = w2; o.w = w3;
    *(uint4*)(outp + (size_t)node * 256 + off) = o;
}

// agg32: F=32 fp8 in, f32 sigmoid out. 8 lanes/node (4 features each).
__global__ __launch_bounds__(256) void agg32_sig(const u8* __restrict__ zq,
                                                 float* __restrict__ out,
                                                 const int* __restrict__ row_ptr,
                                                 const int* __restrict__ csr_src,
                                                 const float* __restrict__ dinv,
                                                 const float* __restrict__ b3,
                                                 int nnodes) {
    int tid = threadIdx.x;
    int grp = tid >> 3, l8 = tid & 7;
    int node = blockIdx.x * 32 + grp;
    if (node >= nnodes) return;
    int off = l8 * 4;
    const u8* bp = zq + off;
    float a0, a1, a2, a3;
    {
        u32 q = *(const u32*)(zq + (size_t)node * 32 + off);
        f32x2 p;
        p = __builtin_amdgcn_cvt_pk_f32_fp8(q, false); a0 = p[0]; a1 = p[1];
        p = __builtin_amdgcn_cvt_pk_f32_fp8(q, true);  a2 = p[0]; a3 = p[1];
    }
    int e = row_ptr[node], e1 = row_ptr[node + 1];
    for (; e < e1; e += 8) {
        int sx[8];
        #pragma unroll
        for (int q = 0; q < 8; ++q) {
            int ee = e + q;
            int vsrc = csr_src[ee < e1 ? ee : e];
            sx[q] = (ee < e1) ? vsrc : nnodes;
        }
        u32 vv[8];
        #pragma unroll
        for (int q = 0; q < 8; ++q) vv[q] = *(const u32*)(bp + (size_t)sx[q] * 32);
        #pragma unroll
        for (int q = 0; q < 8; ++q) {
            f32x2 p;
            p = __builtin_amdgcn_cvt_pk_f32_fp8(vv[q], false); a0 += p[0]; a1 += p[1];
            p = __builtin_amdgcn_cvt_pk_f32_fp8(vv[q], true);  a2 += p[0]; a3 += p[1];
        }
    }
    float d = dinv[node];
    int fb = l8 * 4;
    float4 o;
    o.x = 1.f / (1.f + expf(-(a0 * d + b3[fb + 0])));
    o.y = 1.f / (1.f + expf(-(a1 * d + b3[fb + 1])));
    o.z = 1.f / (1.f + expf(-(a2 * d + b3[fb + 2])));
    o.w = 1.f / (1.f + expf(-(a3 * d + b3[fb + 3])));
    *(float4*)(out + (size_t)node * 32 + fb) = o;
}

// ---------------- launch ----------------

extern "C" void kernel_launch(void* const* d_in, const int* in_sizes, int n_in,
                              void* d_out, int out_size, void* d_ws, size_t ws_size,
                              hipStream_t stream) {
    const float* x  = (const float*)d_in[0];
    const int*   ei = (const int*)d_in[1];
    const float* W1 = (const float*)d_in[2];
    const float* b1 = (const float*)d_in[3];
    const float* g1 = (const float*)d_in[4];
    const float* be1 = (const float*)d_in[5];
    const float* m1 = (const float*)d_in[6];
    const float* v1 = (const float*)d_in[7];
    const float* W2 = (const float*)d_in[8];
    const float* b2 = (const float*)d_in[9];
    const float* g2 = (const float*)d_in[10];
    const float* be2 = (const float*)d_in[11];
    const float* m2 = (const float*)d_in[12];
    const float* v2 = (const float*)d_in[13];
    const float* W3 = (const float*)d_in[14];
    const float* b3 = (const float*)d_in[15];
    float* out = (float*)d_out;

    const int N = in_sizes[0] / 128;   // 100000
    const int E = in_sizes[1] / 2;     // 1600000

    const int NB = (N + 511) >> 9;
    const int NBLK = (E + 2047) / 2048;
    const int PREPB = (128 * 256 + 256 * 256 + 256 * 32 + 512 + 255) / 256;

    char* w = (char*)d_ws;
    auto alloc = [&](size_t bytes) -> void* {
        void* p = (void*)w;
        w += (bytes + 255) & ~(size_t)255;
        return p;
    };
    int* row_ptr   = (int*)alloc((size_t)(N + 1) * 4);
    float* dinv    = (float*)alloc((size_t)N * 4);
    u32* cnt_pb    = (u32*)alloc((size_t)NB * NBLK * 4);
    u32* bases_pb  = (u32*)alloc((size_t)NB * NBLK * 4);
    u32* bkt_tot   = (u32*)alloc((size_t)NB * 4);
    u32* bkt_edges = (u32*)alloc((size_t)E * 4);
    float* s1 = (float*)alloc(256 * 4);
    float* t1 = (float*)alloc(256 * 4);
    float* s2 = (float*)alloc(256 * 4);
    float* t2 = (float*)alloc(256 * 4);
    u16* Wt1 = (u16*)alloc((size_t)128 * 256 * 2);
    u16* Wt2 = (u16*)alloc((size_t)256 * 256 * 2);
    u16* Wt3 = (u16*)alloc((size_t)256 * 32 * 2);
    int* csr_src = (int*)alloc((size_t)E * 4);
    u8*  xq   = (u8*)alloc((size_t)(N + 1) * 128);
    u8*  xa   = (u8*)alloc((size_t)N * 128);
    u8*  h1q  = (u8*)alloc((size_t)(N + 1) * 256);
    u8*  h1a  = (u8*)alloc((size_t)N * 256);
    u8*  h2q  = (u8*)alloc((size_t)(N + 1) * 256);
    u8*  z3 = xq;

    int nT = (N + 63) / 64;
    int gagg16 = (N + 15) / 16;   // 16 nodes/block (4 waves x 4)

    // CSR build (+prep overlapped): 4 kernels
    k_hist<<<NBLK + PREPB, 256, 0, stream>>>(ei, cnt_pb, E, NB, NBLK,
        W1, Wt1, W2, Wt2, W3, Wt3,
        b1, g1, be1, m1, v1, s1, t1, b2, g2, be2, m2, v2, s2, t2);
    k_scanb<<<NB, 1024, 0, stream>>>(cnt_pb, bases_pb, bkt_tot, NBLK);
    k_scatter2<<<NBLK, 256, 0, stream>>>(ei, bases_pb, bkt_tot, bkt_edges, E, NB, NBLK);
    k_bucket<<<NB, 512, 0, stream>>>(bkt_edges, bkt_tot, row_ptr, dinv, csr_src,
                                     x, xq, N, NB, E);

    // Layer 1
    agg_x<<<gagg16, 256, 0, stream>>>(xq, xa, row_ptr, csr_src, dinv, N);
    g_mfma_lds<128, 64, 3, true, 2><<<dim3(128, 4), 256, 0, stream>>>(
        (const void*)xa, Wt1, (void*)h1q, N, 256, s1, t1, dinv, nT);

    // Layer 2
    agg_h<<<gagg16, 256, 0, stream>>>(h1q, h1a, row_ptr, csr_src, dinv, N);
    g_mfma_lds<256, 64, 3, true, 2><<<dim3(128, 4), 256, 0, stream>>>(
        (const void*)h1a, Wt2, (void*)h2q, N, 256, s2, t2, dinv, nT);

    // Layer 3
    g_mfma_lds<256, 32, 4, true, 2><<<dim3(512, 1), 256, 0, stream>>>(
        (const void*)h2q, Wt3, (void*)z3, N, 32, (const float*)nullptr,
        (const float*)nullptr, (const float*)nullptr, nT);
    agg32_sig<<<(N + 31) / 32, 256, 0, stream>>>(z3, out, row_ptr, csr_src, dinv, b3, N);
}